// Round 3
// baseline (2186.354 us; speedup 1.0000x reference)
//
#include <hip/hip_runtime.h>
#include <hip/hip_bf16.h>

#define NE 100000
#define NR 500
#define DD 128
#define NT 250000
#define RELOFF 12800000        // NE*DD
#define TWO_NF 500000.0f
#define NTF 250000.0f

__device__ __forceinline__ float bf2f(unsigned short u){
  unsigned int x = ((unsigned int)u) << 16;
  return __uint_as_float(x);
}
__device__ __forceinline__ float bf2f_lo(unsigned int u){ return __uint_as_float(u << 16); }
__device__ __forceinline__ float bf2f_hi(unsigned int u){ return __uint_as_float(u & 0xFFFF0000u); }
__device__ __forceinline__ unsigned short f2bf(float f){
  __hip_bfloat16 h = __float2bfloat16(f);
  return *reinterpret_cast<unsigned short*>(&h);
}
__device__ __forceinline__ void atomAddF(float* p, float v){ unsafeAtomicAdd(p, v); }
__device__ __forceinline__ float wredsum(float x){
  x += __shfl_xor(x, 1, 64);  x += __shfl_xor(x, 2, 64);  x += __shfl_xor(x, 4, 64);
  x += __shfl_xor(x, 8, 64);  x += __shfl_xor(x, 16, 64); x += __shfl_xor(x, 32, 64);
  return x;
}

// ---------------- K1: entity / relation counts ----------------
__global__ void k_count(const int* __restrict__ trip, int* __restrict__ cnt, int* __restrict__ cntR){
  int i = blockIdx.x*blockDim.x + threadIdx.x;
  if (i < NT){
    atomicAdd(&cnt[trip[3*i+0]], 1);
    atomicAdd(&cnt[trip[3*i+1]], 1);
    atomicAdd(&cntR[trip[3*i+2]], 1);
  }
}

// ---------------- scan: entity offsets (wave-shuffle, 3 barriers/chunk) ----------------
__global__ __launch_bounds__(1024) void k_scan_ent(const int* __restrict__ cnt,
                                                   int* __restrict__ off, int* __restrict__ cur){
  __shared__ int wsum[16];
  __shared__ int carrysh;
  int t = threadIdx.x, lane = t & 63, w = t >> 6;
  if (t == 0) carrysh = 0;
  __syncthreads();
  for (int base = 0; base < NE; base += 1024){
    int v = (base + t < NE) ? cnt[base + t] : 0;
    int x = v;
    #pragma unroll
    for (int s = 1; s < 64; s <<= 1){ int y = __shfl_up(x, s, 64); if (lane >= s) x += y; }
    if (lane == 63) wsum[w] = x;
    __syncthreads();                               // (1)
    if (w == 0 && lane < 16){
      int xs = wsum[lane];
      #pragma unroll
      for (int s = 1; s < 16; s <<= 1){ int y = __shfl_up(xs, s, 16); if ((lane & 15) >= s) xs += y; }
      wsum[lane] = xs;
    }
    __syncthreads();                               // (2)
    int wprev = (w == 0) ? 0 : wsum[w-1];
    int total = wsum[15];
    int c = carrysh;
    if (base + t < NE){
      int ex = c + wprev + x - v;
      off[base + t] = ex;
      cur[base + t] = ex;
    }
    __syncthreads();                               // (3)
    if (t == 0) carrysh = c + total;
  }
  if (t == 0) off[NE] = carrysh;
}

// ---------------- scan: relation offsets ----------------
__global__ __launch_bounds__(512) void k_scan_rel(const int* __restrict__ cntR,
                                                  int* __restrict__ offR, int* __restrict__ curR){
  __shared__ int sm[512];
  int t = threadIdx.x;
  int v = (t < NR) ? cntR[t] : 0;
  sm[t] = v; __syncthreads();
  for (int s = 1; s < 512; s <<= 1){
    int x = (t >= s) ? sm[t - s] : 0;
    __syncthreads();
    sm[t] += x; __syncthreads();
  }
  if (t < NR){ int ex = sm[t] - v; offR[t] = ex; curR[t] = ex; }
  if (t == 0) offR[NR] = sm[NR-1];
}

// ---------------- scatter events into CSR ----------------
// ent event: other<<10 | rel<<1 | bwdflag   (bwd => -V)
__global__ void k_scatter(const int* __restrict__ trip, int* __restrict__ curE, int* __restrict__ curR,
                          unsigned int* __restrict__ evE, uint2* __restrict__ evR){
  int i = blockIdx.x*blockDim.x + threadIdx.x;
  if (i < NT){
    int t0 = trip[3*i+0], t1 = trip[3*i+1], t2 = trip[3*i+2];
    int p0 = atomicAdd(&curE[t0], 1);
    evE[p0] = ((unsigned)t1 << 10) | ((unsigned)t2 << 1);
    int p1 = atomicAdd(&curE[t1], 1);
    evE[p1] = ((unsigned)t0 << 10) | ((unsigned)t2 << 1) | 1u;
    int p2 = atomicAdd(&curR[t2], 1);
    evR[p2] = make_uint2((unsigned)t0, (unsigned)t1);
  }
}

// ---------------- K2: count-weighted entity column stats ----------------
__global__ __launch_bounds__(256) void k_entstats(const float* __restrict__ ent, const int* __restrict__ cnt,
                                                  float* __restrict__ S, float* __restrict__ Q){
  int j = threadIdx.x & 127;
  int half = threadIdx.x >> 7;
  int r0 = blockIdx.x*128 + half;
  int r1 = min(blockIdx.x*128 + 128, NE);
  float s = 0.f, q = 0.f;
  for (int r = r0; r < r1; r += 2){
    int w = cnt[r];
    if (w){
      float x = ent[(size_t)r*DD + j];
      float wf = (float)w;
      s += wf*x; q += wf*x*x;
    }
  }
  __shared__ float ss[256], qq[256];
  ss[threadIdx.x] = s; qq[threadIdx.x] = q; __syncthreads();
  if (half == 0){
    atomAddF(&S[j], ss[j] + ss[j+128]);
    atomAddF(&Q[j], qq[j] + qq[j+128]);
  }
}

// ---------------- K3: BN0 fold + rel variance ----------------
__global__ void k_alpha(const float* __restrict__ rel, const int* __restrict__ cntR,
                        const float* __restrict__ S, const float* __restrict__ Q,
                        const float* __restrict__ bn0g, const float* __restrict__ bn0b,
                        float* __restrict__ alpha0, float* __restrict__ alpha1, float* __restrict__ alpha2,
                        float* __restrict__ beta0, float* __restrict__ beta1){
  int j = threadIdx.x;
  float qr = 0.f;
  for (int k = 0; k < NR; ++k){
    float w = (float)cntR[k];
    float x = rel[k*DD + j];
    qr += w*x*x;
  }
  float mean = S[j] / TWO_NF;
  float var  = Q[j] / TWO_NF - mean*mean;
  float inv  = rsqrtf(var + 1e-5f);
  float a0 = inv * bn0g[j];
  float a1 = inv * bn0g[128+j];
  alpha0[j] = a0; alpha1[j] = a1;
  beta0[j] = bn0b[j]     - mean*a0;
  beta1[j] = bn0b[128+j] - mean*a1;
  float varR = qr / NTF;
  alpha2[j] = rsqrtf(varR + 1e-5f) * bn0g[256+j];
}

// ---------------- K4: folded bias vector ----------------
__global__ void k_bias(const float* __restrict__ aw, const float* __restrict__ ab,
                       const float* __restrict__ bn0b,
                       const float* __restrict__ beta0, const float* __restrict__ beta1,
                       float* __restrict__ bias){
  int o = blockIdx.x, j = threadIdx.x;
  const float* r = aw + (size_t)o*384;
  float p = r[j]*beta0[j] + r[128+j]*beta1[j] + r[256+j]*bn0b[256+j];
  __shared__ float sm[128];
  sm[j] = p; __syncthreads();
  for (int s = 64; s > 0; s >>= 1){ if (j < s) sm[j] += sm[j+s]; __syncthreads(); }
  if (j == 0) bias[o] = ab[o] + sm[0];
}

// ---------------- K5: V table ----------------
__global__ void k_v(const float* __restrict__ rel, const float* __restrict__ aw,
                    const float* __restrict__ alpha2, float* __restrict__ V){
  int k = blockIdx.x, o = threadIdx.x;
  __shared__ float rl[128];
  rl[o] = rel[k*DD + o] * alpha2[o];
  __syncthreads();
  float acc = 0.f;
  #pragma unroll 8
  for (int j = 0; j < 128; ++j) acc += aw[(size_t)o*384 + 256 + j] * rl[j];
  V[k*DD + o] = acc;
}

// ---------------- K5b: fold W' into transposed bf16 table Wt[k][o] ----------------
__global__ void k_wfold(const float* __restrict__ aw, const float* __restrict__ alpha0,
                        const float* __restrict__ alpha1, unsigned short* __restrict__ Wt){
  int k = blockIdx.x;        // 0..127
  int o = threadIdx.x;       // 0..255
  float w;
  if (o < 128) w = aw[(size_t)o*384 + k] * alpha0[k];
  else         w = aw[(size_t)(o-128)*384 + 128 + k] * alpha1[k];
  Wt[k*256 + o] = f2bf(w);
}

// ---------------- K6: U table via LDS-tiled mini-GEMM ----------------
__global__ __launch_bounds__(256) void k_u(const float* __restrict__ ent,
                                           const unsigned short* __restrict__ Wt,
                                           unsigned short* __restrict__ Uo){
  __shared__ unsigned short Wl[128*256];   // 64 KB
  __shared__ float xs[32*128];             // 16 KB
  int tid = threadIdx.x;
  {
    const ushort4* src = (const ushort4*)Wt;
    ushort4* dst = (ushort4*)Wl;
    #pragma unroll 4
    for (int i = tid; i < 128*256/4; i += 256) dst[i] = src[i];
  }
  int e0 = blockIdx.x*32;                  // 3125*32 == 100000
  {
    const float4* src = (const float4*)(ent + (size_t)e0*DD);
    float4* dst = (float4*)xs;
    #pragma unroll
    for (int i = tid; i < 32*128/4; i += 256) dst[i] = src[i];
  }
  __syncthreads();
  int to = tid & 63, te = tid >> 6;
  int ob = to*4, ebase = te*8;
  float acc[8][4];
  #pragma unroll
  for (int i = 0; i < 8; ++i){
    #pragma unroll
    for (int j = 0; j < 4; ++j) acc[i][j] = 0.f;
  }
  for (int k = 0; k < 128; ++k){
    ushort4 w4 = *(const ushort4*)&Wl[k*256 + ob];
    float w0 = bf2f(w4.x), w1 = bf2f(w4.y), w2 = bf2f(w4.z), w3 = bf2f(w4.w);
    #pragma unroll
    for (int ei = 0; ei < 8; ++ei){
      float xv = xs[(ebase+ei)*128 + k];   // wave-uniform -> LDS broadcast
      acc[ei][0] += xv*w0; acc[ei][1] += xv*w1;
      acc[ei][2] += xv*w2; acc[ei][3] += xv*w3;
    }
  }
  #pragma unroll
  for (int ei = 0; ei < 8; ++ei){
    ushort4 o4;
    o4.x = f2bf(acc[ei][0]); o4.y = f2bf(acc[ei][1]);
    o4.z = f2bf(acc[ei][2]); o4.w = f2bf(acc[ei][3]);
    *(ushort4*)&Uo[(size_t)(e0 + ebase + ei)*256 + ob] = o4;
  }
}

// ---------------- K7: BN1 column stats (full-row loads + half-swap, unroll 4) ----------------
// Lanes 0-31 hold U0 cols 4l..4l+3 (fwd rows); lanes 32-63 hold U1 cols (bwd rows).
// y = own(t0 row) + swapped(t1 row) + sgn*V + bias, sgn = +1 fwd / -1 bwd.
__global__ __launch_bounds__(256) void k_c1(const int* __restrict__ trip,
                   const unsigned short* __restrict__ U, const float* __restrict__ V,
                   const float* __restrict__ bias,
                   float* __restrict__ colsum, float* __restrict__ colsumsq){
  int lane = threadIdx.x & 63;
  int c = (lane & 31) * 4;
  float sgn = (lane >= 32) ? -1.f : 1.f;
  int wv = blockIdx.x*(blockDim.x>>6) + (threadIdx.x>>6);
  int nw = gridDim.x*(blockDim.x>>6);
  float4 bv = *(const float4*)&bias[c];
  const uint2* Ur = (const uint2*)U;            // row = 64 uint2 (512B)
  float s0=0,s1=0,s2=0,s3=0,q0=0,q1=0,q2=0,q3=0;
  for (int i0 = wv*4; i0 < NT; i0 += nw*4){
    uint2 ra[4], rb[4]; float4 vv[4]; float wt[4];
    #pragma unroll
    for (int u = 0; u < 4; ++u){
      int ii = i0 + u;
      wt[u] = (ii < NT) ? 1.f : 0.f;
      ii = min(ii, NT-1);
      int t0 = trip[3*ii], t1 = trip[3*ii+1], t2 = trip[3*ii+2];
      ra[u] = Ur[(size_t)t0*64 + lane];
      rb[u] = Ur[(size_t)t1*64 + lane];
      vv[u] = *(const float4*)&V[t2*DD + c];
    }
    #pragma unroll
    for (int u = 0; u < 4; ++u){
      uint2 ex;
      ex.x = __shfl_xor(rb[u].x, 32, 64);
      ex.y = __shfl_xor(rb[u].y, 32, 64);
      float a0 = bf2f_lo(ra[u].x), a1 = bf2f_hi(ra[u].x), a2 = bf2f_lo(ra[u].y), a3 = bf2f_hi(ra[u].y);
      float b0 = bf2f_lo(ex.x),    b1 = bf2f_hi(ex.x),    b2 = bf2f_lo(ex.y),    b3 = bf2f_hi(ex.y);
      float y0 = a0 + b0 + sgn*vv[u].x + bv.x;
      float y1 = a1 + b1 + sgn*vv[u].y + bv.y;
      float y2 = a2 + b2 + sgn*vv[u].z + bv.z;
      float y3 = a3 + b3 + sgn*vv[u].w + bv.w;
      float w = wt[u];
      s0 += w*y0; q0 += w*y0*y0;
      s1 += w*y1; q1 += w*y1*y1;
      s2 += w*y2; q2 += w*y2*y2;
      s3 += w*y3; q3 += w*y3*y3;
    }
  }
  atomAddF(&colsum[c+0], s0); atomAddF(&colsum[c+1], s1);
  atomAddF(&colsum[c+2], s2); atomAddF(&colsum[c+3], s3);
  atomAddF(&colsumsq[c+0], q0); atomAddF(&colsumsq[c+1], q1);
  atomAddF(&colsumsq[c+2], q2); atomAddF(&colsumsq[c+3], q3);
}

// ---------------- K8: BN1 fold + a2 fold ----------------
__global__ void k_bn1fin(const float* __restrict__ colsum, const float* __restrict__ colsumsq,
                         const float* __restrict__ bn1g, const float* __restrict__ bn1b,
                         const float* __restrict__ a2w, const float* __restrict__ a2b,
                         float* __restrict__ A1, float* __restrict__ B1,
                         float* __restrict__ a2A, float* __restrict__ sbase){
  int j = threadIdx.x;
  float mean = colsum[j] / TWO_NF;
  float var  = colsumsq[j] / TWO_NF - mean*mean;
  float A = rsqrtf(var + 1e-5f) * bn1g[j];
  float B = bn1b[j] - mean*A;
  A1[j] = A; B1[j] = B;
  float w2 = a2w[j];
  a2A[j] = w2*A;
  __shared__ float sm[128];
  sm[j] = w2*B; __syncthreads();
  for (int s = 64; s > 0; s >>= 1){ if (j < s) sm[j] += sm[j+s]; __syncthreads(); }
  if (j == 0) sbase[0] = a2b[0] + sm[0];
}

// ---------------- K9: entity gather (event prefetch + unroll 2) ----------------
__global__ __launch_bounds__(256) void k_gent(const unsigned int* __restrict__ evE, const int* __restrict__ offE,
                   const unsigned short* __restrict__ U, const float* __restrict__ V,
                   const float* __restrict__ bias,
                   const float* __restrict__ A1, const float* __restrict__ B1,
                   const float* __restrict__ a2A, const float* __restrict__ sbase,
                   float* __restrict__ out){
  int lane = threadIdx.x & 63;
  int e = blockIdx.x*4 + (threadIdx.x>>6);
  if (e >= NE) return;
  int c0 = 2*lane, c1 = c0+1;
  const ushort2* Ub = (const ushort2*)U;
  const float2*  Vp = (const float2*)V;
  ushort2 u0 = Ub[(size_t)e*128 + lane];
  float base0 = bf2f(u0.x) + bias[c0], base1 = bf2f(u0.y) + bias[c1];
  float A10 = A1[c0], A11 = A1[c1];
  float B10 = B1[c0], B11 = B1[c1];
  float w20 = a2A[c0], w21 = a2A[c1];
  float sb = sbase[0];
  float hs0 = 0.f, hs1 = 0.f, se = 0.f;
  int p0 = offE[e], p1 = offE[e+1];
  auto consume = [&](unsigned ev, ushort2 g, float2 v){
    float sg = (ev & 1) ? -1.f : 1.f;
    float y0 = base0 + bf2f(g.x) + sg*v.x;
    float y1 = base1 + bf2f(g.y) + sg*v.y;
    float pp = wredsum(y0*w20 + y1*w21);
    float s = pp + sb;
    float bb = (s >= 0.f) ? -s : -0.01f*s;
    float eb = expf(bb);
    hs0 += eb*(y0*A10 + B10);
    hs1 += eb*(y1*A11 + B11);
    se  += eb;
  };
  for (int base = p0; base < p1; base += 64){
    int n = min(64, p1 - base);
    unsigned evl = (base + lane < p1) ? evE[base + lane] : 0u;
    int j = 0;
    for (; j + 2 <= n; j += 2){
      unsigned e0 = __shfl(evl, j, 64);
      unsigned e1 = __shfl(evl, j+1, 64);
      ushort2 g0 = Ub[(size_t)(e0 >> 10)*128 + 64 + lane];
      ushort2 g1 = Ub[(size_t)(e1 >> 10)*128 + 64 + lane];
      float2 v0 = Vp[((e0 >> 1) & 0x1FF)*64 + lane];
      float2 v1 = Vp[((e1 >> 1) & 0x1FF)*64 + lane];
      consume(e0, g0, v0);
      consume(e1, g1, v1);
    }
    for (; j < n; ++j){
      unsigned e0 = __shfl(evl, j, 64);
      ushort2 g0 = Ub[(size_t)(e0 >> 10)*128 + 64 + lane];
      float2 v0 = Vp[((e0 >> 1) & 0x1FF)*64 + lane];
      consume(e0, g0, v0);
    }
  }
  float d = (se == 0.f) ? 1e-12f : se;
  out[(size_t)e*DD + c0] = hs0/d;
  out[(size_t)e*DD + c1] = hs1/d;
}

// ---------------- K10: relation gather (event prefetch + unroll 2) ----------------
__global__ __launch_bounds__(256) void k_grel(const uint2* __restrict__ evR, const int* __restrict__ offR,
                   const unsigned short* __restrict__ U, const float* __restrict__ V,
                   const float* __restrict__ bias,
                   const float* __restrict__ A1, const float* __restrict__ B1,
                   const float* __restrict__ a2A, const float* __restrict__ sbase,
                   float* __restrict__ out){
  int lane = threadIdx.x & 63;
  int k = blockIdx.x >> 3;
  int wvs = (blockIdx.x & 7)*4 + (threadIdx.x >> 6);   // 0..31
  int c0 = 2*lane, c1 = c0+1;
  const ushort2* Ub = (const ushort2*)U;
  const float2*  Vp = (const float2*)V;
  float2 v = Vp[k*64 + lane];
  float b0 = bias[c0], b1 = bias[c1];
  float A10 = A1[c0], A11 = A1[c1];
  float B10 = B1[c0], B11 = B1[c1];
  float w20 = a2A[c0], w21 = a2A[c1];
  float sb = sbase[0];
  float acc0 = 0.f, acc1 = 0.f;
  int p0 = offR[k], p1 = offR[k+1];
  int tot = p1 - p0, per = (tot + 31) >> 5;
  int st = p0 + wvs*per, en = min(st + per, p1);
  auto consume = [&](ushort2 ua, ushort2 ud){
    float y0 = bf2f(ua.x) + bf2f(ud.x) + v.x + b0;
    float y1 = bf2f(ua.y) + bf2f(ud.y) + v.y + b1;
    float pp = wredsum(y0*w20 + y1*w21);
    float s = pp + sb;
    float bb = (s >= 0.f) ? -s : -0.01f*s;
    float eb = expf(bb);
    acc0 += eb*(y0*A10 + B10);
    acc1 += eb*(y1*A11 + B11);
  };
  for (int base = st; base < en; base += 64){
    int n = min(64, en - base);
    uint2 evl = (base + lane < en) ? evR[base + lane] : make_uint2(0u, 0u);
    int j = 0;
    for (; j + 2 <= n; j += 2){
      unsigned a0 = __shfl(evl.x, j, 64),   d0 = __shfl(evl.y, j, 64);
      unsigned a1 = __shfl(evl.x, j+1, 64), d1 = __shfl(evl.y, j+1, 64);
      ushort2 ua0 = Ub[(size_t)a0*128 + lane];
      ushort2 ud0 = Ub[(size_t)d0*128 + 64 + lane];
      ushort2 ua1 = Ub[(size_t)a1*128 + lane];
      ushort2 ud1 = Ub[(size_t)d1*128 + 64 + lane];
      consume(ua0, ud0);
      consume(ua1, ud1);
    }
    for (; j < n; ++j){
      unsigned a0 = __shfl(evl.x, j, 64), d0 = __shfl(evl.y, j, 64);
      ushort2 ua0 = Ub[(size_t)a0*128 + lane];
      ushort2 ud0 = Ub[(size_t)d0*128 + 64 + lane];
      consume(ua0, ud0);
    }
  }
  atomAddF(&out[(size_t)RELOFF + (size_t)k*DD + c0], acc0);
  atomAddF(&out[(size_t)RELOFF + (size_t)k*DD + c1], acc1);
}

// ---------------- K11: finalize rel division ----------------
__global__ void k_fin_rel(float* __restrict__ out, const int* __restrict__ cntR){
  int idx = blockIdx.x*blockDim.x + threadIdx.x;   // NR*DD threads
  int k = idx >> 7;
  float c = fmaxf((float)cntR[k], 1.f);
  out[RELOFF + idx] = out[RELOFF + idx] / c;
}

extern "C" void kernel_launch(void* const* d_in, const int* in_sizes, int n_in,
                              void* d_out, int out_size, void* d_ws, size_t ws_size,
                              hipStream_t stream) {
  (void)in_sizes; (void)n_in; (void)ws_size; (void)out_size;
  const int*   trip = (const int*)  d_in[0];
  const float* ent  = (const float*)d_in[1];
  const float* rel  = (const float*)d_in[2];
  const float* aw   = (const float*)d_in[3];
  const float* ab   = (const float*)d_in[4];
  const float* a2w  = (const float*)d_in[5];
  const float* a2b  = (const float*)d_in[6];
  const float* bn0g = (const float*)d_in[7];
  const float* bn0b = (const float*)d_in[8];
  const float* bn1g = (const float*)d_in[9];
  const float* bn1b = (const float*)d_in[10];
  float* out = (float*)d_out;

  char* w = (char*)d_ws;
  size_t off = 0;
  auto take = [&](size_t bytes) -> char* {
    char* p = w + off;
    off = (off + bytes + 511) & ~(size_t)511;
    return p;
  };
  // zeroed region (accumulators)
  float* S        = (float*)take(512);
  float* Q        = (float*)take(512);
  float* colsum   = (float*)take(512);
  float* colsumsq = (float*)take(512);
  int*   cnt      = (int*)  take((size_t)NE*4);
  int*   cntR     = (int*)  take((size_t)NR*4);
  size_t zero_end = off;
  // non-zeroed (fully overwritten each launch)
  float* alpha0 = (float*)take(512);
  float* alpha1 = (float*)take(512);
  float* alpha2 = (float*)take(512);
  float* beta0  = (float*)take(512);
  float* beta1  = (float*)take(512);
  float* biasv  = (float*)take(512);
  float* A1     = (float*)take(512);
  float* B1     = (float*)take(512);
  float* a2A    = (float*)take(512);
  float* sbase  = (float*)take(512);
  int*   offE   = (int*)  take((size_t)(NE+1)*4);
  int*   curE   = (int*)  take((size_t)NE*4);
  int*   offR   = (int*)  take((size_t)(NR+1)*4);
  int*   curR   = (int*)  take((size_t)NR*4);
  unsigned int* evE = (unsigned int*)take((size_t)2*NT*4);
  uint2* evR    = (uint2*)take((size_t)NT*8);
  float* V      = (float*)take((size_t)NR*DD*4);
  unsigned short* Wt = (unsigned short*)take((size_t)128*256*2);
  unsigned short* U  = (unsigned short*)take((size_t)NE*256*2);

  hipMemsetAsync((char*)d_out + (size_t)RELOFF*4, 0, (size_t)NR*DD*4, stream);
  hipMemsetAsync(d_ws, 0, zero_end, stream);

  k_count    <<<(NT+255)/256, 256, 0, stream>>>(trip, cnt, cntR);
  k_scan_ent <<<1, 1024, 0, stream>>>(cnt, offE, curE);
  k_scan_rel <<<1, 512, 0, stream>>>(cntR, offR, curR);
  k_scatter  <<<(NT+255)/256, 256, 0, stream>>>(trip, curE, curR, evE, evR);
  k_entstats <<<(NE+127)/128, 256, 0, stream>>>(ent, cnt, S, Q);
  k_alpha    <<<1, 128, 0, stream>>>(rel, cntR, S, Q, bn0g, bn0b, alpha0, alpha1, alpha2, beta0, beta1);
  k_bias     <<<128, 128, 0, stream>>>(aw, ab, bn0b, beta0, beta1, biasv);
  k_v        <<<NR, 128, 0, stream>>>(rel, aw, alpha2, V);
  k_wfold    <<<128, 256, 0, stream>>>(aw, alpha0, alpha1, Wt);
  k_u        <<<NE/32, 256, 0, stream>>>(ent, Wt, U);
  k_c1       <<<2048, 256, 0, stream>>>(trip, U, V, biasv, colsum, colsumsq);
  k_bn1fin   <<<1, 128, 0, stream>>>(colsum, colsumsq, bn1g, bn1b, a2w, a2b, A1, B1, a2A, sbase);
  k_gent     <<<NE/4, 256, 0, stream>>>(evE, offE, U, V, biasv, A1, B1, a2A, sbase, out);
  k_grel     <<<NR*8, 256, 0, stream>>>(evR, offR, U, V, biasv, A1, B1, a2A, sbase, out);
  k_fin_rel  <<<(NR*DD)/256, 256, 0, stream>>>(out, cntR);
}

// Round 4
// 1385.848 us; speedup vs baseline: 1.5776x; 1.5776x over previous
//
#include <hip/hip_runtime.h>
#include <hip/hip_bf16.h>

#define NE 100000
#define NR 500
#define DD 128
#define NT 250000
#define RELOFF 12800000        // NE*DD
#define TWO_NF 500000.0f
#define NTF 250000.0f

__device__ __forceinline__ float bf2f(unsigned short u){
  unsigned int x = ((unsigned int)u) << 16;
  return __uint_as_float(x);
}
__device__ __forceinline__ float bf2f_lo(unsigned int u){ return __uint_as_float(u << 16); }
__device__ __forceinline__ float bf2f_hi(unsigned int u){ return __uint_as_float(u & 0xFFFF0000u); }
__device__ __forceinline__ unsigned short f2bf(float f){
  __hip_bfloat16 h = __float2bfloat16(f);
  return *reinterpret_cast<unsigned short*>(&h);
}
__device__ __forceinline__ void atomAddF(float* p, float v){ unsafeAtomicAdd(p, v); }
__device__ __forceinline__ float wredsum(float x){
  x += __shfl_xor(x, 1, 64);  x += __shfl_xor(x, 2, 64);  x += __shfl_xor(x, 4, 64);
  x += __shfl_xor(x, 8, 64);  x += __shfl_xor(x, 16, 64); x += __shfl_xor(x, 32, 64);
  return x;
}

// ---------------- K1: entity / relation counts ----------------
__global__ void k_count(const int* __restrict__ trip, int* __restrict__ cnt, int* __restrict__ cntR){
  int i = blockIdx.x*blockDim.x + threadIdx.x;
  if (i < NT){
    atomicAdd(&cnt[trip[3*i+0]], 1);
    atomicAdd(&cnt[trip[3*i+1]], 1);
    atomicAdd(&cntR[trip[3*i+2]], 1);
  }
}

// ---------------- scan: entity offsets (wave-shuffle) ----------------
__global__ __launch_bounds__(1024) void k_scan_ent(const int* __restrict__ cnt,
                                                   int* __restrict__ off, int* __restrict__ cur){
  __shared__ int wsum[16];
  __shared__ int carrysh;
  int t = threadIdx.x, lane = t & 63, w = t >> 6;
  if (t == 0) carrysh = 0;
  __syncthreads();
  for (int base = 0; base < NE; base += 1024){
    int v = (base + t < NE) ? cnt[base + t] : 0;
    int x = v;
    #pragma unroll
    for (int s = 1; s < 64; s <<= 1){ int y = __shfl_up(x, s, 64); if (lane >= s) x += y; }
    if (lane == 63) wsum[w] = x;
    __syncthreads();
    if (w == 0 && lane < 16){
      int xs = wsum[lane];
      #pragma unroll
      for (int s = 1; s < 16; s <<= 1){ int y = __shfl_up(xs, s, 16); if ((lane & 15) >= s) xs += y; }
      wsum[lane] = xs;
    }
    __syncthreads();
    int wprev = (w == 0) ? 0 : wsum[w-1];
    int total = wsum[15];
    int c = carrysh;
    if (base + t < NE){
      int ex = c + wprev + x - v;
      off[base + t] = ex;
      cur[base + t] = ex;
    }
    __syncthreads();
    if (t == 0) carrysh = c + total;
  }
  if (t == 0) off[NE] = carrysh;
}

// ---------------- scan: relation offsets ----------------
__global__ __launch_bounds__(512) void k_scan_rel(const int* __restrict__ cntR,
                                                  int* __restrict__ offR, int* __restrict__ curR){
  __shared__ int sm[512];
  int t = threadIdx.x;
  int v = (t < NR) ? cntR[t] : 0;
  sm[t] = v; __syncthreads();
  for (int s = 1; s < 512; s <<= 1){
    int x = (t >= s) ? sm[t - s] : 0;
    __syncthreads();
    sm[t] += x; __syncthreads();
  }
  if (t < NR){ int ex = sm[t] - v; offR[t] = ex; curR[t] = ex; }
  if (t == 0) offR[NR] = sm[NR-1];
}

// ---------------- scatter events into CSR ----------------
// ent event: other<<10 | rel<<1 | bwdflag   (bwd => -V)
__global__ void k_scatter(const int* __restrict__ trip, int* __restrict__ curE, int* __restrict__ curR,
                          unsigned int* __restrict__ evE, uint2* __restrict__ evR){
  int i = blockIdx.x*blockDim.x + threadIdx.x;
  if (i < NT){
    int t0 = trip[3*i+0], t1 = trip[3*i+1], t2 = trip[3*i+2];
    int p0 = atomicAdd(&curE[t0], 1);
    evE[p0] = ((unsigned)t1 << 10) | ((unsigned)t2 << 1);
    int p1 = atomicAdd(&curE[t1], 1);
    evE[p1] = ((unsigned)t0 << 10) | ((unsigned)t2 << 1) | 1u;
    int p2 = atomicAdd(&curR[t2], 1);
    evR[p2] = make_uint2((unsigned)t0, (unsigned)t1);
  }
}

// ---------------- K2: count-weighted entity column stats ----------------
__global__ __launch_bounds__(256) void k_entstats(const float* __restrict__ ent, const int* __restrict__ cnt,
                                                  float* __restrict__ S, float* __restrict__ Q){
  int j = threadIdx.x & 127;
  int half = threadIdx.x >> 7;
  int r0 = blockIdx.x*128 + half;
  int r1 = min(blockIdx.x*128 + 128, NE);
  float s = 0.f, q = 0.f;
  for (int r = r0; r < r1; r += 2){
    int w = cnt[r];
    if (w){
      float x = ent[(size_t)r*DD + j];
      float wf = (float)w;
      s += wf*x; q += wf*x*x;
    }
  }
  __shared__ float ss[256], qq[256];
  ss[threadIdx.x] = s; qq[threadIdx.x] = q; __syncthreads();
  if (half == 0){
    atomAddF(&S[j], ss[j] + ss[j+128]);
    atomAddF(&Q[j], qq[j] + qq[j+128]);
  }
}

// ---------------- K3: BN0 fold + rel variance ----------------
__global__ void k_alpha(const float* __restrict__ rel, const int* __restrict__ cntR,
                        const float* __restrict__ S, const float* __restrict__ Q,
                        const float* __restrict__ bn0g, const float* __restrict__ bn0b,
                        float* __restrict__ alpha0, float* __restrict__ alpha1, float* __restrict__ alpha2,
                        float* __restrict__ beta0, float* __restrict__ beta1){
  int j = threadIdx.x;
  float qr = 0.f;
  for (int k = 0; k < NR; ++k){
    float w = (float)cntR[k];
    float x = rel[k*DD + j];
    qr += w*x*x;
  }
  float mean = S[j] / TWO_NF;
  float var  = Q[j] / TWO_NF - mean*mean;
  float inv  = rsqrtf(var + 1e-5f);
  float a0 = inv * bn0g[j];
  float a1 = inv * bn0g[128+j];
  alpha0[j] = a0; alpha1[j] = a1;
  beta0[j] = bn0b[j]     - mean*a0;
  beta1[j] = bn0b[128+j] - mean*a1;
  float varR = qr / NTF;
  alpha2[j] = rsqrtf(varR + 1e-5f) * bn0g[256+j];
}

// ---------------- K4: folded bias vector ----------------
__global__ void k_bias(const float* __restrict__ aw, const float* __restrict__ ab,
                       const float* __restrict__ bn0b,
                       const float* __restrict__ beta0, const float* __restrict__ beta1,
                       float* __restrict__ bias){
  int o = blockIdx.x, j = threadIdx.x;
  const float* r = aw + (size_t)o*384;
  float p = r[j]*beta0[j] + r[128+j]*beta1[j] + r[256+j]*bn0b[256+j];
  __shared__ float sm[128];
  sm[j] = p; __syncthreads();
  for (int s = 64; s > 0; s >>= 1){ if (j < s) sm[j] += sm[j+s]; __syncthreads(); }
  if (j == 0) bias[o] = ab[o] + sm[0];
}

// ---------------- K5: V table ----------------
__global__ void k_v(const float* __restrict__ rel, const float* __restrict__ aw,
                    const float* __restrict__ alpha2, float* __restrict__ V){
  int k = blockIdx.x, o = threadIdx.x;
  __shared__ float rl[128];
  rl[o] = rel[k*DD + o] * alpha2[o];
  __syncthreads();
  float acc = 0.f;
  #pragma unroll 8
  for (int j = 0; j < 128; ++j) acc += aw[(size_t)o*384 + 256 + j] * rl[j];
  V[k*DD + o] = acc;
}

// ---------------- K5b: fold W' into transposed bf16 table Wt[k][o] ----------------
__global__ void k_wfold(const float* __restrict__ aw, const float* __restrict__ alpha0,
                        const float* __restrict__ alpha1, unsigned short* __restrict__ Wt){
  int k = blockIdx.x;        // 0..127
  int o = threadIdx.x;       // 0..255
  float w;
  if (o < 128) w = aw[(size_t)o*384 + k] * alpha0[k];
  else         w = aw[(size_t)(o-128)*384 + 128 + k] * alpha1[k];
  Wt[k*256 + o] = f2bf(w);
}

// ---------------- K6: U table via LDS-tiled mini-GEMM ----------------
__global__ __launch_bounds__(256) void k_u(const float* __restrict__ ent,
                                           const unsigned short* __restrict__ Wt,
                                           unsigned short* __restrict__ Uo){
  __shared__ unsigned short Wl[128*256];   // 64 KB
  __shared__ float xs[32*128];             // 16 KB
  int tid = threadIdx.x;
  {
    const ushort4* src = (const ushort4*)Wt;
    ushort4* dst = (ushort4*)Wl;
    #pragma unroll 4
    for (int i = tid; i < 128*256/4; i += 256) dst[i] = src[i];
  }
  int e0 = blockIdx.x*32;                  // 3125*32 == 100000
  {
    const float4* src = (const float4*)(ent + (size_t)e0*DD);
    float4* dst = (float4*)xs;
    #pragma unroll
    for (int i = tid; i < 32*128/4; i += 256) dst[i] = src[i];
  }
  __syncthreads();
  int to = tid & 63, te = tid >> 6;
  int ob = to*4, ebase = te*8;
  float acc[8][4];
  #pragma unroll
  for (int i = 0; i < 8; ++i){
    #pragma unroll
    for (int j = 0; j < 4; ++j) acc[i][j] = 0.f;
  }
  for (int k = 0; k < 128; ++k){
    ushort4 w4 = *(const ushort4*)&Wl[k*256 + ob];
    float w0 = bf2f(w4.x), w1 = bf2f(w4.y), w2 = bf2f(w4.z), w3 = bf2f(w4.w);
    #pragma unroll
    for (int ei = 0; ei < 8; ++ei){
      float xv = xs[(ebase+ei)*128 + k];
      acc[ei][0] += xv*w0; acc[ei][1] += xv*w1;
      acc[ei][2] += xv*w2; acc[ei][3] += xv*w3;
    }
  }
  #pragma unroll
  for (int ei = 0; ei < 8; ++ei){
    ushort4 o4;
    o4.x = f2bf(acc[ei][0]); o4.y = f2bf(acc[ei][1]);
    o4.z = f2bf(acc[ei][2]); o4.w = f2bf(acc[ei][3]);
    *(ushort4*)&Uo[(size_t)(e0 + ebase + ei)*256 + ob] = o4;
  }
}

// ---------------- K7: BN1 column stats (R2 body, unroll x2 with NAMED vars) ----------------
__global__ __launch_bounds__(256) void k_c1(const int* __restrict__ trip,
                   const unsigned short* __restrict__ U, const float* __restrict__ V,
                   const float* __restrict__ bias,
                   float* __restrict__ colsum, float* __restrict__ colsumsq){
  int lane = threadIdx.x & 63;
  int wv = blockIdx.x*(blockDim.x>>6) + (threadIdx.x>>6);
  int nw = gridDim.x*(blockDim.x>>6);
  int c0 = 2*lane, c1 = 2*lane+1;
  float b0 = bias[c0], b1 = bias[c1];
  const ushort2* Ub = (const ushort2*)U;
  const float2*  Vp = (const float2*)V;
  float s0=0.f, s1=0.f, q0=0.f, q1=0.f;
  for (int i = wv; i < NT; i += 2*nw){
    int iB = i + nw;
    float wB = (iB < NT) ? 1.f : 0.f;
    int iBc = (iB < NT) ? iB : i;
    int At0 = trip[3*i],   At1 = trip[3*i+1],   At2 = trip[3*i+2];
    int Bt0 = trip[3*iBc], Bt1 = trip[3*iBc+1], Bt2 = trip[3*iBc+2];
    ushort2 Aa0 = Ub[(size_t)At0*128 + lane];
    ushort2 Aa1 = Ub[(size_t)At0*128 + 64 + lane];
    ushort2 Ad0 = Ub[(size_t)At1*128 + lane];
    ushort2 Ad1 = Ub[(size_t)At1*128 + 64 + lane];
    float2  Av  = Vp[(size_t)At2*64 + lane];
    ushort2 Ba0 = Ub[(size_t)Bt0*128 + lane];
    ushort2 Ba1 = Ub[(size_t)Bt0*128 + 64 + lane];
    ushort2 Bd0 = Ub[(size_t)Bt1*128 + lane];
    ushort2 Bd1 = Ub[(size_t)Bt1*128 + 64 + lane];
    float2  Bv  = Vp[(size_t)Bt2*64 + lane];
    {
      float yf0 = bf2f(Aa0.x) + bf2f(Ad1.x) + Av.x + b0;
      float yf1 = bf2f(Aa0.y) + bf2f(Ad1.y) + Av.y + b1;
      float yb0 = bf2f(Ad0.x) + bf2f(Aa1.x) - Av.x + b0;
      float yb1 = bf2f(Ad0.y) + bf2f(Aa1.y) - Av.y + b1;
      s0 += yf0 + yb0;  s1 += yf1 + yb1;
      q0 += yf0*yf0 + yb0*yb0;  q1 += yf1*yf1 + yb1*yb1;
    }
    {
      float zf0 = bf2f(Ba0.x) + bf2f(Bd1.x) + Bv.x + b0;
      float zf1 = bf2f(Ba0.y) + bf2f(Bd1.y) + Bv.y + b1;
      float zb0 = bf2f(Bd0.x) + bf2f(Ba1.x) - Bv.x + b0;
      float zb1 = bf2f(Bd0.y) + bf2f(Ba1.y) - Bv.y + b1;
      s0 += wB*(zf0 + zb0);  s1 += wB*(zf1 + zb1);
      q0 += wB*(zf0*zf0 + zb0*zb0);  q1 += wB*(zf1*zf1 + zb1*zb1);
    }
  }
  atomAddF(&colsum[c0], s0);   atomAddF(&colsum[c1], s1);
  atomAddF(&colsumsq[c0], q0); atomAddF(&colsumsq[c1], q1);
}

// ---------------- K8: BN1 fold + a2 fold + pbsb ----------------
__global__ void k_bn1fin(const float* __restrict__ colsum, const float* __restrict__ colsumsq,
                         const float* __restrict__ bn1g, const float* __restrict__ bn1b,
                         const float* __restrict__ a2w, const float* __restrict__ a2b,
                         const float* __restrict__ biasv,
                         float* __restrict__ A1, float* __restrict__ B1,
                         float* __restrict__ a2A, float* __restrict__ sbase){
  int j = threadIdx.x;
  float mean = colsum[j] / TWO_NF;
  float var  = colsumsq[j] / TWO_NF - mean*mean;
  float A = rsqrtf(var + 1e-5f) * bn1g[j];
  float B = bn1b[j] - mean*A;
  A1[j] = A; B1[j] = B;
  float w2 = a2w[j];
  float aA = w2*A;
  a2A[j] = aA;
  __shared__ float sm[128], sm2[128];
  sm[j] = w2*B; sm2[j] = biasv[j]*aA;
  __syncthreads();
  for (int s = 64; s > 0; s >>= 1){
    if (j < s){ sm[j] += sm[j+s]; sm2[j] += sm2[j+s]; }
    __syncthreads();
  }
  if (j == 0){
    float sb = a2b[0] + sm[0];
    sbase[0] = sb;
    sbase[1] = sb + sm2[0];   // pbsb = dot(bias,a2A) + sbase
  }
}

// ---------------- K8b: per-entity score scalars sigma0/sigma1 ----------------
__global__ __launch_bounds__(256) void k_sigma(const unsigned short* __restrict__ U,
                                               const float* __restrict__ a2A,
                                               float* __restrict__ sig){
  int lane = threadIdx.x & 63;
  int e = blockIdx.x*4 + (threadIdx.x>>6);
  if (e >= NE) return;
  const uint2* Ur = (const uint2*)U;
  uint2 r = Ur[(size_t)e*64 + lane];
  int c = (lane & 31)*4;
  float4 w = *(const float4*)&a2A[c];
  float p = bf2f_lo(r.x)*w.x + bf2f_hi(r.x)*w.y + bf2f_lo(r.y)*w.z + bf2f_hi(r.y)*w.w;
  p += __shfl_xor(p, 1, 64); p += __shfl_xor(p, 2, 64); p += __shfl_xor(p, 4, 64);
  p += __shfl_xor(p, 8, 64); p += __shfl_xor(p, 16, 64);
  if ((lane & 31) == 0) sig[2*e + (lane >> 5)] = p;
}

// ---------------- K8c: per-relation score scalar rho ----------------
__global__ __launch_bounds__(256) void k_rho(const float* __restrict__ V,
                                             const float* __restrict__ a2A,
                                             float* __restrict__ rho){
  int lane = threadIdx.x & 63;
  int k = blockIdx.x*4 + (threadIdx.x>>6);
  if (k >= NR) return;
  const float2* Vp = (const float2*)V;
  float2 v = Vp[(size_t)k*64 + lane];
  int c0 = 2*lane;
  float p = v.x*a2A[c0] + v.y*a2A[c0+1];
  p = wredsum(p);
  if (lane == 0) rho[k] = p;
}

// ---------------- K9: entity gather — lane-parallel scores + FMA stream ----------------
__global__ __launch_bounds__(256) void k_gent(const unsigned int* __restrict__ evE, const int* __restrict__ offE,
                   const unsigned short* __restrict__ U, const float* __restrict__ V,
                   const float* __restrict__ sig, const float* __restrict__ rho,
                   const float* __restrict__ bias,
                   const float* __restrict__ A1, const float* __restrict__ B1,
                   const float* __restrict__ sbase,
                   float* __restrict__ out){
  int lane = threadIdx.x & 63;
  int e = blockIdx.x*4 + (threadIdx.x>>6);
  if (e >= NE) return;
  int c0 = 2*lane, c1 = c0+1;
  const ushort2* Ub = (const ushort2*)U;
  const float2*  Vp = (const float2*)V;
  ushort2 u0 = Ub[(size_t)e*128 + lane];
  float base0 = bf2f(u0.x) + bias[c0], base1 = bf2f(u0.y) + bias[c1];
  float pb  = sbase[1];
  float s0e = sig[2*e];
  float accU0=0.f, accU1=0.f, accV0=0.f, accV1=0.f, sep=0.f;
  int p0 = offE[e], p1 = offE[e+1];
  for (int bs = p0; bs < p1; bs += 64){
    int n = min(64, p1 - bs);
    unsigned ev = 0u; float ebl = 0.f;
    if (bs + lane < p1){
      ev = evE[bs + lane];
      int oth = ev >> 10, rl = (ev >> 1) & 0x1FF;
      float sg = (ev & 1) ? -1.f : 1.f;
      float s = s0e + sig[2*oth + 1] + sg*rho[rl] + pb;
      float bb = (s >= 0.f) ? -s : -0.01f*s;
      ebl = expf(bb);
    }
    sep += ebl;
    int j = 0;
    for (; j + 2 <= n; j += 2){
      unsigned e0 = __shfl(ev, j, 64);
      unsigned e1 = __shfl(ev, j+1, 64);
      float eb0 = __shfl(ebl, j, 64);
      float eb1 = __shfl(ebl, j+1, 64);
      ushort2 g0 = Ub[(size_t)(e0 >> 10)*128 + 64 + lane];
      ushort2 g1 = Ub[(size_t)(e1 >> 10)*128 + 64 + lane];
      float2 v0 = Vp[((e0 >> 1) & 0x1FF)*64 + lane];
      float2 v1 = Vp[((e1 >> 1) & 0x1FF)*64 + lane];
      float w0 = (e0 & 1) ? -eb0 : eb0;
      float w1 = (e1 & 1) ? -eb1 : eb1;
      accU0 += eb0*bf2f(g0.x); accU1 += eb0*bf2f(g0.y);
      accV0 += w0*v0.x;        accV1 += w0*v0.y;
      accU0 += eb1*bf2f(g1.x); accU1 += eb1*bf2f(g1.y);
      accV0 += w1*v1.x;        accV1 += w1*v1.y;
    }
    for (; j < n; ++j){
      unsigned e0 = __shfl(ev, j, 64);
      float eb0 = __shfl(ebl, j, 64);
      ushort2 g0 = Ub[(size_t)(e0 >> 10)*128 + 64 + lane];
      float2 v0 = Vp[((e0 >> 1) & 0x1FF)*64 + lane];
      float w0 = (e0 & 1) ? -eb0 : eb0;
      accU0 += eb0*bf2f(g0.x); accU1 += eb0*bf2f(g0.y);
      accV0 += w0*v0.x;        accV1 += w0*v0.y;
    }
  }
  float se = wredsum(sep);
  float sY0 = se*base0 + accU0 + accV0;
  float sY1 = se*base1 + accU1 + accV1;
  float hs0 = A1[c0]*sY0 + B1[c0]*se;
  float hs1 = A1[c1]*sY1 + B1[c1]*se;
  float d = (se == 0.f) ? 1e-12f : se;
  out[(size_t)e*DD + c0] = hs0/d;
  out[(size_t)e*DD + c1] = hs1/d;
}

// ---------------- K10: relation gather — lane-parallel scores + FMA stream ----------------
__global__ __launch_bounds__(256) void k_grel(const uint2* __restrict__ evR, const int* __restrict__ offR,
                   const unsigned short* __restrict__ U, const float* __restrict__ V,
                   const float* __restrict__ sig, const float* __restrict__ rho,
                   const float* __restrict__ bias,
                   const float* __restrict__ A1, const float* __restrict__ B1,
                   const float* __restrict__ sbase,
                   float* __restrict__ out){
  int lane = threadIdx.x & 63;
  int k = blockIdx.x >> 3;
  int wvs = (blockIdx.x & 7)*4 + (threadIdx.x >> 6);   // 0..31
  int c0 = 2*lane, c1 = c0+1;
  const ushort2* Ub = (const ushort2*)U;
  const float2*  Vp = (const float2*)V;
  float2 v = Vp[(size_t)k*64 + lane];
  float vb0 = v.x + bias[c0], vb1 = v.y + bias[c1];
  float rpb = rho[k] + sbase[1];
  float accY0=0.f, accY1=0.f, sep=0.f;
  int p0 = offR[k], p1 = offR[k+1];
  int tot = p1 - p0, per = (tot + 31) >> 5;
  int st = p0 + wvs*per, en = min(st + per, p1);
  for (int bs = st; bs < en; bs += 64){
    int n = min(64, en - bs);
    uint2 ev = make_uint2(0u, 0u); float ebl = 0.f;
    if (bs + lane < en){
      ev = evR[bs + lane];
      float s = sig[2*ev.x] + sig[2*ev.y + 1] + rpb;
      float bb = (s >= 0.f) ? -s : -0.01f*s;
      ebl = expf(bb);
    }
    sep += ebl;
    int j = 0;
    for (; j + 2 <= n; j += 2){
      unsigned a0 = __shfl(ev.x, j, 64),   d0 = __shfl(ev.y, j, 64);
      unsigned a1 = __shfl(ev.x, j+1, 64), d1 = __shfl(ev.y, j+1, 64);
      float eb0 = __shfl(ebl, j, 64);
      float eb1 = __shfl(ebl, j+1, 64);
      ushort2 ua0 = Ub[(size_t)a0*128 + lane];
      ushort2 ud0 = Ub[(size_t)d0*128 + 64 + lane];
      ushort2 ua1 = Ub[(size_t)a1*128 + lane];
      ushort2 ud1 = Ub[(size_t)d1*128 + 64 + lane];
      accY0 += eb0*(bf2f(ua0.x) + bf2f(ud0.x));
      accY1 += eb0*(bf2f(ua0.y) + bf2f(ud0.y));
      accY0 += eb1*(bf2f(ua1.x) + bf2f(ud1.x));
      accY1 += eb1*(bf2f(ua1.y) + bf2f(ud1.y));
    }
    for (; j < n; ++j){
      unsigned a0 = __shfl(ev.x, j, 64), d0 = __shfl(ev.y, j, 64);
      float eb0 = __shfl(ebl, j, 64);
      ushort2 ua0 = Ub[(size_t)a0*128 + lane];
      ushort2 ud0 = Ub[(size_t)d0*128 + 64 + lane];
      accY0 += eb0*(bf2f(ua0.x) + bf2f(ud0.x));
      accY1 += eb0*(bf2f(ua0.y) + bf2f(ud0.y));
    }
  }
  float se = wredsum(sep);
  float sY0 = accY0 + se*vb0;
  float sY1 = accY1 + se*vb1;
  float r0 = A1[c0]*sY0 + B1[c0]*se;
  float r1 = A1[c1]*sY1 + B1[c1]*se;
  atomAddF(&out[(size_t)RELOFF + (size_t)k*DD + c0], r0);
  atomAddF(&out[(size_t)RELOFF + (size_t)k*DD + c1], r1);
}

// ---------------- K11: finalize rel division ----------------
__global__ void k_fin_rel(float* __restrict__ out, const int* __restrict__ cntR){
  int idx = blockIdx.x*blockDim.x + threadIdx.x;   // NR*DD threads
  int k = idx >> 7;
  float c = fmaxf((float)cntR[k], 1.f);
  out[RELOFF + idx] = out[RELOFF + idx] / c;
}

extern "C" void kernel_launch(void* const* d_in, const int* in_sizes, int n_in,
                              void* d_out, int out_size, void* d_ws, size_t ws_size,
                              hipStream_t stream) {
  (void)in_sizes; (void)n_in; (void)ws_size; (void)out_size;
  const int*   trip = (const int*)  d_in[0];
  const float* ent  = (const float*)d_in[1];
  const float* rel  = (const float*)d_in[2];
  const float* aw   = (const float*)d_in[3];
  const float* ab   = (const float*)d_in[4];
  const float* a2w  = (const float*)d_in[5];
  const float* a2b  = (const float*)d_in[6];
  const float* bn0g = (const float*)d_in[7];
  const float* bn0b = (const float*)d_in[8];
  const float* bn1g = (const float*)d_in[9];
  const float* bn1b = (const float*)d_in[10];
  float* out = (float*)d_out;

  char* w = (char*)d_ws;
  size_t off = 0;
  auto take = [&](size_t bytes) -> char* {
    char* p = w + off;
    off = (off + bytes + 511) & ~(size_t)511;
    return p;
  };
  // zeroed region (accumulators)
  float* S        = (float*)take(512);
  float* Q        = (float*)take(512);
  float* colsum   = (float*)take(512);
  float* colsumsq = (float*)take(512);
  int*   cnt      = (int*)  take((size_t)NE*4);
  int*   cntR     = (int*)  take((size_t)NR*4);
  size_t zero_end = off;
  // non-zeroed (fully overwritten each launch)
  float* alpha0 = (float*)take(512);
  float* alpha1 = (float*)take(512);
  float* alpha2 = (float*)take(512);
  float* beta0  = (float*)take(512);
  float* beta1  = (float*)take(512);
  float* biasv  = (float*)take(512);
  float* A1     = (float*)take(512);
  float* B1     = (float*)take(512);
  float* a2A    = (float*)take(512);
  float* sbase  = (float*)take(512);
  float* rho    = (float*)take((size_t)NR*4);
  float* sig    = (float*)take((size_t)NE*2*4);
  int*   offE   = (int*)  take((size_t)(NE+1)*4);
  int*   curE   = (int*)  take((size_t)NE*4);
  int*   offR   = (int*)  take((size_t)(NR+1)*4);
  int*   curR   = (int*)  take((size_t)NR*4);
  unsigned int* evE = (unsigned int*)take((size_t)2*NT*4);
  uint2* evR    = (uint2*)take((size_t)NT*8);
  float* V      = (float*)take((size_t)NR*DD*4);
  unsigned short* Wt = (unsigned short*)take((size_t)128*256*2);
  unsigned short* U  = (unsigned short*)take((size_t)NE*256*2);

  hipMemsetAsync((char*)d_out + (size_t)RELOFF*4, 0, (size_t)NR*DD*4, stream);
  hipMemsetAsync(d_ws, 0, zero_end, stream);

  k_count    <<<(NT+255)/256, 256, 0, stream>>>(trip, cnt, cntR);
  k_scan_ent <<<1, 1024, 0, stream>>>(cnt, offE, curE);
  k_scan_rel <<<1, 512, 0, stream>>>(cntR, offR, curR);
  k_scatter  <<<(NT+255)/256, 256, 0, stream>>>(trip, curE, curR, evE, evR);
  k_entstats <<<(NE+127)/128, 256, 0, stream>>>(ent, cnt, S, Q);
  k_alpha    <<<1, 128, 0, stream>>>(rel, cntR, S, Q, bn0g, bn0b, alpha0, alpha1, alpha2, beta0, beta1);
  k_bias     <<<128, 128, 0, stream>>>(aw, ab, bn0b, beta0, beta1, biasv);
  k_v        <<<NR, 128, 0, stream>>>(rel, aw, alpha2, V);
  k_wfold    <<<128, 256, 0, stream>>>(aw, alpha0, alpha1, Wt);
  k_u        <<<NE/32, 256, 0, stream>>>(ent, Wt, U);
  k_c1       <<<4096, 256, 0, stream>>>(trip, U, V, biasv, colsum, colsumsq);
  k_bn1fin   <<<1, 128, 0, stream>>>(colsum, colsumsq, bn1g, bn1b, a2w, a2b, biasv, A1, B1, a2A, sbase);
  k_sigma    <<<NE/4, 256, 0, stream>>>(U, a2A, sig);
  k_rho      <<<(NR+3)/4, 256, 0, stream>>>(V, a2A, rho);
  k_gent     <<<NE/4, 256, 0, stream>>>(evE, offE, U, V, sig, rho, biasv, A1, B1, sbase, out);
  k_grel     <<<NR*8, 256, 0, stream>>>(evR, offR, U, V, sig, rho, biasv, A1, B1, sbase, out);
  k_fin_rel  <<<(NR*DD)/256, 256, 0, stream>>>(out, cntR);
}

// Round 5
// 650.360 us; speedup vs baseline: 3.3618x; 2.1309x over previous
//
#include <hip/hip_runtime.h>
#include <hip/hip_bf16.h>

#define NE 100000
#define NR 500
#define DD 128
#define NT 250000
#define NEV 500000             // 2*NT events
#define RELOFF 12800000        // NE*DD
#define TWO_NF 500000.0f
#define NTF 250000.0f

__device__ __forceinline__ float bf2f(unsigned short u){
  unsigned int x = ((unsigned int)u) << 16;
  return __uint_as_float(x);
}
__device__ __forceinline__ float bf2f_lo(unsigned int u){ return __uint_as_float(u << 16); }
__device__ __forceinline__ float bf2f_hi(unsigned int u){ return __uint_as_float(u & 0xFFFF0000u); }
__device__ __forceinline__ unsigned short f2bf(float f){
  __hip_bfloat16 h = __float2bfloat16(f);
  return *reinterpret_cast<unsigned short*>(&h);
}
__device__ __forceinline__ void atomAddF(float* p, float v){ unsafeAtomicAdd(p, v); }
__device__ __forceinline__ float wredsum(float x){
  x += __shfl_xor(x, 1, 64);  x += __shfl_xor(x, 2, 64);  x += __shfl_xor(x, 4, 64);
  x += __shfl_xor(x, 8, 64);  x += __shfl_xor(x, 16, 64); x += __shfl_xor(x, 32, 64);
  return x;
}

// ---------------- K1: entity / relation counts ----------------
__global__ void k_count(const int* __restrict__ trip, int* __restrict__ cnt, int* __restrict__ cntR){
  int i = blockIdx.x*blockDim.x + threadIdx.x;
  if (i < NT){
    atomicAdd(&cnt[trip[3*i+0]], 1);
    atomicAdd(&cnt[trip[3*i+1]], 1);
    atomicAdd(&cntR[trip[3*i+2]], 1);
  }
}

// ---------------- scan: entity offsets (wave-shuffle) ----------------
__global__ __launch_bounds__(1024) void k_scan_ent(const int* __restrict__ cnt,
                                                   int* __restrict__ off, int* __restrict__ cur){
  __shared__ int wsum[16];
  __shared__ int carrysh;
  int t = threadIdx.x, lane = t & 63, w = t >> 6;
  if (t == 0) carrysh = 0;
  __syncthreads();
  for (int base = 0; base < NE; base += 1024){
    int v = (base + t < NE) ? cnt[base + t] : 0;
    int x = v;
    #pragma unroll
    for (int s = 1; s < 64; s <<= 1){ int y = __shfl_up(x, s, 64); if (lane >= s) x += y; }
    if (lane == 63) wsum[w] = x;
    __syncthreads();
    if (w == 0 && lane < 16){
      int xs = wsum[lane];
      #pragma unroll
      for (int s = 1; s < 16; s <<= 1){ int y = __shfl_up(xs, s, 16); if ((lane & 15) >= s) xs += y; }
      wsum[lane] = xs;
    }
    __syncthreads();
    int wprev = (w == 0) ? 0 : wsum[w-1];
    int total = wsum[15];
    int c = carrysh;
    if (base + t < NE){
      int ex = c + wprev + x - v;
      off[base + t] = ex;
      cur[base + t] = ex;
    }
    __syncthreads();
    if (t == 0) carrysh = c + total;
  }
  if (t == 0) off[NE] = carrysh;
}

// ---------------- scan: relation offsets ----------------
__global__ __launch_bounds__(512) void k_scan_rel(const int* __restrict__ cntR,
                                                  int* __restrict__ offR, int* __restrict__ curR){
  __shared__ int sm[512];
  int t = threadIdx.x;
  int v = (t < NR) ? cntR[t] : 0;
  sm[t] = v; __syncthreads();
  for (int s = 1; s < 512; s <<= 1){
    int x = (t >= s) ? sm[t - s] : 0;
    __syncthreads();
    sm[t] += x; __syncthreads();
  }
  if (t < NR){ int ex = sm[t] - v; offR[t] = ex; curR[t] = ex; }
  if (t == 0) offR[NR] = sm[NR-1];
}

// ---------------- scatter events into CSR ----------------
// ent event: x = owner, y = other<<10 | rel<<1 | bwdflag (bwd => -V)
__global__ void k_scatter(const int* __restrict__ trip, int* __restrict__ curE, int* __restrict__ curR,
                          uint2* __restrict__ evE, uint2* __restrict__ evR){
  int i = blockIdx.x*blockDim.x + threadIdx.x;
  if (i < NT){
    int t0 = trip[3*i+0], t1 = trip[3*i+1], t2 = trip[3*i+2];
    int p0 = atomicAdd(&curE[t0], 1);
    evE[p0] = make_uint2((unsigned)t0, ((unsigned)t1 << 10) | ((unsigned)t2 << 1));
    int p1 = atomicAdd(&curE[t1], 1);
    evE[p1] = make_uint2((unsigned)t1, ((unsigned)t0 << 10) | ((unsigned)t2 << 1) | 1u);
    int p2 = atomicAdd(&curR[t2], 1);
    evR[p2] = make_uint2((unsigned)t0, (unsigned)t1);
  }
}

// ---------------- K2: count-weighted entity column stats ----------------
__global__ __launch_bounds__(256) void k_entstats(const float* __restrict__ ent, const int* __restrict__ cnt,
                                                  float* __restrict__ S, float* __restrict__ Q){
  int j = threadIdx.x & 127;
  int half = threadIdx.x >> 7;
  int r0 = blockIdx.x*128 + half;
  int r1 = min(blockIdx.x*128 + 128, NE);
  float s = 0.f, q = 0.f;
  for (int r = r0; r < r1; r += 2){
    int w = cnt[r];
    if (w){
      float x = ent[(size_t)r*DD + j];
      float wf = (float)w;
      s += wf*x; q += wf*x*x;
    }
  }
  __shared__ float ss[256], qq[256];
  ss[threadIdx.x] = s; qq[threadIdx.x] = q; __syncthreads();
  if (half == 0){
    atomAddF(&S[j], ss[j] + ss[j+128]);
    atomAddF(&Q[j], qq[j] + qq[j+128]);
  }
}

// ---------------- K3: BN0 fold + rel variance ----------------
__global__ void k_alpha(const float* __restrict__ rel, const int* __restrict__ cntR,
                        const float* __restrict__ S, const float* __restrict__ Q,
                        const float* __restrict__ bn0g, const float* __restrict__ bn0b,
                        float* __restrict__ alpha0, float* __restrict__ alpha1, float* __restrict__ alpha2,
                        float* __restrict__ beta0, float* __restrict__ beta1){
  int j = threadIdx.x;
  float qr = 0.f;
  for (int k = 0; k < NR; ++k){
    float w = (float)cntR[k];
    float x = rel[k*DD + j];
    qr += w*x*x;
  }
  float mean = S[j] / TWO_NF;
  float var  = Q[j] / TWO_NF - mean*mean;
  float inv  = rsqrtf(var + 1e-5f);
  float a0 = inv * bn0g[j];
  float a1 = inv * bn0g[128+j];
  alpha0[j] = a0; alpha1[j] = a1;
  beta0[j] = bn0b[j]     - mean*a0;
  beta1[j] = bn0b[128+j] - mean*a1;
  float varR = qr / NTF;
  alpha2[j] = rsqrtf(varR + 1e-5f) * bn0g[256+j];
}

// ---------------- K4: folded bias vector ----------------
__global__ void k_bias(const float* __restrict__ aw, const float* __restrict__ ab,
                       const float* __restrict__ bn0b,
                       const float* __restrict__ beta0, const float* __restrict__ beta1,
                       float* __restrict__ bias){
  int o = blockIdx.x, j = threadIdx.x;
  const float* r = aw + (size_t)o*384;
  float p = r[j]*beta0[j] + r[128+j]*beta1[j] + r[256+j]*bn0b[256+j];
  __shared__ float sm[128];
  sm[j] = p; __syncthreads();
  for (int s = 64; s > 0; s >>= 1){ if (j < s) sm[j] += sm[j+s]; __syncthreads(); }
  if (j == 0) bias[o] = ab[o] + sm[0];
}

// ---------------- K5: V table ----------------
__global__ void k_v(const float* __restrict__ rel, const float* __restrict__ aw,
                    const float* __restrict__ alpha2, float* __restrict__ V){
  int k = blockIdx.x, o = threadIdx.x;
  __shared__ float rl[128];
  rl[o] = rel[k*DD + o] * alpha2[o];
  __syncthreads();
  float acc = 0.f;
  #pragma unroll 8
  for (int j = 0; j < 128; ++j) acc += aw[(size_t)o*384 + 256 + j] * rl[j];
  V[k*DD + o] = acc;
}

// ---------------- K5b: fold W' into transposed bf16 table Wt[k][o] ----------------
__global__ void k_wfold(const float* __restrict__ aw, const float* __restrict__ alpha0,
                        const float* __restrict__ alpha1, unsigned short* __restrict__ Wt){
  int k = blockIdx.x;        // 0..127
  int o = threadIdx.x;       // 0..255
  float w;
  if (o < 128) w = aw[(size_t)o*384 + k] * alpha0[k];
  else         w = aw[(size_t)(o-128)*384 + 128 + k] * alpha1[k];
  Wt[k*256 + o] = f2bf(w);
}

// ---------------- K6: U table via LDS-tiled mini-GEMM ----------------
__global__ __launch_bounds__(256) void k_u(const float* __restrict__ ent,
                                           const unsigned short* __restrict__ Wt,
                                           unsigned short* __restrict__ Uo){
  __shared__ unsigned short Wl[128*256];   // 64 KB
  __shared__ float xs[32*128];             // 16 KB
  int tid = threadIdx.x;
  {
    const ushort4* src = (const ushort4*)Wt;
    ushort4* dst = (ushort4*)Wl;
    #pragma unroll 4
    for (int i = tid; i < 128*256/4; i += 256) dst[i] = src[i];
  }
  int e0 = blockIdx.x*32;                  // 3125*32 == 100000
  {
    const float4* src = (const float4*)(ent + (size_t)e0*DD);
    float4* dst = (float4*)xs;
    #pragma unroll
    for (int i = tid; i < 32*128/4; i += 256) dst[i] = src[i];
  }
  __syncthreads();
  int to = tid & 63, te = tid >> 6;
  int ob = to*4, ebase = te*8;
  float acc[8][4];
  #pragma unroll
  for (int i = 0; i < 8; ++i){
    #pragma unroll
    for (int j = 0; j < 4; ++j) acc[i][j] = 0.f;
  }
  for (int k = 0; k < 128; ++k){
    ushort4 w4 = *(const ushort4*)&Wl[k*256 + ob];
    float w0 = bf2f(w4.x), w1 = bf2f(w4.y), w2 = bf2f(w4.z), w3 = bf2f(w4.w);
    #pragma unroll
    for (int ei = 0; ei < 8; ++ei){
      float xv = xs[(ebase+ei)*128 + k];
      acc[ei][0] += xv*w0; acc[ei][1] += xv*w1;
      acc[ei][2] += xv*w2; acc[ei][3] += xv*w3;
    }
  }
  #pragma unroll
  for (int ei = 0; ei < 8; ++ei){
    ushort4 o4;
    o4.x = f2bf(acc[ei][0]); o4.y = f2bf(acc[ei][1]);
    o4.z = f2bf(acc[ei][2]); o4.w = f2bf(acc[ei][3]);
    *(ushort4*)&Uo[(size_t)(e0 + ebase + ei)*256 + ob] = o4;
  }
}

// ---------------- K7: BN1 column stats over CSR events ----------------
// Each event = one BN row: y = U0[own] + U1[oth] + sgn*V[rel] + bias.
// Events sorted by owner -> U0[own] reads are L1/L2-resident; only U1[oth] is random.
__global__ __launch_bounds__(256) void k_c1b(const uint2* __restrict__ evE,
                   const unsigned short* __restrict__ U, const float* __restrict__ V,
                   const float* __restrict__ bias,
                   float* __restrict__ colsum, float* __restrict__ colsumsq){
  int lane = threadIdx.x & 63;
  int w = threadIdx.x >> 6;
  int wv = blockIdx.x*4 + w;
  int nwv = gridDim.x*4;
  int per = (NEV + nwv - 1) / nwv;
  int st = wv*per, en = min(st + per, NEV);
  int c0 = 2*lane, c1 = c0+1;
  float b0 = bias[c0], b1 = bias[c1];
  const ushort2* Ub = (const ushort2*)U;
  const float2*  Vp = (const float2*)V;
  float s0=0.f, s1=0.f, q0=0.f, q1=0.f;
  for (int bs = st; bs < en; bs += 64){
    int n = min(64, en - bs);
    uint2 ev = (bs + lane < en) ? evE[bs + lane] : make_uint2(0u, 0u);
    int j = 0;
    for (; j + 2 <= n; j += 2){
      unsigned ow0 = __shfl(ev.x, j, 64),   pk0 = __shfl(ev.y, j, 64);
      unsigned ow1 = __shfl(ev.x, j+1, 64), pk1 = __shfl(ev.y, j+1, 64);
      ushort2 a0 = Ub[(size_t)ow0*128 + lane];
      ushort2 g0 = Ub[(size_t)(pk0 >> 10)*128 + 64 + lane];
      float2  v0 = Vp[((pk0 >> 1) & 0x1FF)*64 + lane];
      ushort2 a1 = Ub[(size_t)ow1*128 + lane];
      ushort2 g1 = Ub[(size_t)(pk1 >> 10)*128 + 64 + lane];
      float2  v1 = Vp[((pk1 >> 1) & 0x1FF)*64 + lane];
      float sg0 = (pk0 & 1) ? -1.f : 1.f;
      float sg1 = (pk1 & 1) ? -1.f : 1.f;
      float y00 = bf2f(a0.x) + bf2f(g0.x) + sg0*v0.x + b0;
      float y01 = bf2f(a0.y) + bf2f(g0.y) + sg0*v0.y + b1;
      float y10 = bf2f(a1.x) + bf2f(g1.x) + sg1*v1.x + b0;
      float y11 = bf2f(a1.y) + bf2f(g1.y) + sg1*v1.y + b1;
      s0 += y00 + y10;  q0 += y00*y00 + y10*y10;
      s1 += y01 + y11;  q1 += y01*y01 + y11*y11;
    }
    for (; j < n; ++j){
      unsigned ow0 = __shfl(ev.x, j, 64), pk0 = __shfl(ev.y, j, 64);
      ushort2 a0 = Ub[(size_t)ow0*128 + lane];
      ushort2 g0 = Ub[(size_t)(pk0 >> 10)*128 + 64 + lane];
      float2  v0 = Vp[((pk0 >> 1) & 0x1FF)*64 + lane];
      float sg0 = (pk0 & 1) ? -1.f : 1.f;
      float y00 = bf2f(a0.x) + bf2f(g0.x) + sg0*v0.x + b0;
      float y01 = bf2f(a0.y) + bf2f(g0.y) + sg0*v0.y + b1;
      s0 += y00;  q0 += y00*y00;
      s1 += y01;  q1 += y01*y01;
    }
  }
  __shared__ float sred[4][128], qred[4][128];
  sred[w][c0] = s0; sred[w][c1] = s1;
  qred[w][c0] = q0; qred[w][c1] = q1;
  __syncthreads();
  int t = threadIdx.x;
  if (t < 128){
    atomAddF(&colsum[t],   sred[0][t] + sred[1][t] + sred[2][t] + sred[3][t]);
    atomAddF(&colsumsq[t], qred[0][t] + qred[1][t] + qred[2][t] + qred[3][t]);
  }
}

// ---------------- K8: BN1 fold + a2 fold + pbsb ----------------
__global__ void k_bn1fin(const float* __restrict__ colsum, const float* __restrict__ colsumsq,
                         const float* __restrict__ bn1g, const float* __restrict__ bn1b,
                         const float* __restrict__ a2w, const float* __restrict__ a2b,
                         const float* __restrict__ biasv,
                         float* __restrict__ A1, float* __restrict__ B1,
                         float* __restrict__ a2A, float* __restrict__ sbase){
  int j = threadIdx.x;
  float mean = colsum[j] / TWO_NF;
  float var  = colsumsq[j] / TWO_NF - mean*mean;
  float A = rsqrtf(var + 1e-5f) * bn1g[j];
  float B = bn1b[j] - mean*A;
  A1[j] = A; B1[j] = B;
  float w2 = a2w[j];
  float aA = w2*A;
  a2A[j] = aA;
  __shared__ float sm[128], sm2[128];
  sm[j] = w2*B; sm2[j] = biasv[j]*aA;
  __syncthreads();
  for (int s = 64; s > 0; s >>= 1){
    if (j < s){ sm[j] += sm[j+s]; sm2[j] += sm2[j+s]; }
    __syncthreads();
  }
  if (j == 0){
    float sb = a2b[0] + sm[0];
    sbase[0] = sb;
    sbase[1] = sb + sm2[0];   // pbsb = dot(bias,a2A) + sbase
  }
}

// ---------------- K8b: per-entity score scalars sigma0/sigma1 ----------------
__global__ __launch_bounds__(256) void k_sigma(const unsigned short* __restrict__ U,
                                               const float* __restrict__ a2A,
                                               float* __restrict__ sig){
  int lane = threadIdx.x & 63;
  int e = blockIdx.x*4 + (threadIdx.x>>6);
  if (e >= NE) return;
  const uint2* Ur = (const uint2*)U;
  uint2 r = Ur[(size_t)e*64 + lane];
  int c = (lane & 31)*4;
  float4 w = *(const float4*)&a2A[c];
  float p = bf2f_lo(r.x)*w.x + bf2f_hi(r.x)*w.y + bf2f_lo(r.y)*w.z + bf2f_hi(r.y)*w.w;
  p += __shfl_xor(p, 1, 64); p += __shfl_xor(p, 2, 64); p += __shfl_xor(p, 4, 64);
  p += __shfl_xor(p, 8, 64); p += __shfl_xor(p, 16, 64);
  if ((lane & 31) == 0) sig[2*e + (lane >> 5)] = p;
}

// ---------------- K8c: per-relation score scalar rho ----------------
__global__ __launch_bounds__(256) void k_rho(const float* __restrict__ V,
                                             const float* __restrict__ a2A,
                                             float* __restrict__ rho){
  int lane = threadIdx.x & 63;
  int k = blockIdx.x*4 + (threadIdx.x>>6);
  if (k >= NR) return;
  const float2* Vp = (const float2*)V;
  float2 v = Vp[(size_t)k*64 + lane];
  int c0 = 2*lane;
  float p = v.x*a2A[c0] + v.y*a2A[c0+1];
  p = wredsum(p);
  if (lane == 0) rho[k] = p;
}

// ---------------- K9: entity gather — lane-parallel scores + FMA stream ----------------
__global__ __launch_bounds__(256) void k_gent(const uint2* __restrict__ evE, const int* __restrict__ offE,
                   const unsigned short* __restrict__ U, const float* __restrict__ V,
                   const float* __restrict__ sig, const float* __restrict__ rho,
                   const float* __restrict__ bias,
                   const float* __restrict__ A1, const float* __restrict__ B1,
                   const float* __restrict__ sbase,
                   float* __restrict__ out){
  int lane = threadIdx.x & 63;
  int e = blockIdx.x*4 + (threadIdx.x>>6);
  if (e >= NE) return;
  int c0 = 2*lane, c1 = c0+1;
  const ushort2* Ub = (const ushort2*)U;
  const float2*  Vp = (const float2*)V;
  ushort2 u0 = Ub[(size_t)e*128 + lane];
  float base0 = bf2f(u0.x) + bias[c0], base1 = bf2f(u0.y) + bias[c1];
  float pb  = sbase[1];
  float s0e = sig[2*e];
  float accU0=0.f, accU1=0.f, accV0=0.f, accV1=0.f, sep=0.f;
  int p0 = offE[e], p1 = offE[e+1];
  for (int bs = p0; bs < p1; bs += 64){
    int n = min(64, p1 - bs);
    unsigned ev = 0u; float ebl = 0.f;
    if (bs + lane < p1){
      ev = evE[bs + lane].y;
      int oth = ev >> 10, rl = (ev >> 1) & 0x1FF;
      float sg = (ev & 1) ? -1.f : 1.f;
      float s = s0e + sig[2*oth + 1] + sg*rho[rl] + pb;
      float bb = (s >= 0.f) ? -s : -0.01f*s;
      ebl = expf(bb);
    }
    sep += ebl;
    int j = 0;
    for (; j + 2 <= n; j += 2){
      unsigned e0 = __shfl(ev, j, 64);
      unsigned e1 = __shfl(ev, j+1, 64);
      float eb0 = __shfl(ebl, j, 64);
      float eb1 = __shfl(ebl, j+1, 64);
      ushort2 g0 = Ub[(size_t)(e0 >> 10)*128 + 64 + lane];
      ushort2 g1 = Ub[(size_t)(e1 >> 10)*128 + 64 + lane];
      float2 v0 = Vp[((e0 >> 1) & 0x1FF)*64 + lane];
      float2 v1 = Vp[((e1 >> 1) & 0x1FF)*64 + lane];
      float w0 = (e0 & 1) ? -eb0 : eb0;
      float w1 = (e1 & 1) ? -eb1 : eb1;
      accU0 += eb0*bf2f(g0.x); accU1 += eb0*bf2f(g0.y);
      accV0 += w0*v0.x;        accV1 += w0*v0.y;
      accU0 += eb1*bf2f(g1.x); accU1 += eb1*bf2f(g1.y);
      accV0 += w1*v1.x;        accV1 += w1*v1.y;
    }
    for (; j < n; ++j){
      unsigned e0 = __shfl(ev, j, 64);
      float eb0 = __shfl(ebl, j, 64);
      ushort2 g0 = Ub[(size_t)(e0 >> 10)*128 + 64 + lane];
      float2 v0 = Vp[((e0 >> 1) & 0x1FF)*64 + lane];
      float w0 = (e0 & 1) ? -eb0 : eb0;
      accU0 += eb0*bf2f(g0.x); accU1 += eb0*bf2f(g0.y);
      accV0 += w0*v0.x;        accV1 += w0*v0.y;
    }
  }
  float se = wredsum(sep);
  float sY0 = se*base0 + accU0 + accV0;
  float sY1 = se*base1 + accU1 + accV1;
  float hs0 = A1[c0]*sY0 + B1[c0]*se;
  float hs1 = A1[c1]*sY1 + B1[c1]*se;
  float d = (se == 0.f) ? 1e-12f : se;
  out[(size_t)e*DD + c0] = hs0/d;
  out[(size_t)e*DD + c1] = hs1/d;
}

// ---------------- K10: relation gather — lane-parallel scores + FMA stream ----------------
__global__ __launch_bounds__(256) void k_grel(const uint2* __restrict__ evR, const int* __restrict__ offR,
                   const unsigned short* __restrict__ U, const float* __restrict__ V,
                   const float* __restrict__ sig, const float* __restrict__ rho,
                   const float* __restrict__ bias,
                   const float* __restrict__ A1, const float* __restrict__ B1,
                   const float* __restrict__ sbase,
                   float* __restrict__ out){
  int lane = threadIdx.x & 63;
  int k = blockIdx.x >> 3;
  int wvs = (blockIdx.x & 7)*4 + (threadIdx.x >> 6);   // 0..31
  int c0 = 2*lane, c1 = c0+1;
  const ushort2* Ub = (const ushort2*)U;
  const float2*  Vp = (const float2*)V;
  float2 v = Vp[(size_t)k*64 + lane];
  float vb0 = v.x + bias[c0], vb1 = v.y + bias[c1];
  float rpb = rho[k] + sbase[1];
  float accY0=0.f, accY1=0.f, sep=0.f;
  int p0 = offR[k], p1 = offR[k+1];
  int tot = p1 - p0, per = (tot + 31) >> 5;
  int st = p0 + wvs*per, en = min(st + per, p1);
  for (int bs = st; bs < en; bs += 64){
    int n = min(64, en - bs);
    uint2 ev = make_uint2(0u, 0u); float ebl = 0.f;
    if (bs + lane < en){
      ev = evR[bs + lane];
      float s = sig[2*ev.x] + sig[2*ev.y + 1] + rpb;
      float bb = (s >= 0.f) ? -s : -0.01f*s;
      ebl = expf(bb);
    }
    sep += ebl;
    int j = 0;
    for (; j + 2 <= n; j += 2){
      unsigned a0 = __shfl(ev.x, j, 64),   d0 = __shfl(ev.y, j, 64);
      unsigned a1 = __shfl(ev.x, j+1, 64), d1 = __shfl(ev.y, j+1, 64);
      float eb0 = __shfl(ebl, j, 64);
      float eb1 = __shfl(ebl, j+1, 64);
      ushort2 ua0 = Ub[(size_t)a0*128 + lane];
      ushort2 ud0 = Ub[(size_t)d0*128 + 64 + lane];
      ushort2 ua1 = Ub[(size_t)a1*128 + lane];
      ushort2 ud1 = Ub[(size_t)d1*128 + 64 + lane];
      accY0 += eb0*(bf2f(ua0.x) + bf2f(ud0.x));
      accY1 += eb0*(bf2f(ua0.y) + bf2f(ud0.y));
      accY0 += eb1*(bf2f(ua1.x) + bf2f(ud1.x));
      accY1 += eb1*(bf2f(ua1.y) + bf2f(ud1.y));
    }
    for (; j < n; ++j){
      unsigned a0 = __shfl(ev.x, j, 64), d0 = __shfl(ev.y, j, 64);
      float eb0 = __shfl(ebl, j, 64);
      ushort2 ua0 = Ub[(size_t)a0*128 + lane];
      ushort2 ud0 = Ub[(size_t)d0*128 + 64 + lane];
      accY0 += eb0*(bf2f(ua0.x) + bf2f(ud0.x));
      accY1 += eb0*(bf2f(ua0.y) + bf2f(ud0.y));
    }
  }
  float se = wredsum(sep);
  float sY0 = accY0 + se*vb0;
  float sY1 = accY1 + se*vb1;
  float r0 = A1[c0]*sY0 + B1[c0]*se;
  float r1 = A1[c1]*sY1 + B1[c1]*se;
  atomAddF(&out[(size_t)RELOFF + (size_t)k*DD + c0], r0);
  atomAddF(&out[(size_t)RELOFF + (size_t)k*DD + c1], r1);
}

// ---------------- K11: finalize rel division ----------------
__global__ void k_fin_rel(float* __restrict__ out, const int* __restrict__ cntR){
  int idx = blockIdx.x*blockDim.x + threadIdx.x;   // NR*DD threads
  int k = idx >> 7;
  float c = fmaxf((float)cntR[k], 1.f);
  out[RELOFF + idx] = out[RELOFF + idx] / c;
}

extern "C" void kernel_launch(void* const* d_in, const int* in_sizes, int n_in,
                              void* d_out, int out_size, void* d_ws, size_t ws_size,
                              hipStream_t stream) {
  (void)in_sizes; (void)n_in; (void)ws_size; (void)out_size;
  const int*   trip = (const int*)  d_in[0];
  const float* ent  = (const float*)d_in[1];
  const float* rel  = (const float*)d_in[2];
  const float* aw   = (const float*)d_in[3];
  const float* ab   = (const float*)d_in[4];
  const float* a2w  = (const float*)d_in[5];
  const float* a2b  = (const float*)d_in[6];
  const float* bn0g = (const float*)d_in[7];
  const float* bn0b = (const float*)d_in[8];
  const float* bn1g = (const float*)d_in[9];
  const float* bn1b = (const float*)d_in[10];
  float* out = (float*)d_out;

  char* w = (char*)d_ws;
  size_t off = 0;
  auto take = [&](size_t bytes) -> char* {
    char* p = w + off;
    off = (off + bytes + 511) & ~(size_t)511;
    return p;
  };
  // zeroed region (accumulators)
  float* S        = (float*)take(512);
  float* Q        = (float*)take(512);
  float* colsum   = (float*)take(512);
  float* colsumsq = (float*)take(512);
  int*   cnt      = (int*)  take((size_t)NE*4);
  int*   cntR     = (int*)  take((size_t)NR*4);
  size_t zero_end = off;
  // non-zeroed (fully overwritten each launch)
  float* alpha0 = (float*)take(512);
  float* alpha1 = (float*)take(512);
  float* alpha2 = (float*)take(512);
  float* beta0  = (float*)take(512);
  float* beta1  = (float*)take(512);
  float* biasv  = (float*)take(512);
  float* A1     = (float*)take(512);
  float* B1     = (float*)take(512);
  float* a2A    = (float*)take(512);
  float* sbase  = (float*)take(512);
  float* rho    = (float*)take((size_t)NR*4);
  float* sig    = (float*)take((size_t)NE*2*4);
  int*   offE   = (int*)  take((size_t)(NE+1)*4);
  int*   curE   = (int*)  take((size_t)NE*4);
  int*   offR   = (int*)  take((size_t)(NR+1)*4);
  int*   curR   = (int*)  take((size_t)NR*4);
  uint2* evE    = (uint2*)take((size_t)NEV*8);
  uint2* evR    = (uint2*)take((size_t)NT*8);
  float* V      = (float*)take((size_t)NR*DD*4);
  unsigned short* Wt = (unsigned short*)take((size_t)128*256*2);
  unsigned short* U  = (unsigned short*)take((size_t)NE*256*2);

  hipMemsetAsync((char*)d_out + (size_t)RELOFF*4, 0, (size_t)NR*DD*4, stream);
  hipMemsetAsync(d_ws, 0, zero_end, stream);

  k_count    <<<(NT+255)/256, 256, 0, stream>>>(trip, cnt, cntR);
  k_scan_ent <<<1, 1024, 0, stream>>>(cnt, offE, curE);
  k_scan_rel <<<1, 512, 0, stream>>>(cntR, offR, curR);
  k_scatter  <<<(NT+255)/256, 256, 0, stream>>>(trip, curE, curR, evE, evR);
  k_entstats <<<(NE+127)/128, 256, 0, stream>>>(ent, cnt, S, Q);
  k_alpha    <<<1, 128, 0, stream>>>(rel, cntR, S, Q, bn0g, bn0b, alpha0, alpha1, alpha2, beta0, beta1);
  k_bias     <<<128, 128, 0, stream>>>(aw, ab, bn0b, beta0, beta1, biasv);
  k_v        <<<NR, 128, 0, stream>>>(rel, aw, alpha2, V);
  k_wfold    <<<128, 256, 0, stream>>>(aw, alpha0, alpha1, Wt);
  k_u        <<<NE/32, 256, 0, stream>>>(ent, Wt, U);
  k_c1b      <<<2048, 256, 0, stream>>>(evE, U, V, biasv, colsum, colsumsq);
  k_bn1fin   <<<1, 128, 0, stream>>>(colsum, colsumsq, bn1g, bn1b, a2w, a2b, biasv, A1, B1, a2A, sbase);
  k_sigma    <<<NE/4, 256, 0, stream>>>(U, a2A, sig);
  k_rho      <<<(NR+3)/4, 256, 0, stream>>>(V, a2A, rho);
  k_gent     <<<NE/4, 256, 0, stream>>>(evE, offE, U, V, sig, rho, biasv, A1, B1, sbase, out);
  k_grel     <<<NR*8, 256, 0, stream>>>(evR, offR, U, V, sig, rho, biasv, A1, B1, sbase, out);
  k_fin_rel  <<<(NR*DD)/256, 256, 0, stream>>>(out, cntR);
}

// Round 6
// 615.774 us; speedup vs baseline: 3.5506x; 1.0562x over previous
//
#include <hip/hip_runtime.h>
#include <hip/hip_bf16.h>

#define NE 100000
#define NR 500
#define DD 128
#define NT 250000
#define NEV 500000             // 2*NT events
#define RELOFF 12800000        // NE*DD
#define TWO_NF 500000.0f
#define NTF 250000.0f

typedef __attribute__((ext_vector_type(8))) short short8;
typedef __attribute__((ext_vector_type(4))) float f32x4;

__device__ __forceinline__ float bf2f(unsigned short u){
  unsigned int x = ((unsigned int)u) << 16;
  return __uint_as_float(x);
}
__device__ __forceinline__ float bf2f_lo(unsigned int u){ return __uint_as_float(u << 16); }
__device__ __forceinline__ float bf2f_hi(unsigned int u){ return __uint_as_float(u & 0xFFFF0000u); }
__device__ __forceinline__ unsigned short f2bf(float f){
  __hip_bfloat16 h = __float2bfloat16(f);
  return *reinterpret_cast<unsigned short*>(&h);
}
__device__ __forceinline__ void atomAddF(float* p, float v){ unsafeAtomicAdd(p, v); }
__device__ __forceinline__ float wredsum(float x){
  x += __shfl_xor(x, 1, 64);  x += __shfl_xor(x, 2, 64);  x += __shfl_xor(x, 4, 64);
  x += __shfl_xor(x, 8, 64);  x += __shfl_xor(x, 16, 64); x += __shfl_xor(x, 32, 64);
  return x;
}

// ---------------- K1: entity / relation counts ----------------
__global__ void k_count(const int* __restrict__ trip, int* __restrict__ cnt, int* __restrict__ cntR){
  int i = blockIdx.x*blockDim.x + threadIdx.x;
  if (i < NT){
    atomicAdd(&cnt[trip[3*i+0]], 1);
    atomicAdd(&cnt[trip[3*i+1]], 1);
    atomicAdd(&cntR[trip[3*i+2]], 1);
  }
}

// ---------------- scan: entity offsets (wave-shuffle) ----------------
__global__ __launch_bounds__(1024) void k_scan_ent(const int* __restrict__ cnt,
                                                   int* __restrict__ off, int* __restrict__ cur){
  __shared__ int wsum[16];
  __shared__ int carrysh;
  int t = threadIdx.x, lane = t & 63, w = t >> 6;
  if (t == 0) carrysh = 0;
  __syncthreads();
  for (int base = 0; base < NE; base += 1024){
    int v = (base + t < NE) ? cnt[base + t] : 0;
    int x = v;
    #pragma unroll
    for (int s = 1; s < 64; s <<= 1){ int y = __shfl_up(x, s, 64); if (lane >= s) x += y; }
    if (lane == 63) wsum[w] = x;
    __syncthreads();
    if (w == 0 && lane < 16){
      int xs = wsum[lane];
      #pragma unroll
      for (int s = 1; s < 16; s <<= 1){ int y = __shfl_up(xs, s, 16); if ((lane & 15) >= s) xs += y; }
      wsum[lane] = xs;
    }
    __syncthreads();
    int wprev = (w == 0) ? 0 : wsum[w-1];
    int total = wsum[15];
    int c = carrysh;
    if (base + t < NE){
      int ex = c + wprev + x - v;
      off[base + t] = ex;
      cur[base + t] = ex;
    }
    __syncthreads();
    if (t == 0) carrysh = c + total;
  }
  if (t == 0) off[NE] = carrysh;
}

// ---------------- scan: relation offsets ----------------
__global__ __launch_bounds__(512) void k_scan_rel(const int* __restrict__ cntR,
                                                  int* __restrict__ offR, int* __restrict__ curR){
  __shared__ int sm[512];
  int t = threadIdx.x;
  int v = (t < NR) ? cntR[t] : 0;
  sm[t] = v; __syncthreads();
  for (int s = 1; s < 512; s <<= 1){
    int x = (t >= s) ? sm[t - s] : 0;
    __syncthreads();
    sm[t] += x; __syncthreads();
  }
  if (t < NR){ int ex = sm[t] - v; offR[t] = ex; curR[t] = ex; }
  if (t == 0) offR[NR] = sm[NR-1];
}

// ---------------- scatter events into CSR ----------------
// ent event: x = owner, y = other<<10 | rel<<1 | bwdflag (bwd => -V)
__global__ void k_scatter(const int* __restrict__ trip, int* __restrict__ curE, int* __restrict__ curR,
                          uint2* __restrict__ evE, uint2* __restrict__ evR){
  int i = blockIdx.x*blockDim.x + threadIdx.x;
  if (i < NT){
    int t0 = trip[3*i+0], t1 = trip[3*i+1], t2 = trip[3*i+2];
    int p0 = atomicAdd(&curE[t0], 1);
    evE[p0] = make_uint2((unsigned)t0, ((unsigned)t1 << 10) | ((unsigned)t2 << 1));
    int p1 = atomicAdd(&curE[t1], 1);
    evE[p1] = make_uint2((unsigned)t1, ((unsigned)t0 << 10) | ((unsigned)t2 << 1) | 1u);
    int p2 = atomicAdd(&curR[t2], 1);
    evR[p2] = make_uint2((unsigned)t0, (unsigned)t1);
  }
}

// ---------------- K2: count-weighted entity column stats ----------------
__global__ __launch_bounds__(256) void k_entstats(const float* __restrict__ ent, const int* __restrict__ cnt,
                                                  float* __restrict__ S, float* __restrict__ Q){
  int j = threadIdx.x & 127;
  int half = threadIdx.x >> 7;
  int r0 = blockIdx.x*128 + half;
  int r1 = min(blockIdx.x*128 + 128, NE);
  float s = 0.f, q = 0.f;
  for (int r = r0; r < r1; r += 2){
    int w = cnt[r];
    if (w){
      float x = ent[(size_t)r*DD + j];
      float wf = (float)w;
      s += wf*x; q += wf*x*x;
    }
  }
  __shared__ float ss[256], qq[256];
  ss[threadIdx.x] = s; qq[threadIdx.x] = q; __syncthreads();
  if (half == 0){
    atomAddF(&S[j], ss[j] + ss[j+128]);
    atomAddF(&Q[j], qq[j] + qq[j+128]);
  }
}

// ---------------- K3: BN0 fold + rel variance ----------------
__global__ void k_alpha(const float* __restrict__ rel, const int* __restrict__ cntR,
                        const float* __restrict__ S, const float* __restrict__ Q,
                        const float* __restrict__ bn0g, const float* __restrict__ bn0b,
                        float* __restrict__ alpha0, float* __restrict__ alpha1, float* __restrict__ alpha2,
                        float* __restrict__ beta0, float* __restrict__ beta1){
  int j = threadIdx.x;
  float qr = 0.f;
  for (int k = 0; k < NR; ++k){
    float w = (float)cntR[k];
    float x = rel[k*DD + j];
    qr += w*x*x;
  }
  float mean = S[j] / TWO_NF;
  float var  = Q[j] / TWO_NF - mean*mean;
  float inv  = rsqrtf(var + 1e-5f);
  float a0 = inv * bn0g[j];
  float a1 = inv * bn0g[128+j];
  alpha0[j] = a0; alpha1[j] = a1;
  beta0[j] = bn0b[j]     - mean*a0;
  beta1[j] = bn0b[128+j] - mean*a1;
  float varR = qr / NTF;
  alpha2[j] = rsqrtf(varR + 1e-5f) * bn0g[256+j];
}

// ---------------- K4: folded bias vector ----------------
__global__ void k_bias(const float* __restrict__ aw, const float* __restrict__ ab,
                       const float* __restrict__ bn0b,
                       const float* __restrict__ beta0, const float* __restrict__ beta1,
                       float* __restrict__ bias){
  int o = blockIdx.x, j = threadIdx.x;
  const float* r = aw + (size_t)o*384;
  float p = r[j]*beta0[j] + r[128+j]*beta1[j] + r[256+j]*bn0b[256+j];
  __shared__ float sm[128];
  sm[j] = p; __syncthreads();
  for (int s = 64; s > 0; s >>= 1){ if (j < s) sm[j] += sm[j+s]; __syncthreads(); }
  if (j == 0) bias[o] = ab[o] + sm[0];
}

// ---------------- K5: V table ----------------
__global__ void k_v(const float* __restrict__ rel, const float* __restrict__ aw,
                    const float* __restrict__ alpha2, float* __restrict__ V){
  int k = blockIdx.x, o = threadIdx.x;
  __shared__ float rl[128];
  rl[o] = rel[k*DD + o] * alpha2[o];
  __syncthreads();
  float acc = 0.f;
  #pragma unroll 8
  for (int j = 0; j < 128; ++j) acc += aw[(size_t)o*384 + 256 + j] * rl[j];
  V[k*DD + o] = acc;
}

// ---------------- K5b: fold W' into bf16 table Wt2[o][k] (B-operand layout) ----------------
__global__ void k_wfold2(const float* __restrict__ aw, const float* __restrict__ alpha0,
                         const float* __restrict__ alpha1, unsigned short* __restrict__ Wt2){
  int o = blockIdx.x;        // 0..255
  int k = threadIdx.x;       // 0..127
  float w;
  if (o < 128) w = aw[(size_t)o*384 + k] * alpha0[k];
  else         w = aw[(size_t)(o-128)*384 + 128 + k] * alpha1[k];
  Wt2[(size_t)o*128 + k] = f2bf(w);
}

// ---------------- K6: U table via MFMA (16x16x32 bf16, X split hi/lo) ----------------
// Wave computes 16 entities x 256 outputs. A = X[e][k] (split bf16), B = Wt2[o][k].
// A-frag: lane l -> A[l&15][8*(l>>4)+j]; B-frag: lane l -> B[8*(l>>4)+j][l&15] = Wt2[o0+(l&15)][...]
// D: lane l -> D[4*(l>>4)+r][l&15].
__global__ __launch_bounds__(256) void k_u2(const float* __restrict__ ent,
                                            const unsigned short* __restrict__ Wt2,
                                            unsigned short* __restrict__ Uo){
  __shared__ unsigned short stg[4][16*264];   // 264-ushort row pitch (bank-spread), 33 KB
  int tid = threadIdx.x;
  int w = tid >> 6, l = tid & 63;
  int col = l & 15, grp = l >> 4, kof = grp*8;
  int e0w = (blockIdx.x*4 + w)*16;           // 1563 blocks * 64 = 100032
  int e = min(e0w + col, NE-1);
  const float* xrow = ent + (size_t)e*DD;

  short8 a_hi0, a_hi1, a_hi2, a_hi3, a_lo0, a_lo1, a_lo2, a_lo3;
  {
    #pragma unroll
    for (int ks = 0; ks < 4; ++ks){
      float4 xa = *(const float4*)(xrow + 32*ks + kof);
      float4 xb = *(const float4*)(xrow + 32*ks + kof + 4);
      float xv[8] = {xa.x, xa.y, xa.z, xa.w, xb.x, xb.y, xb.z, xb.w};
      short8 hi, lo;
      #pragma unroll
      for (int j = 0; j < 8; ++j){
        unsigned short h = f2bf(xv[j]);
        unsigned short r = f2bf(xv[j] - bf2f(h));
        hi[j] = (short)h; lo[j] = (short)r;
      }
      if (ks == 0){ a_hi0 = hi; a_lo0 = lo; }
      else if (ks == 1){ a_hi1 = hi; a_lo1 = lo; }
      else if (ks == 2){ a_hi2 = hi; a_lo2 = lo; }
      else { a_hi3 = hi; a_lo3 = lo; }
    }
  }

  f32x4 acc[16];
  #pragma unroll
  for (int ot = 0; ot < 16; ++ot) acc[ot] = (f32x4){0.f, 0.f, 0.f, 0.f};

  #pragma unroll
  for (int ot = 0; ot < 16; ++ot){
    const unsigned short* bbase = Wt2 + (size_t)(ot*16 + col)*128 + kof;
    short8 b0 = *(const short8*)(bbase);
    short8 b1 = *(const short8*)(bbase + 32);
    short8 b2 = *(const short8*)(bbase + 64);
    short8 b3 = *(const short8*)(bbase + 96);
    acc[ot] = __builtin_amdgcn_mfma_f32_16x16x32_bf16(a_hi0, b0, acc[ot], 0, 0, 0);
    acc[ot] = __builtin_amdgcn_mfma_f32_16x16x32_bf16(a_lo0, b0, acc[ot], 0, 0, 0);
    acc[ot] = __builtin_amdgcn_mfma_f32_16x16x32_bf16(a_hi1, b1, acc[ot], 0, 0, 0);
    acc[ot] = __builtin_amdgcn_mfma_f32_16x16x32_bf16(a_lo1, b1, acc[ot], 0, 0, 0);
    acc[ot] = __builtin_amdgcn_mfma_f32_16x16x32_bf16(a_hi2, b2, acc[ot], 0, 0, 0);
    acc[ot] = __builtin_amdgcn_mfma_f32_16x16x32_bf16(a_lo2, b2, acc[ot], 0, 0, 0);
    acc[ot] = __builtin_amdgcn_mfma_f32_16x16x32_bf16(a_hi3, b3, acc[ot], 0, 0, 0);
    acc[ot] = __builtin_amdgcn_mfma_f32_16x16x32_bf16(a_lo3, b3, acc[ot], 0, 0, 0);
  }

  // stage D fragments to LDS (per-wave region), then coalesced bf16 row stores
  #pragma unroll
  for (int ot = 0; ot < 16; ++ot){
    #pragma unroll
    for (int r = 0; r < 4; ++r){
      stg[w][(grp*4 + r)*264 + ot*16 + col] = f2bf(acc[ot][r]);
    }
  }
  // per-wave LDS: program-order ds ops, compiler inserts lgkm waits
  #pragma unroll
  for (int i = 0; i < 16; ++i){
    if (e0w + i < NE){
      ushort4 v = ((const ushort4*)&stg[w][i*264])[l];
      ((ushort4*)Uo)[(size_t)(e0w + i)*64 + l] = v;
    }
  }
}

// ---------------- K7: BN1 column stats over CSR events ----------------
__global__ __launch_bounds__(256) void k_c1b(const uint2* __restrict__ evE,
                   const unsigned short* __restrict__ U, const float* __restrict__ V,
                   const float* __restrict__ bias,
                   float* __restrict__ colsum, float* __restrict__ colsumsq){
  int lane = threadIdx.x & 63;
  int w = threadIdx.x >> 6;
  int wv = blockIdx.x*4 + w;
  int nwv = gridDim.x*4;
  int per = (NEV + nwv - 1) / nwv;
  int st = wv*per, en = min(st + per, NEV);
  int c0 = 2*lane, c1 = c0+1;
  float b0 = bias[c0], b1 = bias[c1];
  const ushort2* Ub = (const ushort2*)U;
  const float2*  Vp = (const float2*)V;
  float s0=0.f, s1=0.f, q0=0.f, q1=0.f;
  for (int bs = st; bs < en; bs += 64){
    int n = min(64, en - bs);
    uint2 ev = (bs + lane < en) ? evE[bs + lane] : make_uint2(0u, 0u);
    int j = 0;
    for (; j + 2 <= n; j += 2){
      unsigned ow0 = __shfl(ev.x, j, 64),   pk0 = __shfl(ev.y, j, 64);
      unsigned ow1 = __shfl(ev.x, j+1, 64), pk1 = __shfl(ev.y, j+1, 64);
      ushort2 a0 = Ub[(size_t)ow0*128 + lane];
      ushort2 g0 = Ub[(size_t)(pk0 >> 10)*128 + 64 + lane];
      float2  v0 = Vp[((pk0 >> 1) & 0x1FF)*64 + lane];
      ushort2 a1 = Ub[(size_t)ow1*128 + lane];
      ushort2 g1 = Ub[(size_t)(pk1 >> 10)*128 + 64 + lane];
      float2  v1 = Vp[((pk1 >> 1) & 0x1FF)*64 + lane];
      float sg0 = (pk0 & 1) ? -1.f : 1.f;
      float sg1 = (pk1 & 1) ? -1.f : 1.f;
      float y00 = bf2f(a0.x) + bf2f(g0.x) + sg0*v0.x + b0;
      float y01 = bf2f(a0.y) + bf2f(g0.y) + sg0*v0.y + b1;
      float y10 = bf2f(a1.x) + bf2f(g1.x) + sg1*v1.x + b0;
      float y11 = bf2f(a1.y) + bf2f(g1.y) + sg1*v1.y + b1;
      s0 += y00 + y10;  q0 += y00*y00 + y10*y10;
      s1 += y01 + y11;  q1 += y01*y01 + y11*y11;
    }
    for (; j < n; ++j){
      unsigned ow0 = __shfl(ev.x, j, 64), pk0 = __shfl(ev.y, j, 64);
      ushort2 a0 = Ub[(size_t)ow0*128 + lane];
      ushort2 g0 = Ub[(size_t)(pk0 >> 10)*128 + 64 + lane];
      float2  v0 = Vp[((pk0 >> 1) & 0x1FF)*64 + lane];
      float sg0 = (pk0 & 1) ? -1.f : 1.f;
      float y00 = bf2f(a0.x) + bf2f(g0.x) + sg0*v0.x + b0;
      float y01 = bf2f(a0.y) + bf2f(g0.y) + sg0*v0.y + b1;
      s0 += y00;  q0 += y00*y00;
      s1 += y01;  q1 += y01*y01;
    }
  }
  __shared__ float sred[4][128], qred[4][128];
  sred[w][c0] = s0; sred[w][c1] = s1;
  qred[w][c0] = q0; qred[w][c1] = q1;
  __syncthreads();
  int t = threadIdx.x;
  if (t < 128){
    atomAddF(&colsum[t],   sred[0][t] + sred[1][t] + sred[2][t] + sred[3][t]);
    atomAddF(&colsumsq[t], qred[0][t] + qred[1][t] + qred[2][t] + qred[3][t]);
  }
}

// ---------------- K8: BN1 fold + a2 fold + pbsb ----------------
__global__ void k_bn1fin(const float* __restrict__ colsum, const float* __restrict__ colsumsq,
                         const float* __restrict__ bn1g, const float* __restrict__ bn1b,
                         const float* __restrict__ a2w, const float* __restrict__ a2b,
                         const float* __restrict__ biasv,
                         float* __restrict__ A1, float* __restrict__ B1,
                         float* __restrict__ a2A, float* __restrict__ sbase){
  int j = threadIdx.x;
  float mean = colsum[j] / TWO_NF;
  float var  = colsumsq[j] / TWO_NF - mean*mean;
  float A = rsqrtf(var + 1e-5f) * bn1g[j];
  float B = bn1b[j] - mean*A;
  A1[j] = A; B1[j] = B;
  float w2 = a2w[j];
  float aA = w2*A;
  a2A[j] = aA;
  __shared__ float sm[128], sm2[128];
  sm[j] = w2*B; sm2[j] = biasv[j]*aA;
  __syncthreads();
  for (int s = 64; s > 0; s >>= 1){
    if (j < s){ sm[j] += sm[j+s]; sm2[j] += sm2[j+s]; }
    __syncthreads();
  }
  if (j == 0){
    float sb = a2b[0] + sm[0];
    sbase[0] = sb;
    sbase[1] = sb + sm2[0];   // pbsb = dot(bias,a2A) + sbase
  }
}

// ---------------- K8b: per-entity score scalars sigma0/sigma1 ----------------
__global__ __launch_bounds__(256) void k_sigma(const unsigned short* __restrict__ U,
                                               const float* __restrict__ a2A,
                                               float* __restrict__ sig){
  int lane = threadIdx.x & 63;
  int e = blockIdx.x*4 + (threadIdx.x>>6);
  if (e >= NE) return;
  const uint2* Ur = (const uint2*)U;
  uint2 r = Ur[(size_t)e*64 + lane];
  int c = (lane & 31)*4;
  float4 w = *(const float4*)&a2A[c];
  float p = bf2f_lo(r.x)*w.x + bf2f_hi(r.x)*w.y + bf2f_lo(r.y)*w.z + bf2f_hi(r.y)*w.w;
  p += __shfl_xor(p, 1, 64); p += __shfl_xor(p, 2, 64); p += __shfl_xor(p, 4, 64);
  p += __shfl_xor(p, 8, 64); p += __shfl_xor(p, 16, 64);
  if ((lane & 31) == 0) sig[2*e + (lane >> 5)] = p;
}

// ---------------- K8c: per-relation score scalar rho ----------------
__global__ __launch_bounds__(256) void k_rho(const float* __restrict__ V,
                                             const float* __restrict__ a2A,
                                             float* __restrict__ rho){
  int lane = threadIdx.x & 63;
  int k = blockIdx.x*4 + (threadIdx.x>>6);
  if (k >= NR) return;
  const float2* Vp = (const float2*)V;
  float2 v = Vp[(size_t)k*64 + lane];
  int c0 = 2*lane;
  float p = v.x*a2A[c0] + v.y*a2A[c0+1];
  p = wredsum(p);
  if (lane == 0) rho[k] = p;
}

// ---------------- K9: entity gather — lane-parallel scores + FMA stream ----------------
__global__ __launch_bounds__(256) void k_gent(const uint2* __restrict__ evE, const int* __restrict__ offE,
                   const unsigned short* __restrict__ U, const float* __restrict__ V,
                   const float* __restrict__ sig, const float* __restrict__ rho,
                   const float* __restrict__ bias,
                   const float* __restrict__ A1, const float* __restrict__ B1,
                   const float* __restrict__ sbase,
                   float* __restrict__ out){
  int lane = threadIdx.x & 63;
  int e = blockIdx.x*4 + (threadIdx.x>>6);
  if (e >= NE) return;
  int c0 = 2*lane, c1 = c0+1;
  const ushort2* Ub = (const ushort2*)U;
  const float2*  Vp = (const float2*)V;
  ushort2 u0 = Ub[(size_t)e*128 + lane];
  float base0 = bf2f(u0.x) + bias[c0], base1 = bf2f(u0.y) + bias[c1];
  float pb  = sbase[1];
  float s0e = sig[2*e];
  float accU0=0.f, accU1=0.f, accV0=0.f, accV1=0.f, sep=0.f;
  int p0 = offE[e], p1 = offE[e+1];
  for (int bs = p0; bs < p1; bs += 64){
    int n = min(64, p1 - bs);
    unsigned ev = 0u; float ebl = 0.f;
    if (bs + lane < p1){
      ev = evE[bs + lane].y;
      int oth = ev >> 10, rl = (ev >> 1) & 0x1FF;
      float sg = (ev & 1) ? -1.f : 1.f;
      float s = s0e + sig[2*oth + 1] + sg*rho[rl] + pb;
      float bb = (s >= 0.f) ? -s : -0.01f*s;
      ebl = expf(bb);
    }
    sep += ebl;
    int j = 0;
    for (; j + 2 <= n; j += 2){
      unsigned e0 = __shfl(ev, j, 64);
      unsigned e1 = __shfl(ev, j+1, 64);
      float eb0 = __shfl(ebl, j, 64);
      float eb1 = __shfl(ebl, j+1, 64);
      ushort2 g0 = Ub[(size_t)(e0 >> 10)*128 + 64 + lane];
      ushort2 g1 = Ub[(size_t)(e1 >> 10)*128 + 64 + lane];
      float2 v0 = Vp[((e0 >> 1) & 0x1FF)*64 + lane];
      float2 v1 = Vp[((e1 >> 1) & 0x1FF)*64 + lane];
      float w0 = (e0 & 1) ? -eb0 : eb0;
      float w1 = (e1 & 1) ? -eb1 : eb1;
      accU0 += eb0*bf2f(g0.x); accU1 += eb0*bf2f(g0.y);
      accV0 += w0*v0.x;        accV1 += w0*v0.y;
      accU0 += eb1*bf2f(g1.x); accU1 += eb1*bf2f(g1.y);
      accV0 += w1*v1.x;        accV1 += w1*v1.y;
    }
    for (; j < n; ++j){
      unsigned e0 = __shfl(ev, j, 64);
      float eb0 = __shfl(ebl, j, 64);
      ushort2 g0 = Ub[(size_t)(e0 >> 10)*128 + 64 + lane];
      float2 v0 = Vp[((e0 >> 1) & 0x1FF)*64 + lane];
      float w0 = (e0 & 1) ? -eb0 : eb0;
      accU0 += eb0*bf2f(g0.x); accU1 += eb0*bf2f(g0.y);
      accV0 += w0*v0.x;        accV1 += w0*v0.y;
    }
  }
  float se = wredsum(sep);
  float sY0 = se*base0 + accU0 + accV0;
  float sY1 = se*base1 + accU1 + accV1;
  float hs0 = A1[c0]*sY0 + B1[c0]*se;
  float hs1 = A1[c1]*sY1 + B1[c1]*se;
  float d = (se == 0.f) ? 1e-12f : se;
  out[(size_t)e*DD + c0] = hs0/d;
  out[(size_t)e*DD + c1] = hs1/d;
}

// ---------------- K10: relation gather — lane-parallel scores + FMA stream ----------------
__global__ __launch_bounds__(256) void k_grel(const uint2* __restrict__ evR, const int* __restrict__ offR,
                   const unsigned short* __restrict__ U, const float* __restrict__ V,
                   const float* __restrict__ sig, const float* __restrict__ rho,
                   const float* __restrict__ bias,
                   const float* __restrict__ A1, const float* __restrict__ B1,
                   const float* __restrict__ sbase,
                   float* __restrict__ out){
  int lane = threadIdx.x & 63;
  int k = blockIdx.x >> 3;
  int wvs = (blockIdx.x & 7)*4 + (threadIdx.x >> 6);   // 0..31
  int c0 = 2*lane, c1 = c0+1;
  const ushort2* Ub = (const ushort2*)U;
  const float2*  Vp = (const float2*)V;
  float2 v = Vp[(size_t)k*64 + lane];
  float vb0 = v.x + bias[c0], vb1 = v.y + bias[c1];
  float rpb = rho[k] + sbase[1];
  float accY0=0.f, accY1=0.f, sep=0.f;
  int p0 = offR[k], p1 = offR[k+1];
  int tot = p1 - p0, per = (tot + 31) >> 5;
  int st = p0 + wvs*per, en = min(st + per, p1);
  for (int bs = st; bs < en; bs += 64){
    int n = min(64, en - bs);
    uint2 ev = make_uint2(0u, 0u); float ebl = 0.f;
    if (bs + lane < en){
      ev = evR[bs + lane];
      float s = sig[2*ev.x] + sig[2*ev.y + 1] + rpb;
      float bb = (s >= 0.f) ? -s : -0.01f*s;
      ebl = expf(bb);
    }
    sep += ebl;
    int j = 0;
    for (; j + 2 <= n; j += 2){
      unsigned a0 = __shfl(ev.x, j, 64),   d0 = __shfl(ev.y, j, 64);
      unsigned a1 = __shfl(ev.x, j+1, 64), d1 = __shfl(ev.y, j+1, 64);
      float eb0 = __shfl(ebl, j, 64);
      float eb1 = __shfl(ebl, j+1, 64);
      ushort2 ua0 = Ub[(size_t)a0*128 + lane];
      ushort2 ud0 = Ub[(size_t)d0*128 + 64 + lane];
      ushort2 ua1 = Ub[(size_t)a1*128 + lane];
      ushort2 ud1 = Ub[(size_t)d1*128 + 64 + lane];
      accY0 += eb0*(bf2f(ua0.x) + bf2f(ud0.x));
      accY1 += eb0*(bf2f(ua0.y) + bf2f(ud0.y));
      accY0 += eb1*(bf2f(ua1.x) + bf2f(ud1.x));
      accY1 += eb1*(bf2f(ua1.y) + bf2f(ud1.y));
    }
    for (; j < n; ++j){
      unsigned a0 = __shfl(ev.x, j, 64), d0 = __shfl(ev.y, j, 64);
      float eb0 = __shfl(ebl, j, 64);
      ushort2 ua0 = Ub[(size_t)a0*128 + lane];
      ushort2 ud0 = Ub[(size_t)d0*128 + 64 + lane];
      accY0 += eb0*(bf2f(ua0.x) + bf2f(ud0.x));
      accY1 += eb0*(bf2f(ua0.y) + bf2f(ud0.y));
    }
  }
  float se = wredsum(sep);
  float sY0 = accY0 + se*vb0;
  float sY1 = accY1 + se*vb1;
  float r0 = A1[c0]*sY0 + B1[c0]*se;
  float r1 = A1[c1]*sY1 + B1[c1]*se;
  atomAddF(&out[(size_t)RELOFF + (size_t)k*DD + c0], r0);
  atomAddF(&out[(size_t)RELOFF + (size_t)k*DD + c1], r1);
}

// ---------------- K11: finalize rel division ----------------
__global__ void k_fin_rel(float* __restrict__ out, const int* __restrict__ cntR){
  int idx = blockIdx.x*blockDim.x + threadIdx.x;   // NR*DD threads
  int k = idx >> 7;
  float c = fmaxf((float)cntR[k], 1.f);
  out[RELOFF + idx] = out[RELOFF + idx] / c;
}

extern "C" void kernel_launch(void* const* d_in, const int* in_sizes, int n_in,
                              void* d_out, int out_size, void* d_ws, size_t ws_size,
                              hipStream_t stream) {
  (void)in_sizes; (void)n_in; (void)ws_size; (void)out_size;
  const int*   trip = (const int*)  d_in[0];
  const float* ent  = (const float*)d_in[1];
  const float* rel  = (const float*)d_in[2];
  const float* aw   = (const float*)d_in[3];
  const float* ab   = (const float*)d_in[4];
  const float* a2w  = (const float*)d_in[5];
  const float* a2b  = (const float*)d_in[6];
  const float* bn0g = (const float*)d_in[7];
  const float* bn0b = (const float*)d_in[8];
  const float* bn1g = (const float*)d_in[9];
  const float* bn1b = (const float*)d_in[10];
  float* out = (float*)d_out;

  char* w = (char*)d_ws;
  size_t off = 0;
  auto take = [&](size_t bytes) -> char* {
    char* p = w + off;
    off = (off + bytes + 511) & ~(size_t)511;
    return p;
  };
  // zeroed region (accumulators)
  float* S        = (float*)take(512);
  float* Q        = (float*)take(512);
  float* colsum   = (float*)take(512);
  float* colsumsq = (float*)take(512);
  int*   cnt      = (int*)  take((size_t)NE*4);
  int*   cntR     = (int*)  take((size_t)NR*4);
  size_t zero_end = off;
  // non-zeroed (fully overwritten each launch)
  float* alpha0 = (float*)take(512);
  float* alpha1 = (float*)take(512);
  float* alpha2 = (float*)take(512);
  float* beta0  = (float*)take(512);
  float* beta1  = (float*)take(512);
  float* biasv  = (float*)take(512);
  float* A1     = (float*)take(512);
  float* B1     = (float*)take(512);
  float* a2A    = (float*)take(512);
  float* sbase  = (float*)take(512);
  float* rho    = (float*)take((size_t)NR*4);
  float* sig    = (float*)take((size_t)NE*2*4);
  int*   offE   = (int*)  take((size_t)(NE+1)*4);
  int*   curE   = (int*)  take((size_t)NE*4);
  int*   offR   = (int*)  take((size_t)(NR+1)*4);
  int*   curR   = (int*)  take((size_t)NR*4);
  uint2* evE    = (uint2*)take((size_t)NEV*8);
  uint2* evR    = (uint2*)take((size_t)NT*8);
  float* V      = (float*)take((size_t)NR*DD*4);
  unsigned short* Wt2 = (unsigned short*)take((size_t)256*128*2);
  unsigned short* U   = (unsigned short*)take((size_t)NE*256*2);

  hipMemsetAsync((char*)d_out + (size_t)RELOFF*4, 0, (size_t)NR*DD*4, stream);
  hipMemsetAsync(d_ws, 0, zero_end, stream);

  k_count    <<<(NT+255)/256, 256, 0, stream>>>(trip, cnt, cntR);
  k_scan_ent <<<1, 1024, 0, stream>>>(cnt, offE, curE);
  k_scan_rel <<<1, 512, 0, stream>>>(cntR, offR, curR);
  k_scatter  <<<(NT+255)/256, 256, 0, stream>>>(trip, curE, curR, evE, evR);
  k_entstats <<<(NE+127)/128, 256, 0, stream>>>(ent, cnt, S, Q);
  k_alpha    <<<1, 128, 0, stream>>>(rel, cntR, S, Q, bn0g, bn0b, alpha0, alpha1, alpha2, beta0, beta1);
  k_bias     <<<128, 128, 0, stream>>>(aw, ab, bn0b, beta0, beta1, biasv);
  k_v        <<<NR, 128, 0, stream>>>(rel, aw, alpha2, V);
  k_wfold2   <<<256, 128, 0, stream>>>(aw, alpha0, alpha1, Wt2);
  k_u2       <<<1563, 256, 0, stream>>>(ent, Wt2, U);
  k_c1b      <<<2048, 256, 0, stream>>>(evE, U, V, biasv, colsum, colsumsq);
  k_bn1fin   <<<1, 128, 0, stream>>>(colsum, colsumsq, bn1g, bn1b, a2w, a2b, biasv, A1, B1, a2A, sbase);
  k_sigma    <<<NE/4, 256, 0, stream>>>(U, a2A, sig);
  k_rho      <<<(NR+3)/4, 256, 0, stream>>>(V, a2A, rho);
  k_gent     <<<NE/4, 256, 0, stream>>>(evE, offE, U, V, sig, rho, biasv, A1, B1, sbase, out);
  k_grel     <<<NR*8, 256, 0, stream>>>(evR, offR, U, V, sig, rho, biasv, A1, B1, sbase, out);
  k_fin_rel  <<<(NR*DD)/256, 256, 0, stream>>>(out, cntR);
}

// Round 7
// 512.141 us; speedup vs baseline: 4.2690x; 1.2024x over previous
//
#include <hip/hip_runtime.h>
#include <hip/hip_bf16.h>

#define NE 100000
#define NR 500
#define DD 128
#define NT 250000
#define NEV 500000             // 2*NT events
#define RELOFF 12800000        // NE*DD
#define TWO_NF 500000.0f
#define NTF 250000.0f
#define TBH 2048
#define NBH ((NT + TBH - 1)/TBH)   // 123

typedef __attribute__((ext_vector_type(8))) short short8;
typedef __attribute__((ext_vector_type(4))) float f32x4;

__device__ __forceinline__ float bf2f(unsigned short u){
  unsigned int x = ((unsigned int)u) << 16;
  return __uint_as_float(x);
}
__device__ __forceinline__ float bf2f_lo(unsigned int u){ return __uint_as_float(u << 16); }
__device__ __forceinline__ float bf2f_hi(unsigned int u){ return __uint_as_float(u & 0xFFFF0000u); }
__device__ __forceinline__ unsigned short f2bf(float f){
  __hip_bfloat16 h = __float2bfloat16(f);
  return *reinterpret_cast<unsigned short*>(&h);
}
__device__ __forceinline__ void atomAddF(float* p, float v){ unsafeAtomicAdd(p, v); }
__device__ __forceinline__ float wredsum(float x){
  x += __shfl_xor(x, 1, 64);  x += __shfl_xor(x, 2, 64);  x += __shfl_xor(x, 4, 64);
  x += __shfl_xor(x, 8, 64);  x += __shfl_xor(x, 16, 64); x += __shfl_xor(x, 32, 64);
  return x;
}

// ---------------- K1: per-block rel histogram + entity counts ----------------
__global__ __launch_bounds__(256) void k_hist(const int* __restrict__ trip,
                                              int* __restrict__ cnt, int* __restrict__ gHist){
  __shared__ int h[NR];
  int t = threadIdx.x;
  for (int r = t; r < NR; r += 256) h[r] = 0;
  __syncthreads();
  int b0 = blockIdx.x*TBH, b1 = min(b0+TBH, NT);
  for (int i = b0 + t; i < b1; i += 256){
    int t0 = trip[3*i], t1 = trip[3*i+1], t2 = trip[3*i+2];
    atomicAdd(&cnt[t0], 1);
    atomicAdd(&cnt[t1], 1);
    atomicAdd(&h[t2], 1);
  }
  __syncthreads();
  for (int r = t; r < NR; r += 256) gHist[blockIdx.x*NR + r] = h[r];
}

// ---------------- K1b: column-scan hists -> per-(block,rel) base, cntR, offR ----------------
__global__ __launch_bounds__(512) void k_histscan(const int* __restrict__ gHist,
                                                  int* __restrict__ base, int* __restrict__ cntR,
                                                  int* __restrict__ offR){
  __shared__ int sm[512];
  int r = threadIdx.x;
  int s = 0;
  if (r < NR){
    for (int b = 0; b < NBH; ++b){ base[b*NR + r] = s; s += gHist[b*NR + r]; }
    cntR[r] = s;
  }
  sm[r] = (r < NR) ? s : 0;
  __syncthreads();
  for (int st = 1; st < 512; st <<= 1){
    int x = (r >= st) ? sm[r-st] : 0;
    __syncthreads();
    sm[r] += x;
    __syncthreads();
  }
  if (r < NR){
    int off = sm[r] - s;               // exclusive
    offR[r] = off;
    for (int b = 0; b < NBH; ++b) base[b*NR + r] += off;
  }
  if (r == 0) offR[NR] = NT;
}

// ---------------- scan: entity offsets (wave-shuffle) ----------------
__global__ __launch_bounds__(1024) void k_scan_ent(const int* __restrict__ cnt,
                                                   int* __restrict__ off, int* __restrict__ cur){
  __shared__ int wsum[16];
  __shared__ int carrysh;
  int t = threadIdx.x, lane = t & 63, w = t >> 6;
  if (t == 0) carrysh = 0;
  __syncthreads();
  for (int base = 0; base < NE; base += 1024){
    int v = (base + t < NE) ? cnt[base + t] : 0;
    int x = v;
    #pragma unroll
    for (int s = 1; s < 64; s <<= 1){ int y = __shfl_up(x, s, 64); if (lane >= s) x += y; }
    if (lane == 63) wsum[w] = x;
    __syncthreads();
    if (w == 0 && lane < 16){
      int xs = wsum[lane];
      #pragma unroll
      for (int s = 1; s < 16; s <<= 1){ int y = __shfl_up(xs, s, 16); if ((lane & 15) >= s) xs += y; }
      wsum[lane] = xs;
    }
    __syncthreads();
    int wprev = (w == 0) ? 0 : wsum[w-1];
    int total = wsum[15];
    int c = carrysh;
    if (base + t < NE){
      int ex = c + wprev + x - v;
      off[base + t] = ex;
      cur[base + t] = ex;
    }
    __syncthreads();
    if (t == 0) carrysh = c + total;
  }
  if (t == 0) off[NE] = carrysh;
}

// ---------------- scatter entity events (global cursors, nt stores) ----------------
// ent event: low32 = owner, high32 = other<<10 | rel<<1 | bwdflag (bwd => -V)
__global__ void k_scat_ent(const int* __restrict__ trip, int* __restrict__ curE,
                           unsigned long long* __restrict__ evE){
  int i = blockIdx.x*blockDim.x + threadIdx.x;
  if (i < NT){
    int t0 = trip[3*i+0], t1 = trip[3*i+1], t2 = trip[3*i+2];
    int p0 = atomicAdd(&curE[t0], 1);
    unsigned long long e0 = (unsigned)t0 |
      ((unsigned long long)(((unsigned)t1 << 10) | ((unsigned)t2 << 1)) << 32);
    __builtin_nontemporal_store(e0, &evE[p0]);
    int p1 = atomicAdd(&curE[t1], 1);
    unsigned long long e1 = (unsigned)t1 |
      ((unsigned long long)(((unsigned)t0 << 10) | ((unsigned)t2 << 1) | 1u) << 32);
    __builtin_nontemporal_store(e1, &evE[p1]);
  }
}

// ---------------- scatter rel events (LDS cursors, deterministic bases) ----------------
__global__ __launch_bounds__(256) void k_scat_rel(const int* __restrict__ trip,
                                                  const int* __restrict__ base,
                                                  unsigned long long* __restrict__ evR){
  __shared__ int cur[NR];
  int t = threadIdx.x;
  for (int r = t; r < NR; r += 256) cur[r] = base[blockIdx.x*NR + r];
  __syncthreads();
  int b0 = blockIdx.x*TBH, b1 = min(b0+TBH, NT);
  for (int i = b0 + t; i < b1; i += 256){
    int t0 = trip[3*i], t1 = trip[3*i+1], t2 = trip[3*i+2];
    int p = atomicAdd(&cur[t2], 1);
    unsigned long long e = (unsigned)t0 | ((unsigned long long)(unsigned)t1 << 32);
    __builtin_nontemporal_store(e, &evR[p]);
  }
}

// ---------------- K2: count-weighted entity column stats ----------------
__global__ __launch_bounds__(256) void k_entstats(const float* __restrict__ ent, const int* __restrict__ cnt,
                                                  float* __restrict__ S, float* __restrict__ Q){
  int j = threadIdx.x & 127;
  int half = threadIdx.x >> 7;
  int r0 = blockIdx.x*128 + half;
  int r1 = min(blockIdx.x*128 + 128, NE);
  float s = 0.f, q = 0.f;
  for (int r = r0; r < r1; r += 2){
    int w = cnt[r];
    if (w){
      float x = ent[(size_t)r*DD + j];
      float wf = (float)w;
      s += wf*x; q += wf*x*x;
    }
  }
  __shared__ float ss[256], qq[256];
  ss[threadIdx.x] = s; qq[threadIdx.x] = q; __syncthreads();
  if (half == 0){
    atomAddF(&S[j], ss[j] + ss[j+128]);
    atomAddF(&Q[j], qq[j] + qq[j+128]);
  }
}

// ---------------- K3: BN0 fold + rel variance ----------------
__global__ void k_alpha(const float* __restrict__ rel, const int* __restrict__ cntR,
                        const float* __restrict__ S, const float* __restrict__ Q,
                        const float* __restrict__ bn0g, const float* __restrict__ bn0b,
                        float* __restrict__ alpha0, float* __restrict__ alpha1, float* __restrict__ alpha2,
                        float* __restrict__ beta0, float* __restrict__ beta1){
  int j = threadIdx.x;
  float qr = 0.f;
  for (int k = 0; k < NR; ++k){
    float w = (float)cntR[k];
    float x = rel[k*DD + j];
    qr += w*x*x;
  }
  float mean = S[j] / TWO_NF;
  float var  = Q[j] / TWO_NF - mean*mean;
  float inv  = rsqrtf(var + 1e-5f);
  float a0 = inv * bn0g[j];
  float a1 = inv * bn0g[128+j];
  alpha0[j] = a0; alpha1[j] = a1;
  beta0[j] = bn0b[j]     - mean*a0;
  beta1[j] = bn0b[128+j] - mean*a1;
  float varR = qr / NTF;
  alpha2[j] = rsqrtf(varR + 1e-5f) * bn0g[256+j];
}

// ---------------- K4: folded bias vector ----------------
__global__ void k_bias(const float* __restrict__ aw, const float* __restrict__ ab,
                       const float* __restrict__ bn0b,
                       const float* __restrict__ beta0, const float* __restrict__ beta1,
                       float* __restrict__ bias){
  int o = blockIdx.x, j = threadIdx.x;
  const float* r = aw + (size_t)o*384;
  float p = r[j]*beta0[j] + r[128+j]*beta1[j] + r[256+j]*bn0b[256+j];
  __shared__ float sm[128];
  sm[j] = p; __syncthreads();
  for (int s = 64; s > 0; s >>= 1){ if (j < s) sm[j] += sm[j+s]; __syncthreads(); }
  if (j == 0) bias[o] = ab[o] + sm[0];
}

// ---------------- K5: V table ----------------
__global__ void k_v(const float* __restrict__ rel, const float* __restrict__ aw,
                    const float* __restrict__ alpha2, float* __restrict__ V){
  int k = blockIdx.x, o = threadIdx.x;
  __shared__ float rl[128];
  rl[o] = rel[k*DD + o] * alpha2[o];
  __syncthreads();
  float acc = 0.f;
  #pragma unroll 8
  for (int j = 0; j < 128; ++j) acc += aw[(size_t)o*384 + 256 + j] * rl[j];
  V[k*DD + o] = acc;
}

// ---------------- K5b: fold W' into bf16 table Wt2[o][k] (B-operand layout) ----------------
__global__ void k_wfold2(const float* __restrict__ aw, const float* __restrict__ alpha0,
                         const float* __restrict__ alpha1, unsigned short* __restrict__ Wt2){
  int o = blockIdx.x;        // 0..255
  int k = threadIdx.x;       // 0..127
  float w;
  if (o < 128) w = aw[(size_t)o*384 + k] * alpha0[k];
  else         w = aw[(size_t)(o-128)*384 + 128 + k] * alpha1[k];
  Wt2[(size_t)o*128 + k] = f2bf(w);
}

// ---------------- K6: U table via MFMA (16x16x32 bf16, X split hi/lo) ----------------
__global__ __launch_bounds__(256) void k_u2(const float* __restrict__ ent,
                                            const unsigned short* __restrict__ Wt2,
                                            unsigned short* __restrict__ Uo){
  __shared__ unsigned short stg[4][16*264];   // 264-ushort row pitch, 33 KB
  int tid = threadIdx.x;
  int w = tid >> 6, l = tid & 63;
  int col = l & 15, grp = l >> 4, kof = grp*8;
  int e0w = (blockIdx.x*4 + w)*16;           // 1563 blocks * 64 = 100032
  int e = min(e0w + col, NE-1);
  const float* xrow = ent + (size_t)e*DD;

  short8 a_hi0, a_hi1, a_hi2, a_hi3, a_lo0, a_lo1, a_lo2, a_lo3;
  {
    #pragma unroll
    for (int ks = 0; ks < 4; ++ks){
      float4 xa = *(const float4*)(xrow + 32*ks + kof);
      float4 xb = *(const float4*)(xrow + 32*ks + kof + 4);
      float xv[8] = {xa.x, xa.y, xa.z, xa.w, xb.x, xb.y, xb.z, xb.w};
      short8 hi, lo;
      #pragma unroll
      for (int j = 0; j < 8; ++j){
        unsigned short h = f2bf(xv[j]);
        unsigned short r = f2bf(xv[j] - bf2f(h));
        hi[j] = (short)h; lo[j] = (short)r;
      }
      if (ks == 0){ a_hi0 = hi; a_lo0 = lo; }
      else if (ks == 1){ a_hi1 = hi; a_lo1 = lo; }
      else if (ks == 2){ a_hi2 = hi; a_lo2 = lo; }
      else { a_hi3 = hi; a_lo3 = lo; }
    }
  }

  f32x4 acc[16];
  #pragma unroll
  for (int ot = 0; ot < 16; ++ot) acc[ot] = (f32x4){0.f, 0.f, 0.f, 0.f};

  #pragma unroll
  for (int ot = 0; ot < 16; ++ot){
    const unsigned short* bbase = Wt2 + (size_t)(ot*16 + col)*128 + kof;
    short8 b0 = *(const short8*)(bbase);
    short8 b1 = *(const short8*)(bbase + 32);
    short8 b2 = *(const short8*)(bbase + 64);
    short8 b3 = *(const short8*)(bbase + 96);
    acc[ot] = __builtin_amdgcn_mfma_f32_16x16x32_bf16(a_hi0, b0, acc[ot], 0, 0, 0);
    acc[ot] = __builtin_amdgcn_mfma_f32_16x16x32_bf16(a_lo0, b0, acc[ot], 0, 0, 0);
    acc[ot] = __builtin_amdgcn_mfma_f32_16x16x32_bf16(a_hi1, b1, acc[ot], 0, 0, 0);
    acc[ot] = __builtin_amdgcn_mfma_f32_16x16x32_bf16(a_lo1, b1, acc[ot], 0, 0, 0);
    acc[ot] = __builtin_amdgcn_mfma_f32_16x16x32_bf16(a_hi2, b2, acc[ot], 0, 0, 0);
    acc[ot] = __builtin_amdgcn_mfma_f32_16x16x32_bf16(a_lo2, b2, acc[ot], 0, 0, 0);
    acc[ot] = __builtin_amdgcn_mfma_f32_16x16x32_bf16(a_hi3, b3, acc[ot], 0, 0, 0);
    acc[ot] = __builtin_amdgcn_mfma_f32_16x16x32_bf16(a_lo3, b3, acc[ot], 0, 0, 0);
  }

  #pragma unroll
  for (int ot = 0; ot < 16; ++ot){
    #pragma unroll
    for (int r = 0; r < 4; ++r){
      stg[w][(grp*4 + r)*264 + ot*16 + col] = f2bf(acc[ot][r]);
    }
  }
  #pragma unroll
  for (int i = 0; i < 16; ++i){
    if (e0w + i < NE){
      ushort4 v = ((const ushort4*)&stg[w][i*264])[l];
      ((ushort4*)Uo)[(size_t)(e0w + i)*64 + l] = v;
    }
  }
}

// ---------------- K7: BN1 column stats over CSR events ----------------
__global__ __launch_bounds__(256) void k_c1b(const uint2* __restrict__ evE,
                   const unsigned short* __restrict__ U, const float* __restrict__ V,
                   const float* __restrict__ bias,
                   float* __restrict__ colsum, float* __restrict__ colsumsq){
  int lane = threadIdx.x & 63;
  int w = threadIdx.x >> 6;
  int wv = blockIdx.x*4 + w;
  int nwv = gridDim.x*4;
  int per = (NEV + nwv - 1) / nwv;
  int st = wv*per, en = min(st + per, NEV);
  int c0 = 2*lane, c1 = c0+1;
  float b0 = bias[c0], b1 = bias[c1];
  const ushort2* Ub = (const ushort2*)U;
  const float2*  Vp = (const float2*)V;
  float s0=0.f, s1=0.f, q0=0.f, q1=0.f;
  for (int bs = st; bs < en; bs += 64){
    int n = min(64, en - bs);
    uint2 ev = (bs + lane < en) ? evE[bs + lane] : make_uint2(0u, 0u);
    int j = 0;
    for (; j + 2 <= n; j += 2){
      unsigned ow0 = __shfl(ev.x, j, 64),   pk0 = __shfl(ev.y, j, 64);
      unsigned ow1 = __shfl(ev.x, j+1, 64), pk1 = __shfl(ev.y, j+1, 64);
      ushort2 a0 = Ub[(size_t)ow0*128 + lane];
      ushort2 g0 = Ub[(size_t)(pk0 >> 10)*128 + 64 + lane];
      float2  v0 = Vp[((pk0 >> 1) & 0x1FF)*64 + lane];
      ushort2 a1 = Ub[(size_t)ow1*128 + lane];
      ushort2 g1 = Ub[(size_t)(pk1 >> 10)*128 + 64 + lane];
      float2  v1 = Vp[((pk1 >> 1) & 0x1FF)*64 + lane];
      float sg0 = (pk0 & 1) ? -1.f : 1.f;
      float sg1 = (pk1 & 1) ? -1.f : 1.f;
      float y00 = bf2f(a0.x) + bf2f(g0.x) + sg0*v0.x + b0;
      float y01 = bf2f(a0.y) + bf2f(g0.y) + sg0*v0.y + b1;
      float y10 = bf2f(a1.x) + bf2f(g1.x) + sg1*v1.x + b0;
      float y11 = bf2f(a1.y) + bf2f(g1.y) + sg1*v1.y + b1;
      s0 += y00 + y10;  q0 += y00*y00 + y10*y10;
      s1 += y01 + y11;  q1 += y01*y01 + y11*y11;
    }
    for (; j < n; ++j){
      unsigned ow0 = __shfl(ev.x, j, 64), pk0 = __shfl(ev.y, j, 64);
      ushort2 a0 = Ub[(size_t)ow0*128 + lane];
      ushort2 g0 = Ub[(size_t)(pk0 >> 10)*128 + 64 + lane];
      float2  v0 = Vp[((pk0 >> 1) & 0x1FF)*64 + lane];
      float sg0 = (pk0 & 1) ? -1.f : 1.f;
      float y00 = bf2f(a0.x) + bf2f(g0.x) + sg0*v0.x + b0;
      float y01 = bf2f(a0.y) + bf2f(g0.y) + sg0*v0.y + b1;
      s0 += y00;  q0 += y00*y00;
      s1 += y01;  q1 += y01*y01;
    }
  }
  __shared__ float sred[4][128], qred[4][128];
  sred[w][c0] = s0; sred[w][c1] = s1;
  qred[w][c0] = q0; qred[w][c1] = q1;
  __syncthreads();
  int t = threadIdx.x;
  if (t < 128){
    atomAddF(&colsum[t],   sred[0][t] + sred[1][t] + sred[2][t] + sred[3][t]);
    atomAddF(&colsumsq[t], qred[0][t] + qred[1][t] + qred[2][t] + qred[3][t]);
  }
}

// ---------------- K8: BN1 fold + a2 fold + pbsb ----------------
__global__ void k_bn1fin(const float* __restrict__ colsum, const float* __restrict__ colsumsq,
                         const float* __restrict__ bn1g, const float* __restrict__ bn1b,
                         const float* __restrict__ a2w, const float* __restrict__ a2b,
                         const float* __restrict__ biasv,
                         float* __restrict__ A1, float* __restrict__ B1,
                         float* __restrict__ a2A, float* __restrict__ sbase){
  int j = threadIdx.x;
  float mean = colsum[j] / TWO_NF;
  float var  = colsumsq[j] / TWO_NF - mean*mean;
  float A = rsqrtf(var + 1e-5f) * bn1g[j];
  float B = bn1b[j] - mean*A;
  A1[j] = A; B1[j] = B;
  float w2 = a2w[j];
  float aA = w2*A;
  a2A[j] = aA;
  __shared__ float sm[128], sm2[128];
  sm[j] = w2*B; sm2[j] = biasv[j]*aA;
  __syncthreads();
  for (int s = 64; s > 0; s >>= 1){
    if (j < s){ sm[j] += sm[j+s]; sm2[j] += sm2[j+s]; }
    __syncthreads();
  }
  if (j == 0){
    float sb = a2b[0] + sm[0];
    sbase[0] = sb;
    sbase[1] = sb + sm2[0];   // pbsb = dot(bias,a2A) + sbase
  }
}

// ---------------- K8b: per-entity score scalars sigma0/sigma1 ----------------
__global__ __launch_bounds__(256) void k_sigma(const unsigned short* __restrict__ U,
                                               const float* __restrict__ a2A,
                                               float* __restrict__ sig){
  int lane = threadIdx.x & 63;
  int e = blockIdx.x*4 + (threadIdx.x>>6);
  if (e >= NE) return;
  const uint2* Ur = (const uint2*)U;
  uint2 r = Ur[(size_t)e*64 + lane];
  int c = (lane & 31)*4;
  float4 w = *(const float4*)&a2A[c];
  float p = bf2f_lo(r.x)*w.x + bf2f_hi(r.x)*w.y + bf2f_lo(r.y)*w.z + bf2f_hi(r.y)*w.w;
  p += __shfl_xor(p, 1, 64); p += __shfl_xor(p, 2, 64); p += __shfl_xor(p, 4, 64);
  p += __shfl_xor(p, 8, 64); p += __shfl_xor(p, 16, 64);
  if ((lane & 31) == 0) sig[2*e + (lane >> 5)] = p;
}

// ---------------- K8c: per-relation score scalar rho ----------------
__global__ __launch_bounds__(256) void k_rho(const float* __restrict__ V,
                                             const float* __restrict__ a2A,
                                             float* __restrict__ rho){
  int lane = threadIdx.x & 63;
  int k = blockIdx.x*4 + (threadIdx.x>>6);
  if (k >= NR) return;
  const float2* Vp = (const float2*)V;
  float2 v = Vp[(size_t)k*64 + lane];
  int c0 = 2*lane;
  float p = v.x*a2A[c0] + v.y*a2A[c0+1];
  p = wredsum(p);
  if (lane == 0) rho[k] = p;
}

// ---------------- K9: entity gather — lane-parallel scores + FMA stream ----------------
__global__ __launch_bounds__(256) void k_gent(const uint2* __restrict__ evE, const int* __restrict__ offE,
                   const unsigned short* __restrict__ U, const float* __restrict__ V,
                   const float* __restrict__ sig, const float* __restrict__ rho,
                   const float* __restrict__ bias,
                   const float* __restrict__ A1, const float* __restrict__ B1,
                   const float* __restrict__ sbase,
                   float* __restrict__ out){
  int lane = threadIdx.x & 63;
  int e = blockIdx.x*4 + (threadIdx.x>>6);
  if (e >= NE) return;
  int c0 = 2*lane, c1 = c0+1;
  const ushort2* Ub = (const ushort2*)U;
  const float2*  Vp = (const float2*)V;
  ushort2 u0 = Ub[(size_t)e*128 + lane];
  float base0 = bf2f(u0.x) + bias[c0], base1 = bf2f(u0.y) + bias[c1];
  float pb  = sbase[1];
  float s0e = sig[2*e];
  float accU0=0.f, accU1=0.f, accV0=0.f, accV1=0.f, sep=0.f;
  int p0 = offE[e], p1 = offE[e+1];
  for (int bs = p0; bs < p1; bs += 64){
    int n = min(64, p1 - bs);
    unsigned ev = 0u; float ebl = 0.f;
    if (bs + lane < p1){
      ev = evE[bs + lane].y;
      int oth = ev >> 10, rl = (ev >> 1) & 0x1FF;
      float sg = (ev & 1) ? -1.f : 1.f;
      float s = s0e + sig[2*oth + 1] + sg*rho[rl] + pb;
      float bb = (s >= 0.f) ? -s : -0.01f*s;
      ebl = expf(bb);
    }
    sep += ebl;
    int j = 0;
    for (; j + 2 <= n; j += 2){
      unsigned e0 = __shfl(ev, j, 64);
      unsigned e1 = __shfl(ev, j+1, 64);
      float eb0 = __shfl(ebl, j, 64);
      float eb1 = __shfl(ebl, j+1, 64);
      ushort2 g0 = Ub[(size_t)(e0 >> 10)*128 + 64 + lane];
      ushort2 g1 = Ub[(size_t)(e1 >> 10)*128 + 64 + lane];
      float2 v0 = Vp[((e0 >> 1) & 0x1FF)*64 + lane];
      float2 v1 = Vp[((e1 >> 1) & 0x1FF)*64 + lane];
      float w0 = (e0 & 1) ? -eb0 : eb0;
      float w1 = (e1 & 1) ? -eb1 : eb1;
      accU0 += eb0*bf2f(g0.x); accU1 += eb0*bf2f(g0.y);
      accV0 += w0*v0.x;        accV1 += w0*v0.y;
      accU0 += eb1*bf2f(g1.x); accU1 += eb1*bf2f(g1.y);
      accV0 += w1*v1.x;        accV1 += w1*v1.y;
    }
    for (; j < n; ++j){
      unsigned e0 = __shfl(ev, j, 64);
      float eb0 = __shfl(ebl, j, 64);
      ushort2 g0 = Ub[(size_t)(e0 >> 10)*128 + 64 + lane];
      float2 v0 = Vp[((e0 >> 1) & 0x1FF)*64 + lane];
      float w0 = (e0 & 1) ? -eb0 : eb0;
      accU0 += eb0*bf2f(g0.x); accU1 += eb0*bf2f(g0.y);
      accV0 += w0*v0.x;        accV1 += w0*v0.y;
    }
  }
  float se = wredsum(sep);
  float sY0 = se*base0 + accU0 + accV0;
  float sY1 = se*base1 + accU1 + accV1;
  float hs0 = A1[c0]*sY0 + B1[c0]*se;
  float hs1 = A1[c1]*sY1 + B1[c1]*se;
  float d = (se == 0.f) ? 1e-12f : se;
  out[(size_t)e*DD + c0] = hs0/d;
  out[(size_t)e*DD + c1] = hs1/d;
}

// ---------------- K10: relation gather — lane-parallel scores + FMA stream ----------------
__global__ __launch_bounds__(256) void k_grel(const uint2* __restrict__ evR, const int* __restrict__ offR,
                   const unsigned short* __restrict__ U, const float* __restrict__ V,
                   const float* __restrict__ sig, const float* __restrict__ rho,
                   const float* __restrict__ bias,
                   const float* __restrict__ A1, const float* __restrict__ B1,
                   const float* __restrict__ sbase,
                   float* __restrict__ out){
  int lane = threadIdx.x & 63;
  int k = blockIdx.x >> 3;
  int wvs = (blockIdx.x & 7)*4 + (threadIdx.x >> 6);   // 0..31
  int c0 = 2*lane, c1 = c0+1;
  const ushort2* Ub = (const ushort2*)U;
  const float2*  Vp = (const float2*)V;
  float2 v = Vp[(size_t)k*64 + lane];
  float vb0 = v.x + bias[c0], vb1 = v.y + bias[c1];
  float rpb = rho[k] + sbase[1];
  float accY0=0.f, accY1=0.f, sep=0.f;
  int p0 = offR[k], p1 = offR[k+1];
  int tot = p1 - p0, per = (tot + 31) >> 5;
  int st = p0 + wvs*per, en = min(st + per, p1);
  for (int bs = st; bs < en; bs += 64){
    int n = min(64, en - bs);
    uint2 ev = make_uint2(0u, 0u); float ebl = 0.f;
    if (bs + lane < en){
      ev = evR[bs + lane];
      float s = sig[2*ev.x] + sig[2*ev.y + 1] + rpb;
      float bb = (s >= 0.f) ? -s : -0.01f*s;
      ebl = expf(bb);
    }
    sep += ebl;
    int j = 0;
    for (; j + 2 <= n; j += 2){
      unsigned a0 = __shfl(ev.x, j, 64),   d0 = __shfl(ev.y, j, 64);
      unsigned a1 = __shfl(ev.x, j+1, 64), d1 = __shfl(ev.y, j+1, 64);
      float eb0 = __shfl(ebl, j, 64);
      float eb1 = __shfl(ebl, j+1, 64);
      ushort2 ua0 = Ub[(size_t)a0*128 + lane];
      ushort2 ud0 = Ub[(size_t)d0*128 + 64 + lane];
      ushort2 ua1 = Ub[(size_t)a1*128 + lane];
      ushort2 ud1 = Ub[(size_t)d1*128 + 64 + lane];
      accY0 += eb0*(bf2f(ua0.x) + bf2f(ud0.x));
      accY1 += eb0*(bf2f(ua0.y) + bf2f(ud0.y));
      accY0 += eb1*(bf2f(ua1.x) + bf2f(ud1.x));
      accY1 += eb1*(bf2f(ua1.y) + bf2f(ud1.y));
    }
    for (; j < n; ++j){
      unsigned a0 = __shfl(ev.x, j, 64), d0 = __shfl(ev.y, j, 64);
      float eb0 = __shfl(ebl, j, 64);
      ushort2 ua0 = Ub[(size_t)a0*128 + lane];
      ushort2 ud0 = Ub[(size_t)d0*128 + 64 + lane];
      accY0 += eb0*(bf2f(ua0.x) + bf2f(ud0.x));
      accY1 += eb0*(bf2f(ua0.y) + bf2f(ud0.y));
    }
  }
  float se = wredsum(sep);
  float sY0 = accY0 + se*vb0;
  float sY1 = accY1 + se*vb1;
  float r0 = A1[c0]*sY0 + B1[c0]*se;
  float r1 = A1[c1]*sY1 + B1[c1]*se;
  atomAddF(&out[(size_t)RELOFF + (size_t)k*DD + c0], r0);
  atomAddF(&out[(size_t)RELOFF + (size_t)k*DD + c1], r1);
}

// ---------------- K11: finalize rel division ----------------
__global__ void k_fin_rel(float* __restrict__ out, const int* __restrict__ cntR){
  int idx = blockIdx.x*blockDim.x + threadIdx.x;   // NR*DD threads
  int k = idx >> 7;
  float c = fmaxf((float)cntR[k], 1.f);
  out[RELOFF + idx] = out[RELOFF + idx] / c;
}

extern "C" void kernel_launch(void* const* d_in, const int* in_sizes, int n_in,
                              void* d_out, int out_size, void* d_ws, size_t ws_size,
                              hipStream_t stream) {
  (void)in_sizes; (void)n_in; (void)ws_size; (void)out_size;
  const int*   trip = (const int*)  d_in[0];
  const float* ent  = (const float*)d_in[1];
  const float* rel  = (const float*)d_in[2];
  const float* aw   = (const float*)d_in[3];
  const float* ab   = (const float*)d_in[4];
  const float* a2w  = (const float*)d_in[5];
  const float* a2b  = (const float*)d_in[6];
  const float* bn0g = (const float*)d_in[7];
  const float* bn0b = (const float*)d_in[8];
  const float* bn1g = (const float*)d_in[9];
  const float* bn1b = (const float*)d_in[10];
  float* out = (float*)d_out;

  char* w = (char*)d_ws;
  size_t off = 0;
  auto take = [&](size_t bytes) -> char* {
    char* p = w + off;
    off = (off + bytes + 511) & ~(size_t)511;
    return p;
  };
  // zeroed region (accumulators)
  float* S        = (float*)take(512);
  float* Q        = (float*)take(512);
  float* colsum   = (float*)take(512);
  float* colsumsq = (float*)take(512);
  int*   cnt      = (int*)  take((size_t)NE*4);
  size_t zero_end = off;
  // non-zeroed (fully overwritten each launch)
  int*   cntR   = (int*)  take((size_t)NR*4);
  float* alpha0 = (float*)take(512);
  float* alpha1 = (float*)take(512);
  float* alpha2 = (float*)take(512);
  float* beta0  = (float*)take(512);
  float* beta1  = (float*)take(512);
  float* biasv  = (float*)take(512);
  float* A1     = (float*)take(512);
  float* B1     = (float*)take(512);
  float* a2A    = (float*)take(512);
  float* sbase  = (float*)take(512);
  float* rho    = (float*)take((size_t)NR*4);
  float* sig    = (float*)take((size_t)NE*2*4);
  int*   offE   = (int*)  take((size_t)(NE+1)*4);
  int*   curE   = (int*)  take((size_t)NE*4);
  int*   offR   = (int*)  take((size_t)(NR+1)*4);
  int*   gHist  = (int*)  take((size_t)NBH*NR*4);
  int*   gBase  = (int*)  take((size_t)NBH*NR*4);
  unsigned long long* evE = (unsigned long long*)take((size_t)NEV*8);
  unsigned long long* evR = (unsigned long long*)take((size_t)NT*8);
  float* V      = (float*)take((size_t)NR*DD*4);
  unsigned short* Wt2 = (unsigned short*)take((size_t)256*128*2);
  unsigned short* U   = (unsigned short*)take((size_t)NE*256*2);

  hipMemsetAsync((char*)d_out + (size_t)RELOFF*4, 0, (size_t)NR*DD*4, stream);
  hipMemsetAsync(d_ws, 0, zero_end, stream);

  k_hist     <<<NBH, 256, 0, stream>>>(trip, cnt, gHist);
  k_histscan <<<1, 512, 0, stream>>>(gHist, gBase, cntR, offR);
  k_scan_ent <<<1, 1024, 0, stream>>>(cnt, offE, curE);
  k_scat_ent <<<(NT+255)/256, 256, 0, stream>>>(trip, curE, evE);
  k_scat_rel <<<NBH, 256, 0, stream>>>(trip, gBase, evR);
  k_entstats <<<(NE+127)/128, 256, 0, stream>>>(ent, cnt, S, Q);
  k_alpha    <<<1, 128, 0, stream>>>(rel, cntR, S, Q, bn0g, bn0b, alpha0, alpha1, alpha2, beta0, beta1);
  k_bias     <<<128, 128, 0, stream>>>(aw, ab, bn0b, beta0, beta1, biasv);
  k_v        <<<NR, 128, 0, stream>>>(rel, aw, alpha2, V);
  k_wfold2   <<<256, 128, 0, stream>>>(aw, alpha0, alpha1, Wt2);
  k_u2       <<<1563, 256, 0, stream>>>(ent, Wt2, U);
  k_c1b      <<<2048, 256, 0, stream>>>((const uint2*)evE, U, V, biasv, colsum, colsumsq);
  k_bn1fin   <<<1, 128, 0, stream>>>(colsum, colsumsq, bn1g, bn1b, a2w, a2b, biasv, A1, B1, a2A, sbase);
  k_sigma    <<<NE/4, 256, 0, stream>>>(U, a2A, sig);
  k_rho      <<<(NR+3)/4, 256, 0, stream>>>(V, a2A, rho);
  k_gent     <<<NE/4, 256, 0, stream>>>((const uint2*)evE, offE, U, V, sig, rho, biasv, A1, B1, sbase, out);
  k_grel     <<<NR*8, 256, 0, stream>>>((const uint2*)evR, offR, U, V, sig, rho, biasv, A1, B1, sbase, out);
  k_fin_rel  <<<(NR*DD)/256, 256, 0, stream>>>(out, cntR);
}

// Round 8
// 426.691 us; speedup vs baseline: 5.1240x; 1.2003x over previous
//
#include <hip/hip_runtime.h>
#include <hip/hip_bf16.h>

#define NE 100000
#define NR 500
#define DD 128
#define NT 250000
#define NEV 500000             // 2*NT events
#define RELOFF 12800000        // NE*DD
#define TWO_NF 500000.0f
#define NTF 250000.0f
#define TBH 2048
#define NBH ((NT + TBH - 1)/TBH)   // 123
#define NBS ((NE + 1023)/1024)     // 98

typedef __attribute__((ext_vector_type(8))) short short8;
typedef __attribute__((ext_vector_type(4))) float f32x4;

__device__ __forceinline__ float bf2f(unsigned short u){
  unsigned int x = ((unsigned int)u) << 16;
  return __uint_as_float(x);
}
__device__ __forceinline__ float bf2f_lo(unsigned int u){ return __uint_as_float(u << 16); }
__device__ __forceinline__ float bf2f_hi(unsigned int u){ return __uint_as_float(u & 0xFFFF0000u); }
__device__ __forceinline__ unsigned short f2bf(float f){
  __hip_bfloat16 h = __float2bfloat16(f);
  return *reinterpret_cast<unsigned short*>(&h);
}
__device__ __forceinline__ void atomAddF(float* p, float v){ unsafeAtomicAdd(p, v); }
__device__ __forceinline__ float wredsum(float x){
  x += __shfl_xor(x, 1, 64);  x += __shfl_xor(x, 2, 64);  x += __shfl_xor(x, 4, 64);
  x += __shfl_xor(x, 8, 64);  x += __shfl_xor(x, 16, 64); x += __shfl_xor(x, 32, 64);
  return x;
}

// ---------------- K1: per-block rel histogram + entity counts ----------------
__global__ __launch_bounds__(256) void k_hist(const int* __restrict__ trip,
                                              int* __restrict__ cnt, int* __restrict__ gHist){
  __shared__ int h[NR];
  int t = threadIdx.x;
  for (int r = t; r < NR; r += 256) h[r] = 0;
  __syncthreads();
  int b0 = blockIdx.x*TBH, b1 = min(b0+TBH, NT);
  for (int i = b0 + t; i < b1; i += 256){
    int t0 = trip[3*i], t1 = trip[3*i+1], t2 = trip[3*i+2];
    atomicAdd(&cnt[t0], 1);
    atomicAdd(&cnt[t1], 1);
    atomicAdd(&h[t2], 1);
  }
  __syncthreads();
  for (int r = t; r < NR; r += 256) gHist[blockIdx.x*NR + r] = h[r];
}

// ---------------- K1b: column-scan hists -> per-(block,rel) base, cntR, offR ----------------
__global__ __launch_bounds__(512) void k_histscan(const int* __restrict__ gHist,
                                                  int* __restrict__ base, int* __restrict__ cntR,
                                                  int* __restrict__ offR){
  __shared__ int sm[512];
  int r = threadIdx.x;
  int s = 0;
  if (r < NR){
    for (int b = 0; b < NBH; ++b){ base[b*NR + r] = s; s += gHist[b*NR + r]; }
    cntR[r] = s;
  }
  sm[r] = (r < NR) ? s : 0;
  __syncthreads();
  for (int st = 1; st < 512; st <<= 1){
    int x = (r >= st) ? sm[r-st] : 0;
    __syncthreads();
    sm[r] += x;
    __syncthreads();
  }
  if (r < NR){
    int off = sm[r] - s;               // exclusive
    offR[r] = off;
    for (int b = 0; b < NBH; ++b) base[b*NR + r] += off;
  }
  if (r == 0) offR[NR] = NT;
}

// ---------------- device-wide entity scan: phase 1 (block-local) ----------------
__global__ __launch_bounds__(1024) void k_scan1(const int* __restrict__ cnt,
                                                int* __restrict__ off, int* __restrict__ bsum){
  __shared__ int wsum[16];
  int t = threadIdx.x, lane = t & 63, w = t >> 6;
  int i = blockIdx.x*1024 + t;
  int v = (i < NE) ? cnt[i] : 0;
  int x = v;
  #pragma unroll
  for (int s = 1; s < 64; s <<= 1){ int y = __shfl_up(x, s, 64); if (lane >= s) x += y; }
  if (lane == 63) wsum[w] = x;
  __syncthreads();
  if (w == 0 && lane < 16){
    int xs = wsum[lane];
    #pragma unroll
    for (int s = 1; s < 16; s <<= 1){ int y = __shfl_up(xs, s, 16); if ((lane & 15) >= s) xs += y; }
    wsum[lane] = xs;
  }
  __syncthreads();
  int wprev = (w == 0) ? 0 : wsum[w-1];
  int incl = wprev + x;
  if (i < NE) off[i] = incl - v;          // block-local exclusive
  if (t == 1023) bsum[blockIdx.x] = incl; // block total
}

// ---------------- device-wide entity scan: phase 2 (scan 98 block totals) ----------------
__global__ __launch_bounds__(128) void k_scan2(const int* __restrict__ bsum,
                                               int* __restrict__ bbase, int* __restrict__ off){
  __shared__ int sm[128];
  int t = threadIdx.x;
  int v = (t < NBS) ? bsum[t] : 0;
  sm[t] = v; __syncthreads();
  for (int s = 1; s < 128; s <<= 1){
    int x = (t >= s) ? sm[t-s] : 0;
    __syncthreads();
    sm[t] += x;
    __syncthreads();
  }
  int incl = sm[t];
  if (t < NBS) bbase[t] = incl - v;
  if (t == NBS-1) off[NE] = incl;
}

// ---------------- device-wide entity scan: phase 3 (add base, write cur) ----------------
__global__ __launch_bounds__(1024) void k_scan3(int* __restrict__ off, int* __restrict__ cur,
                                                const int* __restrict__ bbase){
  int i = blockIdx.x*1024 + threadIdx.x;
  if (i < NE){
    int o = off[i] + bbase[blockIdx.x];
    off[i] = o;
    cur[i] = o;
  }
}

// ---------------- scatter entity events (global cursors, nt stores) ----------------
// ent event: low32 = owner, high32 = other<<10 | rel<<1 | bwdflag (bwd => -V)
__global__ void k_scat_ent(const int* __restrict__ trip, int* __restrict__ curE,
                           unsigned long long* __restrict__ evE){
  int i = blockIdx.x*blockDim.x + threadIdx.x;
  if (i < NT){
    int t0 = trip[3*i+0], t1 = trip[3*i+1], t2 = trip[3*i+2];
    int p0 = atomicAdd(&curE[t0], 1);
    unsigned long long e0 = (unsigned)t0 |
      ((unsigned long long)(((unsigned)t1 << 10) | ((unsigned)t2 << 1)) << 32);
    __builtin_nontemporal_store(e0, &evE[p0]);
    int p1 = atomicAdd(&curE[t1], 1);
    unsigned long long e1 = (unsigned)t1 |
      ((unsigned long long)(((unsigned)t0 << 10) | ((unsigned)t2 << 1) | 1u) << 32);
    __builtin_nontemporal_store(e1, &evE[p1]);
  }
}

// ---------------- scatter rel events (LDS cursors, deterministic bases) ----------------
__global__ __launch_bounds__(256) void k_scat_rel(const int* __restrict__ trip,
                                                  const int* __restrict__ base,
                                                  unsigned long long* __restrict__ evR){
  __shared__ int cur[NR];
  int t = threadIdx.x;
  for (int r = t; r < NR; r += 256) cur[r] = base[blockIdx.x*NR + r];
  __syncthreads();
  int b0 = blockIdx.x*TBH, b1 = min(b0+TBH, NT);
  for (int i = b0 + t; i < b1; i += 256){
    int t0 = trip[3*i], t1 = trip[3*i+1], t2 = trip[3*i+2];
    int p = atomicAdd(&cur[t2], 1);
    unsigned long long e = (unsigned)t0 | ((unsigned long long)(unsigned)t1 << 32);
    __builtin_nontemporal_store(e, &evR[p]);
  }
}

// ---------------- K2: count-weighted entity column stats ----------------
__global__ __launch_bounds__(256) void k_entstats(const float* __restrict__ ent, const int* __restrict__ cnt,
                                                  float* __restrict__ S, float* __restrict__ Q){
  int j = threadIdx.x & 127;
  int half = threadIdx.x >> 7;
  int r0 = blockIdx.x*128 + half;
  int r1 = min(blockIdx.x*128 + 128, NE);
  float s = 0.f, q = 0.f;
  for (int r = r0; r < r1; r += 2){
    int w = cnt[r];
    if (w){
      float x = ent[(size_t)r*DD + j];
      float wf = (float)w;
      s += wf*x; q += wf*x*x;
    }
  }
  __shared__ float ss[256], qq[256];
  ss[threadIdx.x] = s; qq[threadIdx.x] = q; __syncthreads();
  if (half == 0){
    atomAddF(&S[j], ss[j] + ss[j+128]);
    atomAddF(&Q[j], qq[j] + qq[j+128]);
  }
}

// ---------------- K3: BN0 fold + rel variance ----------------
__global__ void k_alpha(const float* __restrict__ rel, const int* __restrict__ cntR,
                        const float* __restrict__ S, const float* __restrict__ Q,
                        const float* __restrict__ bn0g, const float* __restrict__ bn0b,
                        float* __restrict__ alpha0, float* __restrict__ alpha1, float* __restrict__ alpha2,
                        float* __restrict__ beta0, float* __restrict__ beta1){
  int j = threadIdx.x;
  float qr = 0.f;
  for (int k = 0; k < NR; ++k){
    float w = (float)cntR[k];
    float x = rel[k*DD + j];
    qr += w*x*x;
  }
  float mean = S[j] / TWO_NF;
  float var  = Q[j] / TWO_NF - mean*mean;
  float inv  = rsqrtf(var + 1e-5f);
  float a0 = inv * bn0g[j];
  float a1 = inv * bn0g[128+j];
  alpha0[j] = a0; alpha1[j] = a1;
  beta0[j] = bn0b[j]     - mean*a0;
  beta1[j] = bn0b[128+j] - mean*a1;
  float varR = qr / NTF;
  alpha2[j] = rsqrtf(varR + 1e-5f) * bn0g[256+j];
}

// ---------------- K4: folded bias vector ----------------
__global__ void k_bias(const float* __restrict__ aw, const float* __restrict__ ab,
                       const float* __restrict__ bn0b,
                       const float* __restrict__ beta0, const float* __restrict__ beta1,
                       float* __restrict__ bias){
  int o = blockIdx.x, j = threadIdx.x;
  const float* r = aw + (size_t)o*384;
  float p = r[j]*beta0[j] + r[128+j]*beta1[j] + r[256+j]*bn0b[256+j];
  __shared__ float sm[128];
  sm[j] = p; __syncthreads();
  for (int s = 64; s > 0; s >>= 1){ if (j < s) sm[j] += sm[j+s]; __syncthreads(); }
  if (j == 0) bias[o] = ab[o] + sm[0];
}

// ---------------- K5: V table ----------------
__global__ void k_v(const float* __restrict__ rel, const float* __restrict__ aw,
                    const float* __restrict__ alpha2, float* __restrict__ V){
  int k = blockIdx.x, o = threadIdx.x;
  __shared__ float rl[128];
  rl[o] = rel[k*DD + o] * alpha2[o];
  __syncthreads();
  float acc = 0.f;
  #pragma unroll 8
  for (int j = 0; j < 128; ++j) acc += aw[(size_t)o*384 + 256 + j] * rl[j];
  V[k*DD + o] = acc;
}

// ---------------- K5b: fold W' into bf16 table Wt2[o][k] (B-operand layout) ----------------
__global__ void k_wfold2(const float* __restrict__ aw, const float* __restrict__ alpha0,
                         const float* __restrict__ alpha1, unsigned short* __restrict__ Wt2){
  int o = blockIdx.x;        // 0..255
  int k = threadIdx.x;       // 0..127
  float w;
  if (o < 128) w = aw[(size_t)o*384 + k] * alpha0[k];
  else         w = aw[(size_t)(o-128)*384 + 128 + k] * alpha1[k];
  Wt2[(size_t)o*128 + k] = f2bf(w);
}

// ---------------- K6: U table via MFMA (16x16x32 bf16, X split hi/lo) ----------------
__global__ __launch_bounds__(256) void k_u2(const float* __restrict__ ent,
                                            const unsigned short* __restrict__ Wt2,
                                            unsigned short* __restrict__ Uo){
  __shared__ unsigned short stg[4][16*264];   // 264-ushort row pitch, 33 KB
  int tid = threadIdx.x;
  int w = tid >> 6, l = tid & 63;
  int col = l & 15, grp = l >> 4, kof = grp*8;
  int e0w = (blockIdx.x*4 + w)*16;           // 1563 blocks * 64 = 100032
  int e = min(e0w + col, NE-1);
  const float* xrow = ent + (size_t)e*DD;

  short8 a_hi0, a_hi1, a_hi2, a_hi3, a_lo0, a_lo1, a_lo2, a_lo3;
  {
    #pragma unroll
    for (int ks = 0; ks < 4; ++ks){
      float4 xa = *(const float4*)(xrow + 32*ks + kof);
      float4 xb = *(const float4*)(xrow + 32*ks + kof + 4);
      float xv[8] = {xa.x, xa.y, xa.z, xa.w, xb.x, xb.y, xb.z, xb.w};
      short8 hi, lo;
      #pragma unroll
      for (int j = 0; j < 8; ++j){
        unsigned short h = f2bf(xv[j]);
        unsigned short r = f2bf(xv[j] - bf2f(h));
        hi[j] = (short)h; lo[j] = (short)r;
      }
      if (ks == 0){ a_hi0 = hi; a_lo0 = lo; }
      else if (ks == 1){ a_hi1 = hi; a_lo1 = lo; }
      else if (ks == 2){ a_hi2 = hi; a_lo2 = lo; }
      else { a_hi3 = hi; a_lo3 = lo; }
    }
  }

  f32x4 acc[16];
  #pragma unroll
  for (int ot = 0; ot < 16; ++ot) acc[ot] = (f32x4){0.f, 0.f, 0.f, 0.f};

  #pragma unroll
  for (int ot = 0; ot < 16; ++ot){
    const unsigned short* bbase = Wt2 + (size_t)(ot*16 + col)*128 + kof;
    short8 b0 = *(const short8*)(bbase);
    short8 b1 = *(const short8*)(bbase + 32);
    short8 b2 = *(const short8*)(bbase + 64);
    short8 b3 = *(const short8*)(bbase + 96);
    acc[ot] = __builtin_amdgcn_mfma_f32_16x16x32_bf16(a_hi0, b0, acc[ot], 0, 0, 0);
    acc[ot] = __builtin_amdgcn_mfma_f32_16x16x32_bf16(a_lo0, b0, acc[ot], 0, 0, 0);
    acc[ot] = __builtin_amdgcn_mfma_f32_16x16x32_bf16(a_hi1, b1, acc[ot], 0, 0, 0);
    acc[ot] = __builtin_amdgcn_mfma_f32_16x16x32_bf16(a_lo1, b1, acc[ot], 0, 0, 0);
    acc[ot] = __builtin_amdgcn_mfma_f32_16x16x32_bf16(a_hi2, b2, acc[ot], 0, 0, 0);
    acc[ot] = __builtin_amdgcn_mfma_f32_16x16x32_bf16(a_lo2, b2, acc[ot], 0, 0, 0);
    acc[ot] = __builtin_amdgcn_mfma_f32_16x16x32_bf16(a_hi3, b3, acc[ot], 0, 0, 0);
    acc[ot] = __builtin_amdgcn_mfma_f32_16x16x32_bf16(a_lo3, b3, acc[ot], 0, 0, 0);
  }

  #pragma unroll
  for (int ot = 0; ot < 16; ++ot){
    #pragma unroll
    for (int r = 0; r < 4; ++r){
      stg[w][(grp*4 + r)*264 + ot*16 + col] = f2bf(acc[ot][r]);
    }
  }
  #pragma unroll
  for (int i = 0; i < 16; ++i){
    if (e0w + i < NE){
      ushort4 v = ((const ushort4*)&stg[w][i*264])[l];
      ((ushort4*)Uo)[(size_t)(e0w + i)*64 + l] = v;
    }
  }
}

// ---------------- K7: BN1 column stats over CSR events ----------------
__global__ __launch_bounds__(256) void k_c1b(const uint2* __restrict__ evE,
                   const unsigned short* __restrict__ U, const float* __restrict__ V,
                   const float* __restrict__ bias,
                   float* __restrict__ colsum, float* __restrict__ colsumsq){
  int lane = threadIdx.x & 63;
  int w = threadIdx.x >> 6;
  int wv = blockIdx.x*4 + w;
  int nwv = gridDim.x*4;
  int per = (NEV + nwv - 1) / nwv;
  int st = wv*per, en = min(st + per, NEV);
  int c0 = 2*lane, c1 = c0+1;
  float b0 = bias[c0], b1 = bias[c1];
  const ushort2* Ub = (const ushort2*)U;
  const float2*  Vp = (const float2*)V;
  float s0=0.f, s1=0.f, q0=0.f, q1=0.f;
  for (int bs = st; bs < en; bs += 64){
    int n = min(64, en - bs);
    uint2 ev = (bs + lane < en) ? evE[bs + lane] : make_uint2(0u, 0u);
    int j = 0;
    for (; j + 2 <= n; j += 2){
      unsigned ow0 = __shfl(ev.x, j, 64),   pk0 = __shfl(ev.y, j, 64);
      unsigned ow1 = __shfl(ev.x, j+1, 64), pk1 = __shfl(ev.y, j+1, 64);
      ushort2 a0 = Ub[(size_t)ow0*128 + lane];
      ushort2 g0 = Ub[(size_t)(pk0 >> 10)*128 + 64 + lane];
      float2  v0 = Vp[((pk0 >> 1) & 0x1FF)*64 + lane];
      ushort2 a1 = Ub[(size_t)ow1*128 + lane];
      ushort2 g1 = Ub[(size_t)(pk1 >> 10)*128 + 64 + lane];
      float2  v1 = Vp[((pk1 >> 1) & 0x1FF)*64 + lane];
      float sg0 = (pk0 & 1) ? -1.f : 1.f;
      float sg1 = (pk1 & 1) ? -1.f : 1.f;
      float y00 = bf2f(a0.x) + bf2f(g0.x) + sg0*v0.x + b0;
      float y01 = bf2f(a0.y) + bf2f(g0.y) + sg0*v0.y + b1;
      float y10 = bf2f(a1.x) + bf2f(g1.x) + sg1*v1.x + b0;
      float y11 = bf2f(a1.y) + bf2f(g1.y) + sg1*v1.y + b1;
      s0 += y00 + y10;  q0 += y00*y00 + y10*y10;
      s1 += y01 + y11;  q1 += y01*y01 + y11*y11;
    }
    for (; j < n; ++j){
      unsigned ow0 = __shfl(ev.x, j, 64), pk0 = __shfl(ev.y, j, 64);
      ushort2 a0 = Ub[(size_t)ow0*128 + lane];
      ushort2 g0 = Ub[(size_t)(pk0 >> 10)*128 + 64 + lane];
      float2  v0 = Vp[((pk0 >> 1) & 0x1FF)*64 + lane];
      float sg0 = (pk0 & 1) ? -1.f : 1.f;
      float y00 = bf2f(a0.x) + bf2f(g0.x) + sg0*v0.x + b0;
      float y01 = bf2f(a0.y) + bf2f(g0.y) + sg0*v0.y + b1;
      s0 += y00;  q0 += y00*y00;
      s1 += y01;  q1 += y01*y01;
    }
  }
  __shared__ float sred[4][128], qred[4][128];
  sred[w][c0] = s0; sred[w][c1] = s1;
  qred[w][c0] = q0; qred[w][c1] = q1;
  __syncthreads();
  int t = threadIdx.x;
  if (t < 128){
    atomAddF(&colsum[t],   sred[0][t] + sred[1][t] + sred[2][t] + sred[3][t]);
    atomAddF(&colsumsq[t], qred[0][t] + qred[1][t] + qred[2][t] + qred[3][t]);
  }
}

// ---------------- K8: BN1 fold + a2 fold + pbsb ----------------
__global__ void k_bn1fin(const float* __restrict__ colsum, const float* __restrict__ colsumsq,
                         const float* __restrict__ bn1g, const float* __restrict__ bn1b,
                         const float* __restrict__ a2w, const float* __restrict__ a2b,
                         const float* __restrict__ biasv,
                         float* __restrict__ A1, float* __restrict__ B1,
                         float* __restrict__ a2A, float* __restrict__ sbase){
  int j = threadIdx.x;
  float mean = colsum[j] / TWO_NF;
  float var  = colsumsq[j] / TWO_NF - mean*mean;
  float A = rsqrtf(var + 1e-5f) * bn1g[j];
  float B = bn1b[j] - mean*A;
  A1[j] = A; B1[j] = B;
  float w2 = a2w[j];
  float aA = w2*A;
  a2A[j] = aA;
  __shared__ float sm[128], sm2[128];
  sm[j] = w2*B; sm2[j] = biasv[j]*aA;
  __syncthreads();
  for (int s = 64; s > 0; s >>= 1){
    if (j < s){ sm[j] += sm[j+s]; sm2[j] += sm2[j+s]; }
    __syncthreads();
  }
  if (j == 0){
    float sb = a2b[0] + sm[0];
    sbase[0] = sb;
    sbase[1] = sb + sm2[0];   // pbsb = dot(bias,a2A) + sbase
  }
}

// ---------------- K8b: per-entity score scalars sigma0/sigma1 ----------------
__global__ __launch_bounds__(256) void k_sigma(const unsigned short* __restrict__ U,
                                               const float* __restrict__ a2A,
                                               float* __restrict__ sig){
  int lane = threadIdx.x & 63;
  int e = blockIdx.x*4 + (threadIdx.x>>6);
  if (e >= NE) return;
  const uint2* Ur = (const uint2*)U;
  uint2 r = Ur[(size_t)e*64 + lane];
  int c = (lane & 31)*4;
  float4 w = *(const float4*)&a2A[c];
  float p = bf2f_lo(r.x)*w.x + bf2f_hi(r.x)*w.y + bf2f_lo(r.y)*w.z + bf2f_hi(r.y)*w.w;
  p += __shfl_xor(p, 1, 64); p += __shfl_xor(p, 2, 64); p += __shfl_xor(p, 4, 64);
  p += __shfl_xor(p, 8, 64); p += __shfl_xor(p, 16, 64);
  if ((lane & 31) == 0) sig[2*e + (lane >> 5)] = p;
}

// ---------------- K8c: per-relation score scalar rho ----------------
__global__ __launch_bounds__(256) void k_rho(const float* __restrict__ V,
                                             const float* __restrict__ a2A,
                                             float* __restrict__ rho){
  int lane = threadIdx.x & 63;
  int k = blockIdx.x*4 + (threadIdx.x>>6);
  if (k >= NR) return;
  const float2* Vp = (const float2*)V;
  float2 v = Vp[(size_t)k*64 + lane];
  int c0 = 2*lane;
  float p = v.x*a2A[c0] + v.y*a2A[c0+1];
  p = wredsum(p);
  if (lane == 0) rho[k] = p;
}

// ---------------- K9: entity gather — lane-parallel scores + FMA stream ----------------
__global__ __launch_bounds__(256) void k_gent(const uint2* __restrict__ evE, const int* __restrict__ offE,
                   const unsigned short* __restrict__ U, const float* __restrict__ V,
                   const float* __restrict__ sig, const float* __restrict__ rho,
                   const float* __restrict__ bias,
                   const float* __restrict__ A1, const float* __restrict__ B1,
                   const float* __restrict__ sbase,
                   float* __restrict__ out){
  int lane = threadIdx.x & 63;
  int e = blockIdx.x*4 + (threadIdx.x>>6);
  if (e >= NE) return;
  int c0 = 2*lane, c1 = c0+1;
  const ushort2* Ub = (const ushort2*)U;
  const float2*  Vp = (const float2*)V;
  ushort2 u0 = Ub[(size_t)e*128 + lane];
  float base0 = bf2f(u0.x) + bias[c0], base1 = bf2f(u0.y) + bias[c1];
  float pb  = sbase[1];
  float s0e = sig[2*e];
  float accU0=0.f, accU1=0.f, accV0=0.f, accV1=0.f, sep=0.f;
  int p0 = offE[e], p1 = offE[e+1];
  for (int bs = p0; bs < p1; bs += 64){
    int n = min(64, p1 - bs);
    unsigned ev = 0u; float ebl = 0.f;
    if (bs + lane < p1){
      ev = evE[bs + lane].y;
      int oth = ev >> 10, rl = (ev >> 1) & 0x1FF;
      float sg = (ev & 1) ? -1.f : 1.f;
      float s = s0e + sig[2*oth + 1] + sg*rho[rl] + pb;
      float bb = (s >= 0.f) ? -s : -0.01f*s;
      ebl = expf(bb);
    }
    sep += ebl;
    int j = 0;
    for (; j + 2 <= n; j += 2){
      unsigned e0 = __shfl(ev, j, 64);
      unsigned e1 = __shfl(ev, j+1, 64);
      float eb0 = __shfl(ebl, j, 64);
      float eb1 = __shfl(ebl, j+1, 64);
      ushort2 g0 = Ub[(size_t)(e0 >> 10)*128 + 64 + lane];
      ushort2 g1 = Ub[(size_t)(e1 >> 10)*128 + 64 + lane];
      float2 v0 = Vp[((e0 >> 1) & 0x1FF)*64 + lane];
      float2 v1 = Vp[((e1 >> 1) & 0x1FF)*64 + lane];
      float w0 = (e0 & 1) ? -eb0 : eb0;
      float w1 = (e1 & 1) ? -eb1 : eb1;
      accU0 += eb0*bf2f(g0.x); accU1 += eb0*bf2f(g0.y);
      accV0 += w0*v0.x;        accV1 += w0*v0.y;
      accU0 += eb1*bf2f(g1.x); accU1 += eb1*bf2f(g1.y);
      accV0 += w1*v1.x;        accV1 += w1*v1.y;
    }
    for (; j < n; ++j){
      unsigned e0 = __shfl(ev, j, 64);
      float eb0 = __shfl(ebl, j, 64);
      ushort2 g0 = Ub[(size_t)(e0 >> 10)*128 + 64 + lane];
      float2 v0 = Vp[((e0 >> 1) & 0x1FF)*64 + lane];
      float w0 = (e0 & 1) ? -eb0 : eb0;
      accU0 += eb0*bf2f(g0.x); accU1 += eb0*bf2f(g0.y);
      accV0 += w0*v0.x;        accV1 += w0*v0.y;
    }
  }
  float se = wredsum(sep);
  float sY0 = se*base0 + accU0 + accV0;
  float sY1 = se*base1 + accU1 + accV1;
  float hs0 = A1[c0]*sY0 + B1[c0]*se;
  float hs1 = A1[c1]*sY1 + B1[c1]*se;
  float d = (se == 0.f) ? 1e-12f : se;
  out[(size_t)e*DD + c0] = hs0/d;
  out[(size_t)e*DD + c1] = hs1/d;
}

// ---------------- K10: relation gather — lane-parallel scores + FMA stream ----------------
__global__ __launch_bounds__(256) void k_grel(const uint2* __restrict__ evR, const int* __restrict__ offR,
                   const unsigned short* __restrict__ U, const float* __restrict__ V,
                   const float* __restrict__ sig, const float* __restrict__ rho,
                   const float* __restrict__ bias,
                   const float* __restrict__ A1, const float* __restrict__ B1,
                   const float* __restrict__ sbase,
                   float* __restrict__ out){
  int lane = threadIdx.x & 63;
  int k = blockIdx.x >> 3;
  int wvs = (blockIdx.x & 7)*4 + (threadIdx.x >> 6);   // 0..31
  int c0 = 2*lane, c1 = c0+1;
  const ushort2* Ub = (const ushort2*)U;
  const float2*  Vp = (const float2*)V;
  float2 v = Vp[(size_t)k*64 + lane];
  float vb0 = v.x + bias[c0], vb1 = v.y + bias[c1];
  float rpb = rho[k] + sbase[1];
  float accY0=0.f, accY1=0.f, sep=0.f;
  int p0 = offR[k], p1 = offR[k+1];
  int tot = p1 - p0, per = (tot + 31) >> 5;
  int st = p0 + wvs*per, en = min(st + per, p1);
  for (int bs = st; bs < en; bs += 64){
    int n = min(64, en - bs);
    uint2 ev = make_uint2(0u, 0u); float ebl = 0.f;
    if (bs + lane < en){
      ev = evR[bs + lane];
      float s = sig[2*ev.x] + sig[2*ev.y + 1] + rpb;
      float bb = (s >= 0.f) ? -s : -0.01f*s;
      ebl = expf(bb);
    }
    sep += ebl;
    int j = 0;
    for (; j + 2 <= n; j += 2){
      unsigned a0 = __shfl(ev.x, j, 64),   d0 = __shfl(ev.y, j, 64);
      unsigned a1 = __shfl(ev.x, j+1, 64), d1 = __shfl(ev.y, j+1, 64);
      float eb0 = __shfl(ebl, j, 64);
      float eb1 = __shfl(ebl, j+1, 64);
      ushort2 ua0 = Ub[(size_t)a0*128 + lane];
      ushort2 ud0 = Ub[(size_t)d0*128 + 64 + lane];
      ushort2 ua1 = Ub[(size_t)a1*128 + lane];
      ushort2 ud1 = Ub[(size_t)d1*128 + 64 + lane];
      accY0 += eb0*(bf2f(ua0.x) + bf2f(ud0.x));
      accY1 += eb0*(bf2f(ua0.y) + bf2f(ud0.y));
      accY0 += eb1*(bf2f(ua1.x) + bf2f(ud1.x));
      accY1 += eb1*(bf2f(ua1.y) + bf2f(ud1.y));
    }
    for (; j < n; ++j){
      unsigned a0 = __shfl(ev.x, j, 64), d0 = __shfl(ev.y, j, 64);
      float eb0 = __shfl(ebl, j, 64);
      ushort2 ua0 = Ub[(size_t)a0*128 + lane];
      ushort2 ud0 = Ub[(size_t)d0*128 + 64 + lane];
      accY0 += eb0*(bf2f(ua0.x) + bf2f(ud0.x));
      accY1 += eb0*(bf2f(ua0.y) + bf2f(ud0.y));
    }
  }
  float se = wredsum(sep);
  float sY0 = accY0 + se*vb0;
  float sY1 = accY1 + se*vb1;
  float r0 = A1[c0]*sY0 + B1[c0]*se;
  float r1 = A1[c1]*sY1 + B1[c1]*se;
  atomAddF(&out[(size_t)RELOFF + (size_t)k*DD + c0], r0);
  atomAddF(&out[(size_t)RELOFF + (size_t)k*DD + c1], r1);
}

// ---------------- K11: finalize rel division ----------------
__global__ void k_fin_rel(float* __restrict__ out, const int* __restrict__ cntR){
  int idx = blockIdx.x*blockDim.x + threadIdx.x;   // NR*DD threads
  int k = idx >> 7;
  float c = fmaxf((float)cntR[k], 1.f);
  out[RELOFF + idx] = out[RELOFF + idx] / c;
}

extern "C" void kernel_launch(void* const* d_in, const int* in_sizes, int n_in,
                              void* d_out, int out_size, void* d_ws, size_t ws_size,
                              hipStream_t stream) {
  (void)in_sizes; (void)n_in; (void)ws_size; (void)out_size;
  const int*   trip = (const int*)  d_in[0];
  const float* ent  = (const float*)d_in[1];
  const float* rel  = (const float*)d_in[2];
  const float* aw   = (const float*)d_in[3];
  const float* ab   = (const float*)d_in[4];
  const float* a2w  = (const float*)d_in[5];
  const float* a2b  = (const float*)d_in[6];
  const float* bn0g = (const float*)d_in[7];
  const float* bn0b = (const float*)d_in[8];
  const float* bn1g = (const float*)d_in[9];
  const float* bn1b = (const float*)d_in[10];
  float* out = (float*)d_out;

  char* w = (char*)d_ws;
  size_t off = 0;
  auto take = [&](size_t bytes) -> char* {
    char* p = w + off;
    off = (off + bytes + 511) & ~(size_t)511;
    return p;
  };
  // zeroed region (accumulators)
  float* S        = (float*)take(512);
  float* Q        = (float*)take(512);
  float* colsum   = (float*)take(512);
  float* colsumsq = (float*)take(512);
  int*   cnt      = (int*)  take((size_t)NE*4);
  size_t zero_end = off;
  // non-zeroed (fully overwritten each launch)
  int*   cntR   = (int*)  take((size_t)NR*4);
  float* alpha0 = (float*)take(512);
  float* alpha1 = (float*)take(512);
  float* alpha2 = (float*)take(512);
  float* beta0  = (float*)take(512);
  float* beta1  = (float*)take(512);
  float* biasv  = (float*)take(512);
  float* A1     = (float*)take(512);
  float* B1     = (float*)take(512);
  float* a2A    = (float*)take(512);
  float* sbase  = (float*)take(512);
  float* rho    = (float*)take((size_t)NR*4);
  float* sig    = (float*)take((size_t)NE*2*4);
  int*   offE   = (int*)  take((size_t)(NE+1)*4);
  int*   curE   = (int*)  take((size_t)NE*4);
  int*   offR   = (int*)  take((size_t)(NR+1)*4);
  int*   gHist  = (int*)  take((size_t)NBH*NR*4);
  int*   gBase  = (int*)  take((size_t)NBH*NR*4);
  int*   bsum   = (int*)  take((size_t)NBS*4);
  int*   bbase  = (int*)  take((size_t)NBS*4);
  unsigned long long* evE = (unsigned long long*)take((size_t)NEV*8);
  unsigned long long* evR = (unsigned long long*)take((size_t)NT*8);
  float* V      = (float*)take((size_t)NR*DD*4);
  unsigned short* Wt2 = (unsigned short*)take((size_t)256*128*2);
  unsigned short* U   = (unsigned short*)take((size_t)NE*256*2);

  hipMemsetAsync((char*)d_out + (size_t)RELOFF*4, 0, (size_t)NR*DD*4, stream);
  hipMemsetAsync(d_ws, 0, zero_end, stream);

  k_hist     <<<NBH, 256, 0, stream>>>(trip, cnt, gHist);
  k_histscan <<<1, 512, 0, stream>>>(gHist, gBase, cntR, offR);
  k_scan1    <<<NBS, 1024, 0, stream>>>(cnt, offE, bsum);
  k_scan2    <<<1, 128, 0, stream>>>(bsum, bbase, offE);
  k_scan3    <<<NBS, 1024, 0, stream>>>(offE, curE, bbase);
  k_scat_ent <<<(NT+255)/256, 256, 0, stream>>>(trip, curE, evE);
  k_scat_rel <<<NBH, 256, 0, stream>>>(trip, gBase, evR);
  k_entstats <<<(NE+127)/128, 256, 0, stream>>>(ent, cnt, S, Q);
  k_alpha    <<<1, 128, 0, stream>>>(rel, cntR, S, Q, bn0g, bn0b, alpha0, alpha1, alpha2, beta0, beta1);
  k_bias     <<<128, 128, 0, stream>>>(aw, ab, bn0b, beta0, beta1, biasv);
  k_v        <<<NR, 128, 0, stream>>>(rel, aw, alpha2, V);
  k_wfold2   <<<256, 128, 0, stream>>>(aw, alpha0, alpha1, Wt2);
  k_u2       <<<1563, 256, 0, stream>>>(ent, Wt2, U);
  k_c1b      <<<2048, 256, 0, stream>>>((const uint2*)evE, U, V, biasv, colsum, colsumsq);
  k_bn1fin   <<<1, 128, 0, stream>>>(colsum, colsumsq, bn1g, bn1b, a2w, a2b, biasv, A1, B1, a2A, sbase);
  k_sigma    <<<NE/4, 256, 0, stream>>>(U, a2A, sig);
  k_rho      <<<(NR+3)/4, 256, 0, stream>>>(V, a2A, rho);
  k_gent     <<<NE/4, 256, 0, stream>>>((const uint2*)evE, offE, U, V, sig, rho, biasv, A1, B1, sbase, out);
  k_grel     <<<NR*8, 256, 0, stream>>>((const uint2*)evR, offR, U, V, sig, rho, biasv, A1, B1, sbase, out);
  k_fin_rel  <<<(NR*DD)/256, 256, 0, stream>>>(out, cntR);
}

// Round 9
// 419.800 us; speedup vs baseline: 5.2081x; 1.0164x over previous
//
#include <hip/hip_runtime.h>
#include <hip/hip_bf16.h>

#define NE 100000
#define NR 500
#define DD 128
#define NT 250000
#define NEV 500000             // 2*NT events
#define RELOFF 12800000        // NE*DD
#define TWO_NF 500000.0f
#define NTF 250000.0f
#define TBH 2048
#define NBH ((NT + TBH - 1)/TBH)   // 123
#define NBS ((NE + 1023)/1024)     // 98

typedef __attribute__((ext_vector_type(8))) short short8;
typedef __attribute__((ext_vector_type(4))) float f32x4;

__device__ __forceinline__ float bf2f(unsigned short u){
  unsigned int x = ((unsigned int)u) << 16;
  return __uint_as_float(x);
}
__device__ __forceinline__ float bf2f_lo(unsigned int u){ return __uint_as_float(u << 16); }
__device__ __forceinline__ float bf2f_hi(unsigned int u){ return __uint_as_float(u & 0xFFFF0000u); }
__device__ __forceinline__ unsigned short f2bf(float f){
  __hip_bfloat16 h = __float2bfloat16(f);
  return *reinterpret_cast<unsigned short*>(&h);
}
__device__ __forceinline__ void atomAddF(float* p, float v){ unsafeAtomicAdd(p, v); }
__device__ __forceinline__ float wredsum(float x){
  x += __shfl_xor(x, 1, 64);  x += __shfl_xor(x, 2, 64);  x += __shfl_xor(x, 4, 64);
  x += __shfl_xor(x, 8, 64);  x += __shfl_xor(x, 16, 64); x += __shfl_xor(x, 32, 64);
  return x;
}

// ---------------- K1: per-block rel histogram + entity counts ----------------
__global__ __launch_bounds__(256) void k_hist(const int* __restrict__ trip,
                                              int* __restrict__ cnt, int* __restrict__ gHist){
  __shared__ int h[NR];
  int t = threadIdx.x;
  for (int r = t; r < NR; r += 256) h[r] = 0;
  __syncthreads();
  int b0 = blockIdx.x*TBH, b1 = min(b0+TBH, NT);
  for (int i = b0 + t; i < b1; i += 256){
    int t0 = trip[3*i], t1 = trip[3*i+1], t2 = trip[3*i+2];
    atomicAdd(&cnt[t0], 1);
    atomicAdd(&cnt[t1], 1);
    atomicAdd(&h[t2], 1);
  }
  __syncthreads();
  for (int r = t; r < NR; r += 256) gHist[blockIdx.x*NR + r] = h[r];
}

// ---------------- K1b: column-scan hists -> per-(block,rel) base, cntR, offR ----------------
__global__ __launch_bounds__(512) void k_histscan(const int* __restrict__ gHist,
                                                  int* __restrict__ base, int* __restrict__ cntR,
                                                  int* __restrict__ offR){
  __shared__ int sm[512];
  int r = threadIdx.x;
  int s = 0;
  if (r < NR){
    for (int b = 0; b < NBH; ++b){ base[b*NR + r] = s; s += gHist[b*NR + r]; }
    cntR[r] = s;
  }
  sm[r] = (r < NR) ? s : 0;
  __syncthreads();
  for (int st = 1; st < 512; st <<= 1){
    int x = (r >= st) ? sm[r-st] : 0;
    __syncthreads();
    sm[r] += x;
    __syncthreads();
  }
  if (r < NR){
    int off = sm[r] - s;               // exclusive
    offR[r] = off;
    for (int b = 0; b < NBH; ++b) base[b*NR + r] += off;
  }
  if (r == 0) offR[NR] = NT;
}

// ---------------- device-wide entity scan: phase 1 (block-local) ----------------
__global__ __launch_bounds__(1024) void k_scan1(const int* __restrict__ cnt,
                                                int* __restrict__ off, int* __restrict__ bsum){
  __shared__ int wsum[16];
  int t = threadIdx.x, lane = t & 63, w = t >> 6;
  int i = blockIdx.x*1024 + t;
  int v = (i < NE) ? cnt[i] : 0;
  int x = v;
  #pragma unroll
  for (int s = 1; s < 64; s <<= 1){ int y = __shfl_up(x, s, 64); if (lane >= s) x += y; }
  if (lane == 63) wsum[w] = x;
  __syncthreads();
  if (w == 0 && lane < 16){
    int xs = wsum[lane];
    #pragma unroll
    for (int s = 1; s < 16; s <<= 1){ int y = __shfl_up(xs, s, 16); if ((lane & 15) >= s) xs += y; }
    wsum[lane] = xs;
  }
  __syncthreads();
  int wprev = (w == 0) ? 0 : wsum[w-1];
  int incl = wprev + x;
  if (i < NE) off[i] = incl - v;          // block-local exclusive
  if (t == 1023) bsum[blockIdx.x] = incl; // block total
}

// ---------------- device-wide entity scan: phase 2 (scan 98 block totals) ----------------
__global__ __launch_bounds__(128) void k_scan2(const int* __restrict__ bsum,
                                               int* __restrict__ bbase, int* __restrict__ off){
  __shared__ int sm[128];
  int t = threadIdx.x;
  int v = (t < NBS) ? bsum[t] : 0;
  sm[t] = v; __syncthreads();
  for (int s = 1; s < 128; s <<= 1){
    int x = (t >= s) ? sm[t-s] : 0;
    __syncthreads();
    sm[t] += x;
    __syncthreads();
  }
  int incl = sm[t];
  if (t < NBS) bbase[t] = incl - v;
  if (t == NBS-1) off[NE] = incl;
}

// ---------------- device-wide entity scan: phase 3 (add base, write cur) ----------------
__global__ __launch_bounds__(1024) void k_scan3(int* __restrict__ off, int* __restrict__ cur,
                                                const int* __restrict__ bbase){
  int i = blockIdx.x*1024 + threadIdx.x;
  if (i < NE){
    int o = off[i] + bbase[blockIdx.x];
    off[i] = o;
    cur[i] = o;
  }
}

// ---------------- scatter entity events (global cursors, nt stores) ----------------
__global__ void k_scat_ent(const int* __restrict__ trip, int* __restrict__ curE,
                           unsigned long long* __restrict__ evE){
  int i = blockIdx.x*blockDim.x + threadIdx.x;
  if (i < NT){
    int t0 = trip[3*i+0], t1 = trip[3*i+1], t2 = trip[3*i+2];
    int p0 = atomicAdd(&curE[t0], 1);
    unsigned long long e0 = (unsigned)t0 |
      ((unsigned long long)(((unsigned)t1 << 10) | ((unsigned)t2 << 1)) << 32);
    __builtin_nontemporal_store(e0, &evE[p0]);
    int p1 = atomicAdd(&curE[t1], 1);
    unsigned long long e1 = (unsigned)t1 |
      ((unsigned long long)(((unsigned)t0 << 10) | ((unsigned)t2 << 1) | 1u) << 32);
    __builtin_nontemporal_store(e1, &evE[p1]);
  }
}

// ---------------- scatter rel events (LDS cursors, deterministic bases) ----------------
__global__ __launch_bounds__(256) void k_scat_rel(const int* __restrict__ trip,
                                                  const int* __restrict__ base,
                                                  unsigned long long* __restrict__ evR){
  __shared__ int cur[NR];
  int t = threadIdx.x;
  for (int r = t; r < NR; r += 256) cur[r] = base[blockIdx.x*NR + r];
  __syncthreads();
  int b0 = blockIdx.x*TBH, b1 = min(b0+TBH, NT);
  for (int i = b0 + t; i < b1; i += 256){
    int t0 = trip[3*i], t1 = trip[3*i+1], t2 = trip[3*i+2];
    int p = atomicAdd(&cur[t2], 1);
    unsigned long long e = (unsigned)t0 | ((unsigned long long)(unsigned)t1 << 32);
    __builtin_nontemporal_store(e, &evR[p]);
  }
}

// ---------------- K2: count-weighted entity column stats ----------------
__global__ __launch_bounds__(256) void k_entstats(const float* __restrict__ ent, const int* __restrict__ cnt,
                                                  float* __restrict__ S, float* __restrict__ Q){
  int j = threadIdx.x & 127;
  int half = threadIdx.x >> 7;
  int r0 = blockIdx.x*128 + half;
  int r1 = min(blockIdx.x*128 + 128, NE);
  float s = 0.f, q = 0.f;
  for (int r = r0; r < r1; r += 2){
    int w = cnt[r];
    if (w){
      float x = ent[(size_t)r*DD + j];
      float wf = (float)w;
      s += wf*x; q += wf*x*x;
    }
  }
  __shared__ float ss[256], qq[256];
  ss[threadIdx.x] = s; qq[threadIdx.x] = q; __syncthreads();
  if (half == 0){
    atomAddF(&S[j], ss[j] + ss[j+128]);
    atomAddF(&Q[j], qq[j] + qq[j+128]);
  }
}

// ---------------- K3: BN0 fold + rel variance ----------------
__global__ void k_alpha(const float* __restrict__ rel, const int* __restrict__ cntR,
                        const float* __restrict__ S, const float* __restrict__ Q,
                        const float* __restrict__ bn0g, const float* __restrict__ bn0b,
                        float* __restrict__ alpha0, float* __restrict__ alpha1, float* __restrict__ alpha2,
                        float* __restrict__ beta0, float* __restrict__ beta1){
  int j = threadIdx.x;
  float qr = 0.f;
  for (int k = 0; k < NR; ++k){
    float w = (float)cntR[k];
    float x = rel[k*DD + j];
    qr += w*x*x;
  }
  float mean = S[j] / TWO_NF;
  float var  = Q[j] / TWO_NF - mean*mean;
  float inv  = rsqrtf(var + 1e-5f);
  float a0 = inv * bn0g[j];
  float a1 = inv * bn0g[128+j];
  alpha0[j] = a0; alpha1[j] = a1;
  beta0[j] = bn0b[j]     - mean*a0;
  beta1[j] = bn0b[128+j] - mean*a1;
  float varR = qr / NTF;
  alpha2[j] = rsqrtf(varR + 1e-5f) * bn0g[256+j];
}

// ---------------- K4: folded bias vector ----------------
__global__ void k_bias(const float* __restrict__ aw, const float* __restrict__ ab,
                       const float* __restrict__ bn0b,
                       const float* __restrict__ beta0, const float* __restrict__ beta1,
                       float* __restrict__ bias){
  int o = blockIdx.x, j = threadIdx.x;
  const float* r = aw + (size_t)o*384;
  float p = r[j]*beta0[j] + r[128+j]*beta1[j] + r[256+j]*bn0b[256+j];
  __shared__ float sm[128];
  sm[j] = p; __syncthreads();
  for (int s = 64; s > 0; s >>= 1){ if (j < s) sm[j] += sm[j+s]; __syncthreads(); }
  if (j == 0) bias[o] = ab[o] + sm[0];
}

// ---------------- K5: V table ----------------
__global__ void k_v(const float* __restrict__ rel, const float* __restrict__ aw,
                    const float* __restrict__ alpha2, float* __restrict__ V){
  int k = blockIdx.x, o = threadIdx.x;
  __shared__ float rl[128];
  rl[o] = rel[k*DD + o] * alpha2[o];
  __syncthreads();
  float acc = 0.f;
  #pragma unroll 8
  for (int j = 0; j < 128; ++j) acc += aw[(size_t)o*384 + 256 + j] * rl[j];
  V[k*DD + o] = acc;
}

// ---------------- K5b: fold W' into bf16 table Wt2[o][k] (B-operand layout) ----------------
__global__ void k_wfold2(const float* __restrict__ aw, const float* __restrict__ alpha0,
                         const float* __restrict__ alpha1, unsigned short* __restrict__ Wt2){
  int o = blockIdx.x;        // 0..255
  int k = threadIdx.x;       // 0..127
  float w;
  if (o < 128) w = aw[(size_t)o*384 + k] * alpha0[k];
  else         w = aw[(size_t)(o-128)*384 + 128 + k] * alpha1[k];
  Wt2[(size_t)o*128 + k] = f2bf(w);
}

// ---------------- K6: U table via MFMA (16x16x32 bf16) ----------------
__global__ __launch_bounds__(256) void k_u2(const float* __restrict__ ent,
                                            const unsigned short* __restrict__ Wt2,
                                            unsigned short* __restrict__ Uo){
  __shared__ unsigned short stg[4][16*264];   // 264-ushort row pitch, 33 KB
  int tid = threadIdx.x;
  int w = tid >> 6, l = tid & 63;
  int col = l & 15, grp = l >> 4, kof = grp*8;
  int e0w = (blockIdx.x*4 + w)*16;           // 1563 blocks * 64 = 100032
  int e = min(e0w + col, NE-1);
  const float* xrow = ent + (size_t)e*DD;

  short8 a0v, a1v, a2v, a3v;
  {
    #pragma unroll
    for (int ks = 0; ks < 4; ++ks){
      float4 xa = *(const float4*)(xrow + 32*ks + kof);
      float4 xb = *(const float4*)(xrow + 32*ks + kof + 4);
      short8 hi;
      hi[0] = (short)f2bf(xa.x); hi[1] = (short)f2bf(xa.y);
      hi[2] = (short)f2bf(xa.z); hi[3] = (short)f2bf(xa.w);
      hi[4] = (short)f2bf(xb.x); hi[5] = (short)f2bf(xb.y);
      hi[6] = (short)f2bf(xb.z); hi[7] = (short)f2bf(xb.w);
      if (ks == 0) a0v = hi;
      else if (ks == 1) a1v = hi;
      else if (ks == 2) a2v = hi;
      else a3v = hi;
    }
  }

  f32x4 acc[16];
  #pragma unroll
  for (int ot = 0; ot < 16; ++ot) acc[ot] = (f32x4){0.f, 0.f, 0.f, 0.f};

  #pragma unroll
  for (int ot = 0; ot < 16; ++ot){
    const unsigned short* bbase = Wt2 + (size_t)(ot*16 + col)*128 + kof;
    short8 b0 = *(const short8*)(bbase);
    short8 b1 = *(const short8*)(bbase + 32);
    short8 b2 = *(const short8*)(bbase + 64);
    short8 b3 = *(const short8*)(bbase + 96);
    acc[ot] = __builtin_amdgcn_mfma_f32_16x16x32_bf16(a0v, b0, acc[ot], 0, 0, 0);
    acc[ot] = __builtin_amdgcn_mfma_f32_16x16x32_bf16(a1v, b1, acc[ot], 0, 0, 0);
    acc[ot] = __builtin_amdgcn_mfma_f32_16x16x32_bf16(a2v, b2, acc[ot], 0, 0, 0);
    acc[ot] = __builtin_amdgcn_mfma_f32_16x16x32_bf16(a3v, b3, acc[ot], 0, 0, 0);
  }

  #pragma unroll
  for (int ot = 0; ot < 16; ++ot){
    #pragma unroll
    for (int r = 0; r < 4; ++r){
      stg[w][(grp*4 + r)*264 + ot*16 + col] = f2bf(acc[ot][r]);
    }
  }
  #pragma unroll
  for (int i = 0; i < 16; ++i){
    if (e0w + i < NE){
      ushort4 v = ((const ushort4*)&stg[w][i*264])[l];
      ((ushort4*)Uo)[(size_t)(e0w + i)*64 + l] = v;
    }
  }
}

// ---------------- K7: BN1 column stats over CSR events (unroll x4, named) ----------------
__global__ __launch_bounds__(256) void k_c1b(const uint2* __restrict__ evE,
                   const unsigned short* __restrict__ U, const float* __restrict__ V,
                   const float* __restrict__ bias,
                   float* __restrict__ colsum, float* __restrict__ colsumsq){
  int lane = threadIdx.x & 63;
  int w = threadIdx.x >> 6;
  int wv = blockIdx.x*4 + w;
  int nwv = gridDim.x*4;
  int per = (NEV + nwv - 1) / nwv;
  int st = wv*per, en = min(st + per, NEV);
  int c0 = 2*lane, c1 = c0+1;
  float b0 = bias[c0], b1 = bias[c1];
  const ushort2* Ub = (const ushort2*)U;
  const float2*  Vp = (const float2*)V;
  float s0=0.f, s1=0.f, q0=0.f, q1=0.f;
  for (int bs = st; bs < en; bs += 64){
    int n = min(64, en - bs);
    uint2 ev = (bs + lane < en) ? evE[bs + lane] : make_uint2(0u, 0u);
    int j = 0;
    for (; j + 4 <= n; j += 4){
      unsigned ow0 = __shfl(ev.x, j, 64),   pk0 = __shfl(ev.y, j, 64);
      unsigned ow1 = __shfl(ev.x, j+1, 64), pk1 = __shfl(ev.y, j+1, 64);
      unsigned ow2 = __shfl(ev.x, j+2, 64), pk2 = __shfl(ev.y, j+2, 64);
      unsigned ow3 = __shfl(ev.x, j+3, 64), pk3 = __shfl(ev.y, j+3, 64);
      ushort2 a0 = Ub[(size_t)ow0*128 + lane];
      ushort2 g0 = Ub[(size_t)(pk0 >> 10)*128 + 64 + lane];
      float2  v0 = Vp[((pk0 >> 1) & 0x1FF)*64 + lane];
      ushort2 a1 = Ub[(size_t)ow1*128 + lane];
      ushort2 g1 = Ub[(size_t)(pk1 >> 10)*128 + 64 + lane];
      float2  v1 = Vp[((pk1 >> 1) & 0x1FF)*64 + lane];
      ushort2 a2 = Ub[(size_t)ow2*128 + lane];
      ushort2 g2 = Ub[(size_t)(pk2 >> 10)*128 + 64 + lane];
      float2  v2 = Vp[((pk2 >> 1) & 0x1FF)*64 + lane];
      ushort2 a3 = Ub[(size_t)ow3*128 + lane];
      ushort2 g3 = Ub[(size_t)(pk3 >> 10)*128 + 64 + lane];
      float2  v3 = Vp[((pk3 >> 1) & 0x1FF)*64 + lane];
      float sg0 = (pk0 & 1) ? -1.f : 1.f;
      float sg1 = (pk1 & 1) ? -1.f : 1.f;
      float sg2 = (pk2 & 1) ? -1.f : 1.f;
      float sg3 = (pk3 & 1) ? -1.f : 1.f;
      float y00 = bf2f(a0.x) + bf2f(g0.x) + sg0*v0.x + b0;
      float y01 = bf2f(a0.y) + bf2f(g0.y) + sg0*v0.y + b1;
      float y10 = bf2f(a1.x) + bf2f(g1.x) + sg1*v1.x + b0;
      float y11 = bf2f(a1.y) + bf2f(g1.y) + sg1*v1.y + b1;
      float y20 = bf2f(a2.x) + bf2f(g2.x) + sg2*v2.x + b0;
      float y21 = bf2f(a2.y) + bf2f(g2.y) + sg2*v2.y + b1;
      float y30 = bf2f(a3.x) + bf2f(g3.x) + sg3*v3.x + b0;
      float y31 = bf2f(a3.y) + bf2f(g3.y) + sg3*v3.y + b1;
      s0 += y00 + y10 + y20 + y30;
      s1 += y01 + y11 + y21 + y31;
      q0 += y00*y00 + y10*y10 + y20*y20 + y30*y30;
      q1 += y01*y01 + y11*y11 + y21*y21 + y31*y31;
    }
    for (; j < n; ++j){
      unsigned ow0 = __shfl(ev.x, j, 64), pk0 = __shfl(ev.y, j, 64);
      ushort2 a0 = Ub[(size_t)ow0*128 + lane];
      ushort2 g0 = Ub[(size_t)(pk0 >> 10)*128 + 64 + lane];
      float2  v0 = Vp[((pk0 >> 1) & 0x1FF)*64 + lane];
      float sg0 = (pk0 & 1) ? -1.f : 1.f;
      float y00 = bf2f(a0.x) + bf2f(g0.x) + sg0*v0.x + b0;
      float y01 = bf2f(a0.y) + bf2f(g0.y) + sg0*v0.y + b1;
      s0 += y00;  q0 += y00*y00;
      s1 += y01;  q1 += y01*y01;
    }
  }
  __shared__ float sred[4][128], qred[4][128];
  sred[w][c0] = s0; sred[w][c1] = s1;
  qred[w][c0] = q0; qred[w][c1] = q1;
  __syncthreads();
  int t = threadIdx.x;
  if (t < 128){
    atomAddF(&colsum[t],   sred[0][t] + sred[1][t] + sred[2][t] + sred[3][t]);
    atomAddF(&colsumsq[t], qred[0][t] + qred[1][t] + qred[2][t] + qred[3][t]);
  }
}

// ---------------- K8: BN1 fold + a2 fold + pbsb ----------------
__global__ void k_bn1fin(const float* __restrict__ colsum, const float* __restrict__ colsumsq,
                         const float* __restrict__ bn1g, const float* __restrict__ bn1b,
                         const float* __restrict__ a2w, const float* __restrict__ a2b,
                         const float* __restrict__ biasv,
                         float* __restrict__ A1, float* __restrict__ B1,
                         float* __restrict__ a2A, float* __restrict__ sbase){
  int j = threadIdx.x;
  float mean = colsum[j] / TWO_NF;
  float var  = colsumsq[j] / TWO_NF - mean*mean;
  float A = rsqrtf(var + 1e-5f) * bn1g[j];
  float B = bn1b[j] - mean*A;
  A1[j] = A; B1[j] = B;
  float w2 = a2w[j];
  float aA = w2*A;
  a2A[j] = aA;
  __shared__ float sm[128], sm2[128];
  sm[j] = w2*B; sm2[j] = biasv[j]*aA;
  __syncthreads();
  for (int s = 64; s > 0; s >>= 1){
    if (j < s){ sm[j] += sm[j+s]; sm2[j] += sm2[j+s]; }
    __syncthreads();
  }
  if (j == 0){
    float sb = a2b[0] + sm[0];
    sbase[0] = sb;
    sbase[1] = sb + sm2[0];   // pbsb = dot(bias,a2A) + sbase
  }
}

// ---------------- K8b: per-entity score scalars sigma0/sigma1 ----------------
__global__ __launch_bounds__(256) void k_sigma(const unsigned short* __restrict__ U,
                                               const float* __restrict__ a2A,
                                               float* __restrict__ sig){
  int lane = threadIdx.x & 63;
  int e = blockIdx.x*4 + (threadIdx.x>>6);
  if (e >= NE) return;
  const uint2* Ur = (const uint2*)U;
  uint2 r = Ur[(size_t)e*64 + lane];
  int c = (lane & 31)*4;
  float4 w = *(const float4*)&a2A[c];
  float p = bf2f_lo(r.x)*w.x + bf2f_hi(r.x)*w.y + bf2f_lo(r.y)*w.z + bf2f_hi(r.y)*w.w;
  p += __shfl_xor(p, 1, 64); p += __shfl_xor(p, 2, 64); p += __shfl_xor(p, 4, 64);
  p += __shfl_xor(p, 8, 64); p += __shfl_xor(p, 16, 64);
  if ((lane & 31) == 0) sig[2*e + (lane >> 5)] = p;
}

// ---------------- K8c: per-relation score scalar rho ----------------
__global__ __launch_bounds__(256) void k_rho(const float* __restrict__ V,
                                             const float* __restrict__ a2A,
                                             float* __restrict__ rho){
  int lane = threadIdx.x & 63;
  int k = blockIdx.x*4 + (threadIdx.x>>6);
  if (k >= NR) return;
  const float2* Vp = (const float2*)V;
  float2 v = Vp[(size_t)k*64 + lane];
  int c0 = 2*lane;
  float p = v.x*a2A[c0] + v.y*a2A[c0+1];
  p = wredsum(p);
  if (lane == 0) rho[k] = p;
}

// ---------------- K9: entity gather (unroll x4, named) ----------------
__global__ __launch_bounds__(256) void k_gent(const uint2* __restrict__ evE, const int* __restrict__ offE,
                   const unsigned short* __restrict__ U, const float* __restrict__ V,
                   const float* __restrict__ sig, const float* __restrict__ rho,
                   const float* __restrict__ bias,
                   const float* __restrict__ A1, const float* __restrict__ B1,
                   const float* __restrict__ sbase,
                   float* __restrict__ out){
  int lane = threadIdx.x & 63;
  int e = blockIdx.x*4 + (threadIdx.x>>6);
  if (e >= NE) return;
  int c0 = 2*lane, c1 = c0+1;
  const ushort2* Ub = (const ushort2*)U;
  const float2*  Vp = (const float2*)V;
  ushort2 u0 = Ub[(size_t)e*128 + lane];
  float base0 = bf2f(u0.x) + bias[c0], base1 = bf2f(u0.y) + bias[c1];
  float pb  = sbase[1];
  float s0e = sig[2*e];
  float accU0=0.f, accU1=0.f, accV0=0.f, accV1=0.f, sep=0.f;
  int p0 = offE[e], p1 = offE[e+1];
  for (int bs = p0; bs < p1; bs += 64){
    int n = min(64, p1 - bs);
    unsigned ev = 0u; float ebl = 0.f;
    if (bs + lane < p1){
      ev = evE[bs + lane].y;
      int oth = ev >> 10, rl = (ev >> 1) & 0x1FF;
      float sg = (ev & 1) ? -1.f : 1.f;
      float s = s0e + sig[2*oth + 1] + sg*rho[rl] + pb;
      float bb = (s >= 0.f) ? -s : -0.01f*s;
      ebl = expf(bb);
    }
    sep += ebl;
    int j = 0;
    for (; j + 4 <= n; j += 4){
      unsigned e0 = __shfl(ev, j, 64);
      unsigned e1 = __shfl(ev, j+1, 64);
      unsigned e2 = __shfl(ev, j+2, 64);
      unsigned e3 = __shfl(ev, j+3, 64);
      float eb0 = __shfl(ebl, j, 64);
      float eb1 = __shfl(ebl, j+1, 64);
      float eb2 = __shfl(ebl, j+2, 64);
      float eb3 = __shfl(ebl, j+3, 64);
      ushort2 g0 = Ub[(size_t)(e0 >> 10)*128 + 64 + lane];
      ushort2 g1 = Ub[(size_t)(e1 >> 10)*128 + 64 + lane];
      ushort2 g2 = Ub[(size_t)(e2 >> 10)*128 + 64 + lane];
      ushort2 g3 = Ub[(size_t)(e3 >> 10)*128 + 64 + lane];
      float2 v0 = Vp[((e0 >> 1) & 0x1FF)*64 + lane];
      float2 v1 = Vp[((e1 >> 1) & 0x1FF)*64 + lane];
      float2 v2 = Vp[((e2 >> 1) & 0x1FF)*64 + lane];
      float2 v3 = Vp[((e3 >> 1) & 0x1FF)*64 + lane];
      float w0 = (e0 & 1) ? -eb0 : eb0;
      float w1 = (e1 & 1) ? -eb1 : eb1;
      float w2 = (e2 & 1) ? -eb2 : eb2;
      float w3 = (e3 & 1) ? -eb3 : eb3;
      accU0 += eb0*bf2f(g0.x); accU1 += eb0*bf2f(g0.y);
      accV0 += w0*v0.x;        accV1 += w0*v0.y;
      accU0 += eb1*bf2f(g1.x); accU1 += eb1*bf2f(g1.y);
      accV0 += w1*v1.x;        accV1 += w1*v1.y;
      accU0 += eb2*bf2f(g2.x); accU1 += eb2*bf2f(g2.y);
      accV0 += w2*v2.x;        accV1 += w2*v2.y;
      accU0 += eb3*bf2f(g3.x); accU1 += eb3*bf2f(g3.y);
      accV0 += w3*v3.x;        accV1 += w3*v3.y;
    }
    for (; j < n; ++j){
      unsigned e0 = __shfl(ev, j, 64);
      float eb0 = __shfl(ebl, j, 64);
      ushort2 g0 = Ub[(size_t)(e0 >> 10)*128 + 64 + lane];
      float2 v0 = Vp[((e0 >> 1) & 0x1FF)*64 + lane];
      float w0 = (e0 & 1) ? -eb0 : eb0;
      accU0 += eb0*bf2f(g0.x); accU1 += eb0*bf2f(g0.y);
      accV0 += w0*v0.x;        accV1 += w0*v0.y;
    }
  }
  float se = wredsum(sep);
  float sY0 = se*base0 + accU0 + accV0;
  float sY1 = se*base1 + accU1 + accV1;
  float hs0 = A1[c0]*sY0 + B1[c0]*se;
  float hs1 = A1[c1]*sY1 + B1[c1]*se;
  float d = (se == 0.f) ? 1e-12f : se;
  out[(size_t)e*DD + c0] = hs0/d;
  out[(size_t)e*DD + c1] = hs1/d;
}

// ---------------- K10: relation gather — lane-parallel scores + FMA stream ----------------
__global__ __launch_bounds__(256) void k_grel(const uint2* __restrict__ evR, const int* __restrict__ offR,
                   const unsigned short* __restrict__ U, const float* __restrict__ V,
                   const float* __restrict__ sig, const float* __restrict__ rho,
                   const float* __restrict__ bias,
                   const float* __restrict__ A1, const float* __restrict__ B1,
                   const float* __restrict__ sbase,
                   float* __restrict__ out){
  int lane = threadIdx.x & 63;
  int k = blockIdx.x >> 3;
  int wvs = (blockIdx.x & 7)*4 + (threadIdx.x >> 6);   // 0..31
  int c0 = 2*lane, c1 = c0+1;
  const ushort2* Ub = (const ushort2*)U;
  const float2*  Vp = (const float2*)V;
  float2 v = Vp[(size_t)k*64 + lane];
  float vb0 = v.x + bias[c0], vb1 = v.y + bias[c1];
  float rpb = rho[k] + sbase[1];
  float accY0=0.f, accY1=0.f, sep=0.f;
  int p0 = offR[k], p1 = offR[k+1];
  int tot = p1 - p0, per = (tot + 31) >> 5;
  int st = p0 + wvs*per, en = min(st + per, p1);
  for (int bs = st; bs < en; bs += 64){
    int n = min(64, en - bs);
    uint2 ev = make_uint2(0u, 0u); float ebl = 0.f;
    if (bs + lane < en){
      ev = evR[bs + lane];
      float s = sig[2*ev.x] + sig[2*ev.y + 1] + rpb;
      float bb = (s >= 0.f) ? -s : -0.01f*s;
      ebl = expf(bb);
    }
    sep += ebl;
    int j = 0;
    for (; j + 2 <= n; j += 2){
      unsigned a0 = __shfl(ev.x, j, 64),   d0 = __shfl(ev.y, j, 64);
      unsigned a1 = __shfl(ev.x, j+1, 64), d1 = __shfl(ev.y, j+1, 64);
      float eb0 = __shfl(ebl, j, 64);
      float eb1 = __shfl(ebl, j+1, 64);
      ushort2 ua0 = Ub[(size_t)a0*128 + lane];
      ushort2 ud0 = Ub[(size_t)d0*128 + 64 + lane];
      ushort2 ua1 = Ub[(size_t)a1*128 + lane];
      ushort2 ud1 = Ub[(size_t)d1*128 + 64 + lane];
      accY0 += eb0*(bf2f(ua0.x) + bf2f(ud0.x));
      accY1 += eb0*(bf2f(ua0.y) + bf2f(ud0.y));
      accY0 += eb1*(bf2f(ua1.x) + bf2f(ud1.x));
      accY1 += eb1*(bf2f(ua1.y) + bf2f(ud1.y));
    }
    for (; j < n; ++j){
      unsigned a0 = __shfl(ev.x, j, 64), d0 = __shfl(ev.y, j, 64);
      float eb0 = __shfl(ebl, j, 64);
      ushort2 ua0 = Ub[(size_t)a0*128 + lane];
      ushort2 ud0 = Ub[(size_t)d0*128 + 64 + lane];
      accY0 += eb0*(bf2f(ua0.x) + bf2f(ud0.x));
      accY1 += eb0*(bf2f(ua0.y) + bf2f(ud0.y));
    }
  }
  float se = wredsum(sep);
  float sY0 = accY0 + se*vb0;
  float sY1 = accY1 + se*vb1;
  float r0 = A1[c0]*sY0 + B1[c0]*se;
  float r1 = A1[c1]*sY1 + B1[c1]*se;
  atomAddF(&out[(size_t)RELOFF + (size_t)k*DD + c0], r0);
  atomAddF(&out[(size_t)RELOFF + (size_t)k*DD + c1], r1);
}

// ---------------- K11: finalize rel division ----------------
__global__ void k_fin_rel(float* __restrict__ out, const int* __restrict__ cntR){
  int idx = blockIdx.x*blockDim.x + threadIdx.x;   // NR*DD threads
  int k = idx >> 7;
  float c = fmaxf((float)cntR[k], 1.f);
  out[RELOFF + idx] = out[RELOFF + idx] / c;
}

extern "C" void kernel_launch(void* const* d_in, const int* in_sizes, int n_in,
                              void* d_out, int out_size, void* d_ws, size_t ws_size,
                              hipStream_t stream) {
  (void)in_sizes; (void)n_in; (void)ws_size; (void)out_size;
  const int*   trip = (const int*)  d_in[0];
  const float* ent  = (const float*)d_in[1];
  const float* rel  = (const float*)d_in[2];
  const float* aw   = (const float*)d_in[3];
  const float* ab   = (const float*)d_in[4];
  const float* a2w  = (const float*)d_in[5];
  const float* a2b  = (const float*)d_in[6];
  const float* bn0g = (const float*)d_in[7];
  const float* bn0b = (const float*)d_in[8];
  const float* bn1g = (const float*)d_in[9];
  const float* bn1b = (const float*)d_in[10];
  float* out = (float*)d_out;

  char* w = (char*)d_ws;
  size_t off = 0;
  auto take = [&](size_t bytes) -> char* {
    char* p = w + off;
    off = (off + bytes + 511) & ~(size_t)511;
    return p;
  };
  // zeroed region (accumulators)
  float* S        = (float*)take(512);
  float* Q        = (float*)take(512);
  float* colsum   = (float*)take(512);
  float* colsumsq = (float*)take(512);
  int*   cnt      = (int*)  take((size_t)NE*4);
  size_t zero_end = off;
  // non-zeroed (fully overwritten each launch)
  int*   cntR   = (int*)  take((size_t)NR*4);
  float* alpha0 = (float*)take(512);
  float* alpha1 = (float*)take(512);
  float* alpha2 = (float*)take(512);
  float* beta0  = (float*)take(512);
  float* beta1  = (float*)take(512);
  float* biasv  = (float*)take(512);
  float* A1     = (float*)take(512);
  float* B1     = (float*)take(512);
  float* a2A    = (float*)take(512);
  float* sbase  = (float*)take(512);
  float* rho    = (float*)take((size_t)NR*4);
  float* sig    = (float*)take((size_t)NE*2*4);
  int*   offE   = (int*)  take((size_t)(NE+1)*4);
  int*   curE   = (int*)  take((size_t)NE*4);
  int*   offR   = (int*)  take((size_t)(NR+1)*4);
  int*   gHist  = (int*)  take((size_t)NBH*NR*4);
  int*   gBase  = (int*)  take((size_t)NBH*NR*4);
  int*   bsum   = (int*)  take((size_t)NBS*4);
  int*   bbase  = (int*)  take((size_t)NBS*4);
  unsigned long long* evE = (unsigned long long*)take((size_t)NEV*8);
  unsigned long long* evR = (unsigned long long*)take((size_t)NT*8);
  float* V      = (float*)take((size_t)NR*DD*4);
  unsigned short* Wt2 = (unsigned short*)take((size_t)256*128*2);
  unsigned short* U   = (unsigned short*)take((size_t)NE*256*2);

  hipMemsetAsync((char*)d_out + (size_t)RELOFF*4, 0, (size_t)NR*DD*4, stream);
  hipMemsetAsync(d_ws, 0, zero_end, stream);

  k_hist     <<<NBH, 256, 0, stream>>>(trip, cnt, gHist);
  k_histscan <<<1, 512, 0, stream>>>(gHist, gBase, cntR, offR);
  k_scan1    <<<NBS, 1024, 0, stream>>>(cnt, offE, bsum);
  k_scan2    <<<1, 128, 0, stream>>>(bsum, bbase, offE);
  k_scan3    <<<NBS, 1024, 0, stream>>>(offE, curE, bbase);
  k_scat_ent <<<(NT+255)/256, 256, 0, stream>>>(trip, curE, evE);
  k_scat_rel <<<NBH, 256, 0, stream>>>(trip, gBase, evR);
  k_entstats <<<(NE+127)/128, 256, 0, stream>>>(ent, cnt, S, Q);
  k_alpha    <<<1, 128, 0, stream>>>(rel, cntR, S, Q, bn0g, bn0b, alpha0, alpha1, alpha2, beta0, beta1);
  k_bias     <<<128, 128, 0, stream>>>(aw, ab, bn0b, beta0, beta1, biasv);
  k_v        <<<NR, 128, 0, stream>>>(rel, aw, alpha2, V);
  k_wfold2   <<<256, 128, 0, stream>>>(aw, alpha0, alpha1, Wt2);
  k_u2       <<<1563, 256, 0, stream>>>(ent, Wt2, U);
  k_c1b      <<<2048, 256, 0, stream>>>((const uint2*)evE, U, V, biasv, colsum, colsumsq);
  k_bn1fin   <<<1, 128, 0, stream>>>(colsum, colsumsq, bn1g, bn1b, a2w, a2b, biasv, A1, B1, a2A, sbase);
  k_sigma    <<<NE/4, 256, 0, stream>>>(U, a2A, sig);
  k_rho      <<<(NR+3)/4, 256, 0, stream>>>(V, a2A, rho);
  k_gent     <<<NE/4, 256, 0, stream>>>((const uint2*)evE, offE, U, V, sig, rho, biasv, A1, B1, sbase, out);
  k_grel     <<<NR*8, 256, 0, stream>>>((const uint2*)evR, offR, U, V, sig, rho, biasv, A1, B1, sbase, out);
  k_fin_rel  <<<(NR*DD)/256, 256, 0, stream>>>(out, cntR);
}

// Round 10
// 403.940 us; speedup vs baseline: 5.4126x; 1.0393x over previous
//
#include <hip/hip_runtime.h>
#include <hip/hip_bf16.h>

#define NE 100000
#define NR 500
#define DD 128
#define NT 250000
#define NEV 500000             // 2*NT events
#define RELOFF 12800000        // NE*DD
#define TWO_NF 500000.0f
#define NTF 250000.0f
#define TBH 2048
#define NBH ((NT + TBH - 1)/TBH)   // 123
#define NBS ((NE + 1023)/1024)     // 98

typedef __attribute__((ext_vector_type(8))) short short8;
typedef __attribute__((ext_vector_type(4))) float f32x4;

__device__ __forceinline__ float bf2f(unsigned short u){
  unsigned int x = ((unsigned int)u) << 16;
  return __uint_as_float(x);
}
__device__ __forceinline__ float bf2f_lo(unsigned int u){ return __uint_as_float(u << 16); }
__device__ __forceinline__ float bf2f_hi(unsigned int u){ return __uint_as_float(u & 0xFFFF0000u); }
__device__ __forceinline__ unsigned short f2bf(float f){
  __hip_bfloat16 h = __float2bfloat16(f);
  return *reinterpret_cast<unsigned short*>(&h);
}
__device__ __forceinline__ void atomAddF(float* p, float v){ unsafeAtomicAdd(p, v); }
__device__ __forceinline__ float wredsum(float x){
  x += __shfl_xor(x, 1, 64);  x += __shfl_xor(x, 2, 64);  x += __shfl_xor(x, 4, 64);
  x += __shfl_xor(x, 8, 64);  x += __shfl_xor(x, 16, 64); x += __shfl_xor(x, 32, 64);
  return x;
}

// ---------------- K1: per-block rel histogram + entity counts ----------------
__global__ __launch_bounds__(256) void k_hist(const int* __restrict__ trip,
                                              int* __restrict__ cnt, int* __restrict__ gHist){
  __shared__ int h[NR];
  int t = threadIdx.x;
  for (int r = t; r < NR; r += 256) h[r] = 0;
  __syncthreads();
  int b0 = blockIdx.x*TBH, b1 = min(b0+TBH, NT);
  for (int i = b0 + t; i < b1; i += 256){
    int t0 = trip[3*i], t1 = trip[3*i+1], t2 = trip[3*i+2];
    atomicAdd(&cnt[t0], 1);
    atomicAdd(&cnt[t1], 1);
    atomicAdd(&h[t2], 1);
  }
  __syncthreads();
  for (int r = t; r < NR; r += 256) gHist[blockIdx.x*NR + r] = h[r];
}

// ---------------- K1b: column-scan hists -> per-(block,rel) base, cntR, offR ----------------
__global__ __launch_bounds__(512) void k_histscan(const int* __restrict__ gHist,
                                                  int* __restrict__ base, int* __restrict__ cntR,
                                                  int* __restrict__ offR){
  __shared__ int sm[512];
  int r = threadIdx.x;
  int s = 0;
  if (r < NR){
    for (int b = 0; b < NBH; ++b){ base[b*NR + r] = s; s += gHist[b*NR + r]; }
    cntR[r] = s;
  }
  sm[r] = (r < NR) ? s : 0;
  __syncthreads();
  for (int st = 1; st < 512; st <<= 1){
    int x = (r >= st) ? sm[r-st] : 0;
    __syncthreads();
    sm[r] += x;
    __syncthreads();
  }
  if (r < NR){
    int off = sm[r] - s;               // exclusive
    offR[r] = off;
    for (int b = 0; b < NBH; ++b) base[b*NR + r] += off;
  }
  if (r == 0) offR[NR] = NT;
}

// ---------------- device-wide entity scan: phase 1 (block-local) ----------------
__global__ __launch_bounds__(1024) void k_scan1(const int* __restrict__ cnt,
                                                int* __restrict__ off, int* __restrict__ bsum){
  __shared__ int wsum[16];
  int t = threadIdx.x, lane = t & 63, w = t >> 6;
  int i = blockIdx.x*1024 + t;
  int v = (i < NE) ? cnt[i] : 0;
  int x = v;
  #pragma unroll
  for (int s = 1; s < 64; s <<= 1){ int y = __shfl_up(x, s, 64); if (lane >= s) x += y; }
  if (lane == 63) wsum[w] = x;
  __syncthreads();
  if (w == 0 && lane < 16){
    int xs = wsum[lane];
    #pragma unroll
    for (int s = 1; s < 16; s <<= 1){ int y = __shfl_up(xs, s, 16); if ((lane & 15) >= s) xs += y; }
    wsum[lane] = xs;
  }
  __syncthreads();
  int wprev = (w == 0) ? 0 : wsum[w-1];
  int incl = wprev + x;
  if (i < NE) off[i] = incl - v;          // block-local exclusive
  if (t == 1023) bsum[blockIdx.x] = incl; // block total
}

// ---------------- device-wide entity scan: phase 2 (scan 98 block totals) ----------------
__global__ __launch_bounds__(128) void k_scan2(const int* __restrict__ bsum,
                                               int* __restrict__ bbase, int* __restrict__ off){
  __shared__ int sm[128];
  int t = threadIdx.x;
  int v = (t < NBS) ? bsum[t] : 0;
  sm[t] = v; __syncthreads();
  for (int s = 1; s < 128; s <<= 1){
    int x = (t >= s) ? sm[t-s] : 0;
    __syncthreads();
    sm[t] += x;
    __syncthreads();
  }
  int incl = sm[t];
  if (t < NBS) bbase[t] = incl - v;
  if (t == NBS-1) off[NE] = incl;
}

// ---------------- device-wide entity scan: phase 3 (add base, write cur) ----------------
__global__ __launch_bounds__(1024) void k_scan3(int* __restrict__ off, int* __restrict__ cur,
                                                const int* __restrict__ bbase){
  int i = blockIdx.x*1024 + threadIdx.x;
  if (i < NE){
    int o = off[i] + bbase[blockIdx.x];
    off[i] = o;
    cur[i] = o;
  }
}

// ---------------- scatter entity events (global cursors, nt stores) ----------------
__global__ void k_scat_ent(const int* __restrict__ trip, int* __restrict__ curE,
                           unsigned long long* __restrict__ evE){
  int i = blockIdx.x*blockDim.x + threadIdx.x;
  if (i < NT){
    int t0 = trip[3*i+0], t1 = trip[3*i+1], t2 = trip[3*i+2];
    int p0 = atomicAdd(&curE[t0], 1);
    unsigned long long e0 = (unsigned)t0 |
      ((unsigned long long)(((unsigned)t1 << 10) | ((unsigned)t2 << 1)) << 32);
    __builtin_nontemporal_store(e0, &evE[p0]);
    int p1 = atomicAdd(&curE[t1], 1);
    unsigned long long e1 = (unsigned)t1 |
      ((unsigned long long)(((unsigned)t0 << 10) | ((unsigned)t2 << 1) | 1u) << 32);
    __builtin_nontemporal_store(e1, &evE[p1]);
  }
}

// ---------------- scatter rel events (LDS cursors, deterministic bases) ----------------
__global__ __launch_bounds__(256) void k_scat_rel(const int* __restrict__ trip,
                                                  const int* __restrict__ base,
                                                  unsigned long long* __restrict__ evR){
  __shared__ int cur[NR];
  int t = threadIdx.x;
  for (int r = t; r < NR; r += 256) cur[r] = base[blockIdx.x*NR + r];
  __syncthreads();
  int b0 = blockIdx.x*TBH, b1 = min(b0+TBH, NT);
  for (int i = b0 + t; i < b1; i += 256){
    int t0 = trip[3*i], t1 = trip[3*i+1], t2 = trip[3*i+2];
    int p = atomicAdd(&cur[t2], 1);
    unsigned long long e = (unsigned)t0 | ((unsigned long long)(unsigned)t1 << 32);
    __builtin_nontemporal_store(e, &evR[p]);
  }
}

// ---------------- K2: entity column stats + fused X->bf16 convert ----------------
__global__ __launch_bounds__(256) void k_entstats(const float* __restrict__ ent, const int* __restrict__ cnt,
                                                  float* __restrict__ S, float* __restrict__ Q,
                                                  unsigned short* __restrict__ Xbf){
  int j = threadIdx.x & 127;
  int half = threadIdx.x >> 7;
  int r0 = blockIdx.x*128 + half;
  int r1 = min(blockIdx.x*128 + 128, NE);
  float s = 0.f, q = 0.f;
  for (int r = r0; r < r1; r += 2){
    float x = ent[(size_t)r*DD + j];
    Xbf[(size_t)r*DD + j] = f2bf(x);
    int w = cnt[r];
    if (w){
      float wf = (float)w;
      s += wf*x; q += wf*x*x;
    }
  }
  __shared__ float ss[256], qq[256];
  ss[threadIdx.x] = s; qq[threadIdx.x] = q; __syncthreads();
  if (half == 0){
    atomAddF(&S[j], ss[j] + ss[j+128]);
    atomAddF(&Q[j], qq[j] + qq[j+128]);
  }
}

// ---------------- K3: BN0 fold + rel variance ----------------
__global__ void k_alpha(const float* __restrict__ rel, const int* __restrict__ cntR,
                        const float* __restrict__ S, const float* __restrict__ Q,
                        const float* __restrict__ bn0g, const float* __restrict__ bn0b,
                        float* __restrict__ alpha0, float* __restrict__ alpha1, float* __restrict__ alpha2,
                        float* __restrict__ beta0, float* __restrict__ beta1){
  int j = threadIdx.x;
  float qr = 0.f;
  for (int k = 0; k < NR; ++k){
    float w = (float)cntR[k];
    float x = rel[k*DD + j];
    qr += w*x*x;
  }
  float mean = S[j] / TWO_NF;
  float var  = Q[j] / TWO_NF - mean*mean;
  float inv  = rsqrtf(var + 1e-5f);
  float a0 = inv * bn0g[j];
  float a1 = inv * bn0g[128+j];
  alpha0[j] = a0; alpha1[j] = a1;
  beta0[j] = bn0b[j]     - mean*a0;
  beta1[j] = bn0b[128+j] - mean*a1;
  float varR = qr / NTF;
  alpha2[j] = rsqrtf(varR + 1e-5f) * bn0g[256+j];
}

// ---------------- K4: folded bias vector ----------------
__global__ void k_bias(const float* __restrict__ aw, const float* __restrict__ ab,
                       const float* __restrict__ bn0b,
                       const float* __restrict__ beta0, const float* __restrict__ beta1,
                       float* __restrict__ bias){
  int o = blockIdx.x, j = threadIdx.x;
  const float* r = aw + (size_t)o*384;
  float p = r[j]*beta0[j] + r[128+j]*beta1[j] + r[256+j]*bn0b[256+j];
  __shared__ float sm[128];
  sm[j] = p; __syncthreads();
  for (int s = 64; s > 0; s >>= 1){ if (j < s) sm[j] += sm[j+s]; __syncthreads(); }
  if (j == 0) bias[o] = ab[o] + sm[0];
}

// ---------------- K5: V table ----------------
__global__ void k_v(const float* __restrict__ rel, const float* __restrict__ aw,
                    const float* __restrict__ alpha2, float* __restrict__ V){
  int k = blockIdx.x, o = threadIdx.x;
  __shared__ float rl[128];
  rl[o] = rel[k*DD + o] * alpha2[o];
  __syncthreads();
  float acc = 0.f;
  #pragma unroll 8
  for (int j = 0; j < 128; ++j) acc += aw[(size_t)o*384 + 256 + j] * rl[j];
  V[k*DD + o] = acc;
}

// ---------------- K5b: fold W' into bf16 table Wt2[o][k] (B-operand layout) ----------------
__global__ void k_wfold2(const float* __restrict__ aw, const float* __restrict__ alpha0,
                         const float* __restrict__ alpha1, unsigned short* __restrict__ Wt2){
  int o = blockIdx.x;        // 0..255
  int k = threadIdx.x;       // 0..127
  float w;
  if (o < 128) w = aw[(size_t)o*384 + k] * alpha0[k];
  else         w = aw[(size_t)(o-128)*384 + 128 + k] * alpha1[k];
  Wt2[(size_t)o*128 + k] = f2bf(w);
}

// ---------------- K6: U table via MFMA (bf16 X input, no LDS, direct stores) ----------------
__global__ __launch_bounds__(256) void k_u2(const unsigned short* __restrict__ Xbf,
                                            const unsigned short* __restrict__ Wt2,
                                            unsigned short* __restrict__ Uo){
  int tid = threadIdx.x;
  int w = tid >> 6, l = tid & 63;
  int col = l & 15, grp = l >> 4, kof = grp*8;
  int e0w = (blockIdx.x*4 + w)*16;           // 1563 blocks * 64 = 100032
  int e = min(e0w + col, NE-1);
  const unsigned short* xrow = Xbf + (size_t)e*DD;
  short8 a0v = *(const short8*)(xrow + kof);
  short8 a1v = *(const short8*)(xrow + 32 + kof);
  short8 a2v = *(const short8*)(xrow + 64 + kof);
  short8 a3v = *(const short8*)(xrow + 96 + kof);

  f32x4 acc[16];
  #pragma unroll
  for (int ot = 0; ot < 16; ++ot) acc[ot] = (f32x4){0.f, 0.f, 0.f, 0.f};

  #pragma unroll
  for (int ot = 0; ot < 16; ++ot){
    const unsigned short* bbase = Wt2 + (size_t)(ot*16 + col)*128 + kof;
    short8 b0 = *(const short8*)(bbase);
    short8 b1 = *(const short8*)(bbase + 32);
    short8 b2 = *(const short8*)(bbase + 64);
    short8 b3 = *(const short8*)(bbase + 96);
    acc[ot] = __builtin_amdgcn_mfma_f32_16x16x32_bf16(a0v, b0, acc[ot], 0, 0, 0);
    acc[ot] = __builtin_amdgcn_mfma_f32_16x16x32_bf16(a1v, b1, acc[ot], 0, 0, 0);
    acc[ot] = __builtin_amdgcn_mfma_f32_16x16x32_bf16(a2v, b2, acc[ot], 0, 0, 0);
    acc[ot] = __builtin_amdgcn_mfma_f32_16x16x32_bf16(a3v, b3, acc[ot], 0, 0, 0);
  }

  // direct stores: lane (grp,col) holds D[4*grp+r][ot*16+col]
  #pragma unroll
  for (int ot = 0; ot < 16; ++ot){
    #pragma unroll
    for (int r = 0; r < 4; ++r){
      int row = e0w + 4*grp + r;
      if (row < NE)
        Uo[(size_t)row*256 + ot*16 + col] = f2bf(acc[ot][r]);
    }
  }
}

// ---------------- K7: BN1 column stats over CSR events (unroll x4, named) ----------------
__global__ __launch_bounds__(256) void k_c1b(const uint2* __restrict__ evE,
                   const unsigned short* __restrict__ U, const float* __restrict__ V,
                   const float* __restrict__ bias,
                   float* __restrict__ colsum, float* __restrict__ colsumsq){
  int lane = threadIdx.x & 63;
  int w = threadIdx.x >> 6;
  int wv = blockIdx.x*4 + w;
  int nwv = gridDim.x*4;
  int per = (NEV + nwv - 1) / nwv;
  int st = wv*per, en = min(st + per, NEV);
  int c0 = 2*lane, c1 = c0+1;
  float b0 = bias[c0], b1 = bias[c1];
  const ushort2* Ub = (const ushort2*)U;
  const float2*  Vp = (const float2*)V;
  float s0=0.f, s1=0.f, q0=0.f, q1=0.f;
  for (int bs = st; bs < en; bs += 64){
    int n = min(64, en - bs);
    uint2 ev = (bs + lane < en) ? evE[bs + lane] : make_uint2(0u, 0u);
    int j = 0;
    for (; j + 4 <= n; j += 4){
      unsigned ow0 = __shfl(ev.x, j, 64),   pk0 = __shfl(ev.y, j, 64);
      unsigned ow1 = __shfl(ev.x, j+1, 64), pk1 = __shfl(ev.y, j+1, 64);
      unsigned ow2 = __shfl(ev.x, j+2, 64), pk2 = __shfl(ev.y, j+2, 64);
      unsigned ow3 = __shfl(ev.x, j+3, 64), pk3 = __shfl(ev.y, j+3, 64);
      ushort2 a0 = Ub[(size_t)ow0*128 + lane];
      ushort2 g0 = Ub[(size_t)(pk0 >> 10)*128 + 64 + lane];
      float2  v0 = Vp[((pk0 >> 1) & 0x1FF)*64 + lane];
      ushort2 a1 = Ub[(size_t)ow1*128 + lane];
      ushort2 g1 = Ub[(size_t)(pk1 >> 10)*128 + 64 + lane];
      float2  v1 = Vp[((pk1 >> 1) & 0x1FF)*64 + lane];
      ushort2 a2 = Ub[(size_t)ow2*128 + lane];
      ushort2 g2 = Ub[(size_t)(pk2 >> 10)*128 + 64 + lane];
      float2  v2 = Vp[((pk2 >> 1) & 0x1FF)*64 + lane];
      ushort2 a3 = Ub[(size_t)ow3*128 + lane];
      ushort2 g3 = Ub[(size_t)(pk3 >> 10)*128 + 64 + lane];
      float2  v3 = Vp[((pk3 >> 1) & 0x1FF)*64 + lane];
      float sg0 = (pk0 & 1) ? -1.f : 1.f;
      float sg1 = (pk1 & 1) ? -1.f : 1.f;
      float sg2 = (pk2 & 1) ? -1.f : 1.f;
      float sg3 = (pk3 & 1) ? -1.f : 1.f;
      float y00 = bf2f(a0.x) + bf2f(g0.x) + sg0*v0.x + b0;
      float y01 = bf2f(a0.y) + bf2f(g0.y) + sg0*v0.y + b1;
      float y10 = bf2f(a1.x) + bf2f(g1.x) + sg1*v1.x + b0;
      float y11 = bf2f(a1.y) + bf2f(g1.y) + sg1*v1.y + b1;
      float y20 = bf2f(a2.x) + bf2f(g2.x) + sg2*v2.x + b0;
      float y21 = bf2f(a2.y) + bf2f(g2.y) + sg2*v2.y + b1;
      float y30 = bf2f(a3.x) + bf2f(g3.x) + sg3*v3.x + b0;
      float y31 = bf2f(a3.y) + bf2f(g3.y) + sg3*v3.y + b1;
      s0 += y00 + y10 + y20 + y30;
      s1 += y01 + y11 + y21 + y31;
      q0 += y00*y00 + y10*y10 + y20*y20 + y30*y30;
      q1 += y01*y01 + y11*y11 + y21*y21 + y31*y31;
    }
    for (; j < n; ++j){
      unsigned ow0 = __shfl(ev.x, j, 64), pk0 = __shfl(ev.y, j, 64);
      ushort2 a0 = Ub[(size_t)ow0*128 + lane];
      ushort2 g0 = Ub[(size_t)(pk0 >> 10)*128 + 64 + lane];
      float2  v0 = Vp[((pk0 >> 1) & 0x1FF)*64 + lane];
      float sg0 = (pk0 & 1) ? -1.f : 1.f;
      float y00 = bf2f(a0.x) + bf2f(g0.x) + sg0*v0.x + b0;
      float y01 = bf2f(a0.y) + bf2f(g0.y) + sg0*v0.y + b1;
      s0 += y00;  q0 += y00*y00;
      s1 += y01;  q1 += y01*y01;
    }
  }
  __shared__ float sred[4][128], qred[4][128];
  sred[w][c0] = s0; sred[w][c1] = s1;
  qred[w][c0] = q0; qred[w][c1] = q1;
  __syncthreads();
  int t = threadIdx.x;
  if (t < 128){
    atomAddF(&colsum[t],   sred[0][t] + sred[1][t] + sred[2][t] + sred[3][t]);
    atomAddF(&colsumsq[t], qred[0][t] + qred[1][t] + qred[2][t] + qred[3][t]);
  }
}

// ---------------- K8: BN1 fold + a2 fold + pbsb ----------------
__global__ void k_bn1fin(const float* __restrict__ colsum, const float* __restrict__ colsumsq,
                         const float* __restrict__ bn1g, const float* __restrict__ bn1b,
                         const float* __restrict__ a2w, const float* __restrict__ a2b,
                         const float* __restrict__ biasv,
                         float* __restrict__ A1, float* __restrict__ B1,
                         float* __restrict__ a2A, float* __restrict__ sbase){
  int j = threadIdx.x;
  float mean = colsum[j] / TWO_NF;
  float var  = colsumsq[j] / TWO_NF - mean*mean;
  float A = rsqrtf(var + 1e-5f) * bn1g[j];
  float B = bn1b[j] - mean*A;
  A1[j] = A; B1[j] = B;
  float w2 = a2w[j];
  float aA = w2*A;
  a2A[j] = aA;
  __shared__ float sm[128], sm2[128];
  sm[j] = w2*B; sm2[j] = biasv[j]*aA;
  __syncthreads();
  for (int s = 64; s > 0; s >>= 1){
    if (j < s){ sm[j] += sm[j+s]; sm2[j] += sm2[j+s]; }
    __syncthreads();
  }
  if (j == 0){
    float sb = a2b[0] + sm[0];
    sbase[0] = sb;
    sbase[1] = sb + sm2[0];   // pbsb = dot(bias,a2A) + sbase
  }
}

// ---------------- K8b: per-entity score scalars sigma0/sigma1 ----------------
__global__ __launch_bounds__(256) void k_sigma(const unsigned short* __restrict__ U,
                                               const float* __restrict__ a2A,
                                               float* __restrict__ sig){
  int lane = threadIdx.x & 63;
  int e = blockIdx.x*4 + (threadIdx.x>>6);
  if (e >= NE) return;
  const uint2* Ur = (const uint2*)U;
  uint2 r = Ur[(size_t)e*64 + lane];
  int c = (lane & 31)*4;
  float4 w = *(const float4*)&a2A[c];
  float p = bf2f_lo(r.x)*w.x + bf2f_hi(r.x)*w.y + bf2f_lo(r.y)*w.z + bf2f_hi(r.y)*w.w;
  p += __shfl_xor(p, 1, 64); p += __shfl_xor(p, 2, 64); p += __shfl_xor(p, 4, 64);
  p += __shfl_xor(p, 8, 64); p += __shfl_xor(p, 16, 64);
  if ((lane & 31) == 0) sig[2*e + (lane >> 5)] = p;
}

// ---------------- K8c: per-relation score scalar rho ----------------
__global__ __launch_bounds__(256) void k_rho(const float* __restrict__ V,
                                             const float* __restrict__ a2A,
                                             float* __restrict__ rho){
  int lane = threadIdx.x & 63;
  int k = blockIdx.x*4 + (threadIdx.x>>6);
  if (k >= NR) return;
  const float2* Vp = (const float2*)V;
  float2 v = Vp[(size_t)k*64 + lane];
  int c0 = 2*lane;
  float p = v.x*a2A[c0] + v.y*a2A[c0+1];
  p = wredsum(p);
  if (lane == 0) rho[k] = p;
}

// ---------------- K9: entity gather (unroll x4, named) ----------------
__global__ __launch_bounds__(256) void k_gent(const uint2* __restrict__ evE, const int* __restrict__ offE,
                   const unsigned short* __restrict__ U, const float* __restrict__ V,
                   const float* __restrict__ sig, const float* __restrict__ rho,
                   const float* __restrict__ bias,
                   const float* __restrict__ A1, const float* __restrict__ B1,
                   const float* __restrict__ sbase,
                   float* __restrict__ out){
  int lane = threadIdx.x & 63;
  int e = blockIdx.x*4 + (threadIdx.x>>6);
  if (e >= NE) return;
  int c0 = 2*lane, c1 = c0+1;
  const ushort2* Ub = (const ushort2*)U;
  const float2*  Vp = (const float2*)V;
  ushort2 u0 = Ub[(size_t)e*128 + lane];
  float base0 = bf2f(u0.x) + bias[c0], base1 = bf2f(u0.y) + bias[c1];
  float pb  = sbase[1];
  float s0e = sig[2*e];
  float accU0=0.f, accU1=0.f, accV0=0.f, accV1=0.f, sep=0.f;
  int p0 = offE[e], p1 = offE[e+1];
  for (int bs = p0; bs < p1; bs += 64){
    int n = min(64, p1 - bs);
    unsigned ev = 0u; float ebl = 0.f;
    if (bs + lane < p1){
      ev = evE[bs + lane].y;
      int oth = ev >> 10, rl = (ev >> 1) & 0x1FF;
      float sg = (ev & 1) ? -1.f : 1.f;
      float s = s0e + sig[2*oth + 1] + sg*rho[rl] + pb;
      float bb = (s >= 0.f) ? -s : -0.01f*s;
      ebl = expf(bb);
    }
    sep += ebl;
    int j = 0;
    for (; j + 4 <= n; j += 4){
      unsigned e0 = __shfl(ev, j, 64);
      unsigned e1 = __shfl(ev, j+1, 64);
      unsigned e2 = __shfl(ev, j+2, 64);
      unsigned e3 = __shfl(ev, j+3, 64);
      float eb0 = __shfl(ebl, j, 64);
      float eb1 = __shfl(ebl, j+1, 64);
      float eb2 = __shfl(ebl, j+2, 64);
      float eb3 = __shfl(ebl, j+3, 64);
      ushort2 g0 = Ub[(size_t)(e0 >> 10)*128 + 64 + lane];
      ushort2 g1 = Ub[(size_t)(e1 >> 10)*128 + 64 + lane];
      ushort2 g2 = Ub[(size_t)(e2 >> 10)*128 + 64 + lane];
      ushort2 g3 = Ub[(size_t)(e3 >> 10)*128 + 64 + lane];
      float2 v0 = Vp[((e0 >> 1) & 0x1FF)*64 + lane];
      float2 v1 = Vp[((e1 >> 1) & 0x1FF)*64 + lane];
      float2 v2 = Vp[((e2 >> 1) & 0x1FF)*64 + lane];
      float2 v3 = Vp[((e3 >> 1) & 0x1FF)*64 + lane];
      float w0 = (e0 & 1) ? -eb0 : eb0;
      float w1 = (e1 & 1) ? -eb1 : eb1;
      float w2 = (e2 & 1) ? -eb2 : eb2;
      float w3 = (e3 & 1) ? -eb3 : eb3;
      accU0 += eb0*bf2f(g0.x); accU1 += eb0*bf2f(g0.y);
      accV0 += w0*v0.x;        accV1 += w0*v0.y;
      accU0 += eb1*bf2f(g1.x); accU1 += eb1*bf2f(g1.y);
      accV0 += w1*v1.x;        accV1 += w1*v1.y;
      accU0 += eb2*bf2f(g2.x); accU1 += eb2*bf2f(g2.y);
      accV0 += w2*v2.x;        accV1 += w2*v2.y;
      accU0 += eb3*bf2f(g3.x); accU1 += eb3*bf2f(g3.y);
      accV0 += w3*v3.x;        accV1 += w3*v3.y;
    }
    for (; j < n; ++j){
      unsigned e0 = __shfl(ev, j, 64);
      float eb0 = __shfl(ebl, j, 64);
      ushort2 g0 = Ub[(size_t)(e0 >> 10)*128 + 64 + lane];
      float2 v0 = Vp[((e0 >> 1) & 0x1FF)*64 + lane];
      float w0 = (e0 & 1) ? -eb0 : eb0;
      accU0 += eb0*bf2f(g0.x); accU1 += eb0*bf2f(g0.y);
      accV0 += w0*v0.x;        accV1 += w0*v0.y;
    }
  }
  float se = wredsum(sep);
  float sY0 = se*base0 + accU0 + accV0;
  float sY1 = se*base1 + accU1 + accV1;
  float hs0 = A1[c0]*sY0 + B1[c0]*se;
  float hs1 = A1[c1]*sY1 + B1[c1]*se;
  float d = (se == 0.f) ? 1e-12f : se;
  out[(size_t)e*DD + c0] = hs0/d;
  out[(size_t)e*DD + c1] = hs1/d;
}

// ---------------- K10: relation gather — lane-parallel scores + FMA stream ----------------
__global__ __launch_bounds__(256) void k_grel(const uint2* __restrict__ evR, const int* __restrict__ offR,
                   const unsigned short* __restrict__ U, const float* __restrict__ V,
                   const float* __restrict__ sig, const float* __restrict__ rho,
                   const float* __restrict__ bias,
                   const float* __restrict__ A1, const float* __restrict__ B1,
                   const float* __restrict__ sbase,
                   float* __restrict__ out){
  int lane = threadIdx.x & 63;
  int k = blockIdx.x >> 3;
  int wvs = (blockIdx.x & 7)*4 + (threadIdx.x >> 6);   // 0..31
  int c0 = 2*lane, c1 = c0+1;
  const ushort2* Ub = (const ushort2*)U;
  const float2*  Vp = (const float2*)V;
  float2 v = Vp[(size_t)k*64 + lane];
  float vb0 = v.x + bias[c0], vb1 = v.y + bias[c1];
  float rpb = rho[k] + sbase[1];
  float accY0=0.f, accY1=0.f, sep=0.f;
  int p0 = offR[k], p1 = offR[k+1];
  int tot = p1 - p0, per = (tot + 31) >> 5;
  int st = p0 + wvs*per, en = min(st + per, p1);
  for (int bs = st; bs < en; bs += 64){
    int n = min(64, en - bs);
    uint2 ev = make_uint2(0u, 0u); float ebl = 0.f;
    if (bs + lane < en){
      ev = evR[bs + lane];
      float s = sig[2*ev.x] + sig[2*ev.y + 1] + rpb;
      float bb = (s >= 0.f) ? -s : -0.01f*s;
      ebl = expf(bb);
    }
    sep += ebl;
    int j = 0;
    for (; j + 2 <= n; j += 2){
      unsigned a0 = __shfl(ev.x, j, 64),   d0 = __shfl(ev.y, j, 64);
      unsigned a1 = __shfl(ev.x, j+1, 64), d1 = __shfl(ev.y, j+1, 64);
      float eb0 = __shfl(ebl, j, 64);
      float eb1 = __shfl(ebl, j+1, 64);
      ushort2 ua0 = Ub[(size_t)a0*128 + lane];
      ushort2 ud0 = Ub[(size_t)d0*128 + 64 + lane];
      ushort2 ua1 = Ub[(size_t)a1*128 + lane];
      ushort2 ud1 = Ub[(size_t)d1*128 + 64 + lane];
      accY0 += eb0*(bf2f(ua0.x) + bf2f(ud0.x));
      accY1 += eb0*(bf2f(ua0.y) + bf2f(ud0.y));
      accY0 += eb1*(bf2f(ua1.x) + bf2f(ud1.x));
      accY1 += eb1*(bf2f(ua1.y) + bf2f(ud1.y));
    }
    for (; j < n; ++j){
      unsigned a0 = __shfl(ev.x, j, 64), d0 = __shfl(ev.y, j, 64);
      float eb0 = __shfl(ebl, j, 64);
      ushort2 ua0 = Ub[(size_t)a0*128 + lane];
      ushort2 ud0 = Ub[(size_t)d0*128 + 64 + lane];
      accY0 += eb0*(bf2f(ua0.x) + bf2f(ud0.x));
      accY1 += eb0*(bf2f(ua0.y) + bf2f(ud0.y));
    }
  }
  float se = wredsum(sep);
  float sY0 = accY0 + se*vb0;
  float sY1 = accY1 + se*vb1;
  float r0 = A1[c0]*sY0 + B1[c0]*se;
  float r1 = A1[c1]*sY1 + B1[c1]*se;
  atomAddF(&out[(size_t)RELOFF + (size_t)k*DD + c0], r0);
  atomAddF(&out[(size_t)RELOFF + (size_t)k*DD + c1], r1);
}

// ---------------- K11: finalize rel division ----------------
__global__ void k_fin_rel(float* __restrict__ out, const int* __restrict__ cntR){
  int idx = blockIdx.x*blockDim.x + threadIdx.x;   // NR*DD threads
  int k = idx >> 7;
  float c = fmaxf((float)cntR[k], 1.f);
  out[RELOFF + idx] = out[RELOFF + idx] / c;
}

extern "C" void kernel_launch(void* const* d_in, const int* in_sizes, int n_in,
                              void* d_out, int out_size, void* d_ws, size_t ws_size,
                              hipStream_t stream) {
  (void)in_sizes; (void)n_in; (void)ws_size; (void)out_size;
  const int*   trip = (const int*)  d_in[0];
  const float* ent  = (const float*)d_in[1];
  const float* rel  = (const float*)d_in[2];
  const float* aw   = (const float*)d_in[3];
  const float* ab   = (const float*)d_in[4];
  const float* a2w  = (const float*)d_in[5];
  const float* a2b  = (const float*)d_in[6];
  const float* bn0g = (const float*)d_in[7];
  const float* bn0b = (const float*)d_in[8];
  const float* bn1g = (const float*)d_in[9];
  const float* bn1b = (const float*)d_in[10];
  float* out = (float*)d_out;
  // Xbf scratch lives in the entity half of d_out (overwritten later by k_gent)
  unsigned short* Xbf = (unsigned short*)d_out;

  char* w = (char*)d_ws;
  size_t off = 0;
  auto take = [&](size_t bytes) -> char* {
    char* p = w + off;
    off = (off + bytes + 511) & ~(size_t)511;
    return p;
  };
  // zeroed region (accumulators)
  float* S        = (float*)take(512);
  float* Q        = (float*)take(512);
  float* colsum   = (float*)take(512);
  float* colsumsq = (float*)take(512);
  int*   cnt      = (int*)  take((size_t)NE*4);
  size_t zero_end = off;
  // non-zeroed (fully overwritten each launch)
  int*   cntR   = (int*)  take((size_t)NR*4);
  float* alpha0 = (float*)take(512);
  float* alpha1 = (float*)take(512);
  float* alpha2 = (float*)take(512);
  float* beta0  = (float*)take(512);
  float* beta1  = (float*)take(512);
  float* biasv  = (float*)take(512);
  float* A1     = (float*)take(512);
  float* B1     = (float*)take(512);
  float* a2A    = (float*)take(512);
  float* sbase  = (float*)take(512);
  float* rho    = (float*)take((size_t)NR*4);
  float* sig    = (float*)take((size_t)NE*2*4);
  int*   offE   = (int*)  take((size_t)(NE+1)*4);
  int*   curE   = (int*)  take((size_t)NE*4);
  int*   offR   = (int*)  take((size_t)(NR+1)*4);
  int*   gHist  = (int*)  take((size_t)NBH*NR*4);
  int*   gBase  = (int*)  take((size_t)NBH*NR*4);
  int*   bsum   = (int*)  take((size_t)NBS*4);
  int*   bbase  = (int*)  take((size_t)NBS*4);
  unsigned long long* evE = (unsigned long long*)take((size_t)NEV*8);
  unsigned long long* evR = (unsigned long long*)take((size_t)NT*8);
  float* V      = (float*)take((size_t)NR*DD*4);
  unsigned short* Wt2 = (unsigned short*)take((size_t)256*128*2);
  unsigned short* U   = (unsigned short*)take((size_t)NE*256*2);

  hipMemsetAsync((char*)d_out + (size_t)RELOFF*4, 0, (size_t)NR*DD*4, stream);
  hipMemsetAsync(d_ws, 0, zero_end, stream);

  k_hist     <<<NBH, 256, 0, stream>>>(trip, cnt, gHist);
  k_histscan <<<1, 512, 0, stream>>>(gHist, gBase, cntR, offR);
  k_scan1    <<<NBS, 1024, 0, stream>>>(cnt, offE, bsum);
  k_scan2    <<<1, 128, 0, stream>>>(bsum, bbase, offE);
  k_scan3    <<<NBS, 1024, 0, stream>>>(offE, curE, bbase);
  k_scat_ent <<<(NT+255)/256, 256, 0, stream>>>(trip, curE, evE);
  k_scat_rel <<<NBH, 256, 0, stream>>>(trip, gBase, evR);
  k_entstats <<<(NE+127)/128, 256, 0, stream>>>(ent, cnt, S, Q, Xbf);
  k_alpha    <<<1, 128, 0, stream>>>(rel, cntR, S, Q, bn0g, bn0b, alpha0, alpha1, alpha2, beta0, beta1);
  k_bias     <<<128, 128, 0, stream>>>(aw, ab, bn0b, beta0, beta1, biasv);
  k_v        <<<NR, 128, 0, stream>>>(rel, aw, alpha2, V);
  k_wfold2   <<<256, 128, 0, stream>>>(aw, alpha0, alpha1, Wt2);
  k_u2       <<<1563, 256, 0, stream>>>(Xbf, Wt2, U);
  k_c1b      <<<2048, 256, 0, stream>>>((const uint2*)evE, U, V, biasv, colsum, colsumsq);
  k_bn1fin   <<<1, 128, 0, stream>>>(colsum, colsumsq, bn1g, bn1b, a2w, a2b, biasv, A1, B1, a2A, sbase);
  k_sigma    <<<NE/4, 256, 0, stream>>>(U, a2A, sig);
  k_rho      <<<(NR+3)/4, 256, 0, stream>>>(V, a2A, rho);
  k_gent     <<<NE/4, 256, 0, stream>>>((const uint2*)evE, offE, U, V, sig, rho, biasv, A1, B1, sbase, out);
  k_grel     <<<NR*8, 256, 0, stream>>>((const uint2*)evR, offR, U, V, sig, rho, biasv, A1, B1, sbase, out);
  k_fin_rel  <<<(NR*DD)/256, 256, 0, stream>>>(out, cntR);
}

// Round 11
// 375.881 us; speedup vs baseline: 5.8166x; 1.0746x over previous
//
#include <hip/hip_runtime.h>
#include <hip/hip_bf16.h>

#define NE 100000
#define NR 500
#define DD 128
#define NT 250000
#define NEV 500000             // 2*NT events
#define RELOFF 12800000        // NE*DD
#define TWO_NF 500000.0f
#define NTF 250000.0f
#define TBH 2048
#define NBH ((NT + TBH - 1)/TBH)   // 123
#define NBS ((NE + 1023)/1024)     // 98

typedef __attribute__((ext_vector_type(8))) short short8;
typedef __attribute__((ext_vector_type(4))) float f32x4;

__device__ __forceinline__ float bf2f(unsigned short u){
  unsigned int x = ((unsigned int)u) << 16;
  return __uint_as_float(x);
}
__device__ __forceinline__ float bf2f_lo(unsigned int u){ return __uint_as_float(u << 16); }
__device__ __forceinline__ float bf2f_hi(unsigned int u){ return __uint_as_float(u & 0xFFFF0000u); }
__device__ __forceinline__ unsigned short f2bf(float f){
  __hip_bfloat16 h = __float2bfloat16(f);
  return *reinterpret_cast<unsigned short*>(&h);
}
__device__ __forceinline__ void atomAddF(float* p, float v){ unsafeAtomicAdd(p, v); }
__device__ __forceinline__ float wredsum(float x){
  x += __shfl_xor(x, 1, 64);  x += __shfl_xor(x, 2, 64);  x += __shfl_xor(x, 4, 64);
  x += __shfl_xor(x, 8, 64);  x += __shfl_xor(x, 16, 64); x += __shfl_xor(x, 32, 64);
  return x;
}

// ---------------- K1: per-block rel histogram + entity counts ----------------
__global__ __launch_bounds__(256) void k_hist(const int* __restrict__ trip,
                                              int* __restrict__ cnt, int* __restrict__ gHist){
  __shared__ int h[NR];
  int t = threadIdx.x;
  for (int r = t; r < NR; r += 256) h[r] = 0;
  __syncthreads();
  int b0 = blockIdx.x*TBH, b1 = min(b0+TBH, NT);
  for (int i = b0 + t; i < b1; i += 256){
    int t0 = trip[3*i], t1 = trip[3*i+1], t2 = trip[3*i+2];
    atomicAdd(&cnt[t0], 1);
    atomicAdd(&cnt[t1], 1);
    atomicAdd(&h[t2], 1);
  }
  __syncthreads();
  for (int r = t; r < NR; r += 256) gHist[blockIdx.x*NR + r] = h[r];
}

// ---------------- K1b: column-scan hists -> per-(block,rel) base, cntR, offR ----------------
__global__ __launch_bounds__(512) void k_histscan(const int* __restrict__ gHist,
                                                  int* __restrict__ base, int* __restrict__ cntR,
                                                  int* __restrict__ offR){
  __shared__ int sm[512];
  int r = threadIdx.x;
  int s = 0;
  if (r < NR){
    for (int b = 0; b < NBH; ++b){ base[b*NR + r] = s; s += gHist[b*NR + r]; }
    cntR[r] = s;
  }
  sm[r] = (r < NR) ? s : 0;
  __syncthreads();
  for (int st = 1; st < 512; st <<= 1){
    int x = (r >= st) ? sm[r-st] : 0;
    __syncthreads();
    sm[r] += x;
    __syncthreads();
  }
  if (r < NR){
    int off = sm[r] - s;               // exclusive
    offR[r] = off;
    for (int b = 0; b < NBH; ++b) base[b*NR + r] += off;
  }
  if (r == 0) offR[NR] = NT;
}

// ---------------- device-wide entity scan: phase 1 (block-local) ----------------
__global__ __launch_bounds__(1024) void k_scan1(const int* __restrict__ cnt,
                                                int* __restrict__ off, int* __restrict__ bsum){
  __shared__ int wsum[16];
  int t = threadIdx.x, lane = t & 63, w = t >> 6;
  int i = blockIdx.x*1024 + t;
  int v = (i < NE) ? cnt[i] : 0;
  int x = v;
  #pragma unroll
  for (int s = 1; s < 64; s <<= 1){ int y = __shfl_up(x, s, 64); if (lane >= s) x += y; }
  if (lane == 63) wsum[w] = x;
  __syncthreads();
  if (w == 0 && lane < 16){
    int xs = wsum[lane];
    #pragma unroll
    for (int s = 1; s < 16; s <<= 1){ int y = __shfl_up(xs, s, 16); if ((lane & 15) >= s) xs += y; }
    wsum[lane] = xs;
  }
  __syncthreads();
  int wprev = (w == 0) ? 0 : wsum[w-1];
  int incl = wprev + x;
  if (i < NE) off[i] = incl - v;          // block-local exclusive
  if (t == 1023) bsum[blockIdx.x] = incl; // block total
}

// ---------------- device-wide entity scan: phase 2 (scan 98 block totals) ----------------
__global__ __launch_bounds__(128) void k_scan2(const int* __restrict__ bsum,
                                               int* __restrict__ bbase, int* __restrict__ off){
  __shared__ int sm[128];
  int t = threadIdx.x;
  int v = (t < NBS) ? bsum[t] : 0;
  sm[t] = v; __syncthreads();
  for (int s = 1; s < 128; s <<= 1){
    int x = (t >= s) ? sm[t-s] : 0;
    __syncthreads();
    sm[t] += x;
    __syncthreads();
  }
  int incl = sm[t];
  if (t < NBS) bbase[t] = incl - v;
  if (t == NBS-1) off[NE] = incl;
}

// ---------------- device-wide entity scan: phase 3 (add base, write cur) ----------------
__global__ __launch_bounds__(1024) void k_scan3(int* __restrict__ off, int* __restrict__ cur,
                                                const int* __restrict__ bbase){
  int i = blockIdx.x*1024 + threadIdx.x;
  if (i < NE){
    int o = off[i] + bbase[blockIdx.x];
    off[i] = o;
    cur[i] = o;
  }
}

// ---------------- scatter entity events (global cursors, nt stores) ----------------
__global__ void k_scat_ent(const int* __restrict__ trip, int* __restrict__ curE,
                           unsigned long long* __restrict__ evE){
  int i = blockIdx.x*blockDim.x + threadIdx.x;
  if (i < NT){
    int t0 = trip[3*i+0], t1 = trip[3*i+1], t2 = trip[3*i+2];
    int p0 = atomicAdd(&curE[t0], 1);
    unsigned long long e0 = (unsigned)t0 |
      ((unsigned long long)(((unsigned)t1 << 10) | ((unsigned)t2 << 1)) << 32);
    __builtin_nontemporal_store(e0, &evE[p0]);
    int p1 = atomicAdd(&curE[t1], 1);
    unsigned long long e1 = (unsigned)t1 |
      ((unsigned long long)(((unsigned)t0 << 10) | ((unsigned)t2 << 1) | 1u) << 32);
    __builtin_nontemporal_store(e1, &evE[p1]);
  }
}

// ---------------- scatter rel events (LDS cursors, deterministic bases) ----------------
__global__ __launch_bounds__(256) void k_scat_rel(const int* __restrict__ trip,
                                                  const int* __restrict__ base,
                                                  unsigned long long* __restrict__ evR){
  __shared__ int cur[NR];
  int t = threadIdx.x;
  for (int r = t; r < NR; r += 256) cur[r] = base[blockIdx.x*NR + r];
  __syncthreads();
  int b0 = blockIdx.x*TBH, b1 = min(b0+TBH, NT);
  for (int i = b0 + t; i < b1; i += 256){
    int t0 = trip[3*i], t1 = trip[3*i+1], t2 = trip[3*i+2];
    int p = atomicAdd(&cur[t2], 1);
    unsigned long long e = (unsigned)t0 | ((unsigned long long)(unsigned)t1 << 32);
    __builtin_nontemporal_store(e, &evR[p]);
  }
}

// ---------------- K2: entity column stats + fused X->bf16 convert ----------------
__global__ __launch_bounds__(256) void k_entstats(const float* __restrict__ ent, const int* __restrict__ cnt,
                                                  float* __restrict__ S, float* __restrict__ Q,
                                                  unsigned short* __restrict__ Xbf){
  int j = threadIdx.x & 127;
  int half = threadIdx.x >> 7;
  int r0 = blockIdx.x*128 + half;
  int r1 = min(blockIdx.x*128 + 128, NE);
  float s = 0.f, q = 0.f;
  for (int r = r0; r < r1; r += 2){
    float x = ent[(size_t)r*DD + j];
    Xbf[(size_t)r*DD + j] = f2bf(x);
    int w = cnt[r];
    if (w){
      float wf = (float)w;
      s += wf*x; q += wf*x*x;
    }
  }
  __shared__ float ss[256], qq[256];
  ss[threadIdx.x] = s; qq[threadIdx.x] = q; __syncthreads();
  if (half == 0){
    atomAddF(&S[j], ss[j] + ss[j+128]);
    atomAddF(&Q[j], qq[j] + qq[j+128]);
  }
}

// ---------------- K3: BN0 fold + rel variance ----------------
__global__ void k_alpha(const float* __restrict__ rel, const int* __restrict__ cntR,
                        const float* __restrict__ S, const float* __restrict__ Q,
                        const float* __restrict__ bn0g, const float* __restrict__ bn0b,
                        float* __restrict__ alpha0, float* __restrict__ alpha1, float* __restrict__ alpha2,
                        float* __restrict__ beta0, float* __restrict__ beta1){
  int j = threadIdx.x;
  float qr = 0.f;
  for (int k = 0; k < NR; ++k){
    float w = (float)cntR[k];
    float x = rel[k*DD + j];
    qr += w*x*x;
  }
  float mean = S[j] / TWO_NF;
  float var  = Q[j] / TWO_NF - mean*mean;
  float inv  = rsqrtf(var + 1e-5f);
  float a0 = inv * bn0g[j];
  float a1 = inv * bn0g[128+j];
  alpha0[j] = a0; alpha1[j] = a1;
  beta0[j] = bn0b[j]     - mean*a0;
  beta1[j] = bn0b[128+j] - mean*a1;
  float varR = qr / NTF;
  alpha2[j] = rsqrtf(varR + 1e-5f) * bn0g[256+j];
}

// ---------------- K4: folded bias vector ----------------
__global__ void k_bias(const float* __restrict__ aw, const float* __restrict__ ab,
                       const float* __restrict__ bn0b,
                       const float* __restrict__ beta0, const float* __restrict__ beta1,
                       float* __restrict__ bias){
  int o = blockIdx.x, j = threadIdx.x;
  const float* r = aw + (size_t)o*384;
  float p = r[j]*beta0[j] + r[128+j]*beta1[j] + r[256+j]*bn0b[256+j];
  __shared__ float sm[128];
  sm[j] = p; __syncthreads();
  for (int s = 64; s > 0; s >>= 1){ if (j < s) sm[j] += sm[j+s]; __syncthreads(); }
  if (j == 0) bias[o] = ab[o] + sm[0];
}

// ---------------- K5: V table ----------------
__global__ void k_v(const float* __restrict__ rel, const float* __restrict__ aw,
                    const float* __restrict__ alpha2, float* __restrict__ V){
  int k = blockIdx.x, o = threadIdx.x;
  __shared__ float rl[128];
  rl[o] = rel[k*DD + o] * alpha2[o];
  __syncthreads();
  float acc = 0.f;
  #pragma unroll 8
  for (int j = 0; j < 128; ++j) acc += aw[(size_t)o*384 + 256 + j] * rl[j];
  V[k*DD + o] = acc;
}

// ---------------- K5b: fold W' into bf16 table Wt2[o][k] (B-operand layout) ----------------
__global__ void k_wfold2(const float* __restrict__ aw, const float* __restrict__ alpha0,
                         const float* __restrict__ alpha1, unsigned short* __restrict__ Wt2){
  int o = blockIdx.x;        // 0..255
  int k = threadIdx.x;       // 0..127
  float w;
  if (o < 128) w = aw[(size_t)o*384 + k] * alpha0[k];
  else         w = aw[(size_t)(o-128)*384 + 128 + k] * alpha1[k];
  Wt2[(size_t)o*128 + k] = f2bf(w);
}

// ---------------- K6: U table via MFMA — wave owns 4 output tiles, B in registers ----------------
// Block covers 64 entities; wave w computes output cols [w*64, w*64+64) for all 64 entities.
// B fragments (16 short8) preloaded once per wave, reused across 4 entity tiles.
__global__ __launch_bounds__(256) void k_u2(const unsigned short* __restrict__ Xbf,
                                            const unsigned short* __restrict__ Wt2,
                                            unsigned short* __restrict__ Uo){
  int tid = threadIdx.x;
  int w = tid >> 6, l = tid & 63;
  int col = l & 15, grp = l >> 4, kof = grp*8;
  int e0 = blockIdx.x*64;                    // 1563 blocks * 64 = 100032
  int ot0 = w*4;

  const unsigned short* wb0 = Wt2 + (size_t)((ot0+0)*16 + col)*128 + kof;
  const unsigned short* wb1 = Wt2 + (size_t)((ot0+1)*16 + col)*128 + kof;
  const unsigned short* wb2 = Wt2 + (size_t)((ot0+2)*16 + col)*128 + kof;
  const unsigned short* wb3 = Wt2 + (size_t)((ot0+3)*16 + col)*128 + kof;
  short8 b00 = *(const short8*)(wb0);
  short8 b01 = *(const short8*)(wb0+32);
  short8 b02 = *(const short8*)(wb0+64);
  short8 b03 = *(const short8*)(wb0+96);
  short8 b10 = *(const short8*)(wb1);
  short8 b11 = *(const short8*)(wb1+32);
  short8 b12 = *(const short8*)(wb1+64);
  short8 b13 = *(const short8*)(wb1+96);
  short8 b20 = *(const short8*)(wb2);
  short8 b21 = *(const short8*)(wb2+32);
  short8 b22 = *(const short8*)(wb2+64);
  short8 b23 = *(const short8*)(wb2+96);
  short8 b30 = *(const short8*)(wb3);
  short8 b31 = *(const short8*)(wb3+32);
  short8 b32 = *(const short8*)(wb3+64);
  short8 b33 = *(const short8*)(wb3+96);

  #pragma unroll
  for (int et = 0; et < 4; ++et){
    int ebase = e0 + et*16;
    int e = min(ebase + col, NE-1);
    const unsigned short* xrow = Xbf + (size_t)e*DD;
    short8 a0 = *(const short8*)(xrow + kof);
    short8 a1 = *(const short8*)(xrow + 32 + kof);
    short8 a2 = *(const short8*)(xrow + 64 + kof);
    short8 a3 = *(const short8*)(xrow + 96 + kof);
    f32x4 c0 = (f32x4){0.f,0.f,0.f,0.f};
    f32x4 c1 = (f32x4){0.f,0.f,0.f,0.f};
    f32x4 c2 = (f32x4){0.f,0.f,0.f,0.f};
    f32x4 c3 = (f32x4){0.f,0.f,0.f,0.f};
    c0 = __builtin_amdgcn_mfma_f32_16x16x32_bf16(a0, b00, c0, 0, 0, 0);
    c1 = __builtin_amdgcn_mfma_f32_16x16x32_bf16(a0, b10, c1, 0, 0, 0);
    c2 = __builtin_amdgcn_mfma_f32_16x16x32_bf16(a0, b20, c2, 0, 0, 0);
    c3 = __builtin_amdgcn_mfma_f32_16x16x32_bf16(a0, b30, c3, 0, 0, 0);
    c0 = __builtin_amdgcn_mfma_f32_16x16x32_bf16(a1, b01, c0, 0, 0, 0);
    c1 = __builtin_amdgcn_mfma_f32_16x16x32_bf16(a1, b11, c1, 0, 0, 0);
    c2 = __builtin_amdgcn_mfma_f32_16x16x32_bf16(a1, b21, c2, 0, 0, 0);
    c3 = __builtin_amdgcn_mfma_f32_16x16x32_bf16(a1, b31, c3, 0, 0, 0);
    c0 = __builtin_amdgcn_mfma_f32_16x16x32_bf16(a2, b02, c0, 0, 0, 0);
    c1 = __builtin_amdgcn_mfma_f32_16x16x32_bf16(a2, b12, c1, 0, 0, 0);
    c2 = __builtin_amdgcn_mfma_f32_16x16x32_bf16(a2, b22, c2, 0, 0, 0);
    c3 = __builtin_amdgcn_mfma_f32_16x16x32_bf16(a2, b32, c3, 0, 0, 0);
    c0 = __builtin_amdgcn_mfma_f32_16x16x32_bf16(a3, b03, c0, 0, 0, 0);
    c1 = __builtin_amdgcn_mfma_f32_16x16x32_bf16(a3, b13, c1, 0, 0, 0);
    c2 = __builtin_amdgcn_mfma_f32_16x16x32_bf16(a3, b23, c2, 0, 0, 0);
    c3 = __builtin_amdgcn_mfma_f32_16x16x32_bf16(a3, b33, c3, 0, 0, 0);
    #pragma unroll
    for (int r = 0; r < 4; ++r){
      int row = ebase + 4*grp + r;
      if (row < NE){
        size_t rb = (size_t)row*256 + col;
        Uo[rb + (ot0+0)*16] = f2bf(c0[r]);
        Uo[rb + (ot0+1)*16] = f2bf(c1[r]);
        Uo[rb + (ot0+2)*16] = f2bf(c2[r]);
        Uo[rb + (ot0+3)*16] = f2bf(c3[r]);
      }
    }
  }
}

// ---------------- K7: BN1 column stats over CSR events (unroll x4, named) ----------------
__global__ __launch_bounds__(256) void k_c1b(const uint2* __restrict__ evE,
                   const unsigned short* __restrict__ U, const float* __restrict__ V,
                   const float* __restrict__ bias,
                   float* __restrict__ colsum, float* __restrict__ colsumsq){
  int lane = threadIdx.x & 63;
  int w = threadIdx.x >> 6;
  int wv = blockIdx.x*4 + w;
  int nwv = gridDim.x*4;
  int per = (NEV + nwv - 1) / nwv;
  int st = wv*per, en = min(st + per, NEV);
  int c0 = 2*lane, c1 = c0+1;
  float b0 = bias[c0], b1 = bias[c1];
  const ushort2* Ub = (const ushort2*)U;
  const float2*  Vp = (const float2*)V;
  float s0=0.f, s1=0.f, q0=0.f, q1=0.f;
  for (int bs = st; bs < en; bs += 64){
    int n = min(64, en - bs);
    uint2 ev = (bs + lane < en) ? evE[bs + lane] : make_uint2(0u, 0u);
    int j = 0;
    for (; j + 4 <= n; j += 4){
      unsigned ow0 = __shfl(ev.x, j, 64),   pk0 = __shfl(ev.y, j, 64);
      unsigned ow1 = __shfl(ev.x, j+1, 64), pk1 = __shfl(ev.y, j+1, 64);
      unsigned ow2 = __shfl(ev.x, j+2, 64), pk2 = __shfl(ev.y, j+2, 64);
      unsigned ow3 = __shfl(ev.x, j+3, 64), pk3 = __shfl(ev.y, j+3, 64);
      ushort2 a0 = Ub[(size_t)ow0*128 + lane];
      ushort2 g0 = Ub[(size_t)(pk0 >> 10)*128 + 64 + lane];
      float2  v0 = Vp[((pk0 >> 1) & 0x1FF)*64 + lane];
      ushort2 a1 = Ub[(size_t)ow1*128 + lane];
      ushort2 g1 = Ub[(size_t)(pk1 >> 10)*128 + 64 + lane];
      float2  v1 = Vp[((pk1 >> 1) & 0x1FF)*64 + lane];
      ushort2 a2 = Ub[(size_t)ow2*128 + lane];
      ushort2 g2 = Ub[(size_t)(pk2 >> 10)*128 + 64 + lane];
      float2  v2 = Vp[((pk2 >> 1) & 0x1FF)*64 + lane];
      ushort2 a3 = Ub[(size_t)ow3*128 + lane];
      ushort2 g3 = Ub[(size_t)(pk3 >> 10)*128 + 64 + lane];
      float2  v3 = Vp[((pk3 >> 1) & 0x1FF)*64 + lane];
      float sg0 = (pk0 & 1) ? -1.f : 1.f;
      float sg1 = (pk1 & 1) ? -1.f : 1.f;
      float sg2 = (pk2 & 1) ? -1.f : 1.f;
      float sg3 = (pk3 & 1) ? -1.f : 1.f;
      float y00 = bf2f(a0.x) + bf2f(g0.x) + sg0*v0.x + b0;
      float y01 = bf2f(a0.y) + bf2f(g0.y) + sg0*v0.y + b1;
      float y10 = bf2f(a1.x) + bf2f(g1.x) + sg1*v1.x + b0;
      float y11 = bf2f(a1.y) + bf2f(g1.y) + sg1*v1.y + b1;
      float y20 = bf2f(a2.x) + bf2f(g2.x) + sg2*v2.x + b0;
      float y21 = bf2f(a2.y) + bf2f(g2.y) + sg2*v2.y + b1;
      float y30 = bf2f(a3.x) + bf2f(g3.x) + sg3*v3.x + b0;
      float y31 = bf2f(a3.y) + bf2f(g3.y) + sg3*v3.y + b1;
      s0 += y00 + y10 + y20 + y30;
      s1 += y01 + y11 + y21 + y31;
      q0 += y00*y00 + y10*y10 + y20*y20 + y30*y30;
      q1 += y01*y01 + y11*y11 + y21*y21 + y31*y31;
    }
    for (; j < n; ++j){
      unsigned ow0 = __shfl(ev.x, j, 64), pk0 = __shfl(ev.y, j, 64);
      ushort2 a0 = Ub[(size_t)ow0*128 + lane];
      ushort2 g0 = Ub[(size_t)(pk0 >> 10)*128 + 64 + lane];
      float2  v0 = Vp[((pk0 >> 1) & 0x1FF)*64 + lane];
      float sg0 = (pk0 & 1) ? -1.f : 1.f;
      float y00 = bf2f(a0.x) + bf2f(g0.x) + sg0*v0.x + b0;
      float y01 = bf2f(a0.y) + bf2f(g0.y) + sg0*v0.y + b1;
      s0 += y00;  q0 += y00*y00;
      s1 += y01;  q1 += y01*y01;
    }
  }
  __shared__ float sred[4][128], qred[4][128];
  sred[w][c0] = s0; sred[w][c1] = s1;
  qred[w][c0] = q0; qred[w][c1] = q1;
  __syncthreads();
  int t = threadIdx.x;
  if (t < 128){
    atomAddF(&colsum[t],   sred[0][t] + sred[1][t] + sred[2][t] + sred[3][t]);
    atomAddF(&colsumsq[t], qred[0][t] + qred[1][t] + qred[2][t] + qred[3][t]);
  }
}

// ---------------- K8: BN1 fold + a2 fold + pbsb ----------------
__global__ void k_bn1fin(const float* __restrict__ colsum, const float* __restrict__ colsumsq,
                         const float* __restrict__ bn1g, const float* __restrict__ bn1b,
                         const float* __restrict__ a2w, const float* __restrict__ a2b,
                         const float* __restrict__ biasv,
                         float* __restrict__ A1, float* __restrict__ B1,
                         float* __restrict__ a2A, float* __restrict__ sbase){
  int j = threadIdx.x;
  float mean = colsum[j] / TWO_NF;
  float var  = colsumsq[j] / TWO_NF - mean*mean;
  float A = rsqrtf(var + 1e-5f) * bn1g[j];
  float B = bn1b[j] - mean*A;
  A1[j] = A; B1[j] = B;
  float w2 = a2w[j];
  float aA = w2*A;
  a2A[j] = aA;
  __shared__ float sm[128], sm2[128];
  sm[j] = w2*B; sm2[j] = biasv[j]*aA;
  __syncthreads();
  for (int s = 64; s > 0; s >>= 1){
    if (j < s){ sm[j] += sm[j+s]; sm2[j] += sm2[j+s]; }
    __syncthreads();
  }
  if (j == 0){
    float sb = a2b[0] + sm[0];
    sbase[0] = sb;
    sbase[1] = sb + sm2[0];   // pbsb = dot(bias,a2A) + sbase
  }
}

// ---------------- K8b: per-entity score scalars sigma0/sigma1 ----------------
__global__ __launch_bounds__(256) void k_sigma(const unsigned short* __restrict__ U,
                                               const float* __restrict__ a2A,
                                               float* __restrict__ sig){
  int lane = threadIdx.x & 63;
  int e = blockIdx.x*4 + (threadIdx.x>>6);
  if (e >= NE) return;
  const uint2* Ur = (const uint2*)U;
  uint2 r = Ur[(size_t)e*64 + lane];
  int c = (lane & 31)*4;
  float4 w = *(const float4*)&a2A[c];
  float p = bf2f_lo(r.x)*w.x + bf2f_hi(r.x)*w.y + bf2f_lo(r.y)*w.z + bf2f_hi(r.y)*w.w;
  p += __shfl_xor(p, 1, 64); p += __shfl_xor(p, 2, 64); p += __shfl_xor(p, 4, 64);
  p += __shfl_xor(p, 8, 64); p += __shfl_xor(p, 16, 64);
  if ((lane & 31) == 0) sig[2*e + (lane >> 5)] = p;
}

// ---------------- K8c: per-relation score scalar rho ----------------
__global__ __launch_bounds__(256) void k_rho(const float* __restrict__ V,
                                             const float* __restrict__ a2A,
                                             float* __restrict__ rho){
  int lane = threadIdx.x & 63;
  int k = blockIdx.x*4 + (threadIdx.x>>6);
  if (k >= NR) return;
  const float2* Vp = (const float2*)V;
  float2 v = Vp[(size_t)k*64 + lane];
  int c0 = 2*lane;
  float p = v.x*a2A[c0] + v.y*a2A[c0+1];
  p = wredsum(p);
  if (lane == 0) rho[k] = p;
}

// ---------------- K9: entity gather (unroll x4, named) ----------------
__global__ __launch_bounds__(256) void k_gent(const uint2* __restrict__ evE, const int* __restrict__ offE,
                   const unsigned short* __restrict__ U, const float* __restrict__ V,
                   const float* __restrict__ sig, const float* __restrict__ rho,
                   const float* __restrict__ bias,
                   const float* __restrict__ A1, const float* __restrict__ B1,
                   const float* __restrict__ sbase,
                   float* __restrict__ out){
  int lane = threadIdx.x & 63;
  int e = blockIdx.x*4 + (threadIdx.x>>6);
  if (e >= NE) return;
  int c0 = 2*lane, c1 = c0+1;
  const ushort2* Ub = (const ushort2*)U;
  const float2*  Vp = (const float2*)V;
  ushort2 u0 = Ub[(size_t)e*128 + lane];
  float base0 = bf2f(u0.x) + bias[c0], base1 = bf2f(u0.y) + bias[c1];
  float pb  = sbase[1];
  float s0e = sig[2*e];
  float accU0=0.f, accU1=0.f, accV0=0.f, accV1=0.f, sep=0.f;
  int p0 = offE[e], p1 = offE[e+1];
  for (int bs = p0; bs < p1; bs += 64){
    int n = min(64, p1 - bs);
    unsigned ev = 0u; float ebl = 0.f;
    if (bs + lane < p1){
      ev = evE[bs + lane].y;
      int oth = ev >> 10, rl = (ev >> 1) & 0x1FF;
      float sg = (ev & 1) ? -1.f : 1.f;
      float s = s0e + sig[2*oth + 1] + sg*rho[rl] + pb;
      float bb = (s >= 0.f) ? -s : -0.01f*s;
      ebl = expf(bb);
    }
    sep += ebl;
    int j = 0;
    for (; j + 4 <= n; j += 4){
      unsigned e0 = __shfl(ev, j, 64);
      unsigned e1 = __shfl(ev, j+1, 64);
      unsigned e2 = __shfl(ev, j+2, 64);
      unsigned e3 = __shfl(ev, j+3, 64);
      float eb0 = __shfl(ebl, j, 64);
      float eb1 = __shfl(ebl, j+1, 64);
      float eb2 = __shfl(ebl, j+2, 64);
      float eb3 = __shfl(ebl, j+3, 64);
      ushort2 g0 = Ub[(size_t)(e0 >> 10)*128 + 64 + lane];
      ushort2 g1 = Ub[(size_t)(e1 >> 10)*128 + 64 + lane];
      ushort2 g2 = Ub[(size_t)(e2 >> 10)*128 + 64 + lane];
      ushort2 g3 = Ub[(size_t)(e3 >> 10)*128 + 64 + lane];
      float2 v0 = Vp[((e0 >> 1) & 0x1FF)*64 + lane];
      float2 v1 = Vp[((e1 >> 1) & 0x1FF)*64 + lane];
      float2 v2 = Vp[((e2 >> 1) & 0x1FF)*64 + lane];
      float2 v3 = Vp[((e3 >> 1) & 0x1FF)*64 + lane];
      float w0 = (e0 & 1) ? -eb0 : eb0;
      float w1 = (e1 & 1) ? -eb1 : eb1;
      float w2 = (e2 & 1) ? -eb2 : eb2;
      float w3 = (e3 & 1) ? -eb3 : eb3;
      accU0 += eb0*bf2f(g0.x); accU1 += eb0*bf2f(g0.y);
      accV0 += w0*v0.x;        accV1 += w0*v0.y;
      accU0 += eb1*bf2f(g1.x); accU1 += eb1*bf2f(g1.y);
      accV0 += w1*v1.x;        accV1 += w1*v1.y;
      accU0 += eb2*bf2f(g2.x); accU1 += eb2*bf2f(g2.y);
      accV0 += w2*v2.x;        accV1 += w2*v2.y;
      accU0 += eb3*bf2f(g3.x); accU1 += eb3*bf2f(g3.y);
      accV0 += w3*v3.x;        accV1 += w3*v3.y;
    }
    for (; j < n; ++j){
      unsigned e0 = __shfl(ev, j, 64);
      float eb0 = __shfl(ebl, j, 64);
      ushort2 g0 = Ub[(size_t)(e0 >> 10)*128 + 64 + lane];
      float2 v0 = Vp[((e0 >> 1) & 0x1FF)*64 + lane];
      float w0 = (e0 & 1) ? -eb0 : eb0;
      accU0 += eb0*bf2f(g0.x); accU1 += eb0*bf2f(g0.y);
      accV0 += w0*v0.x;        accV1 += w0*v0.y;
    }
  }
  float se = wredsum(sep);
  float sY0 = se*base0 + accU0 + accV0;
  float sY1 = se*base1 + accU1 + accV1;
  float hs0 = A1[c0]*sY0 + B1[c0]*se;
  float hs1 = A1[c1]*sY1 + B1[c1]*se;
  float d = (se == 0.f) ? 1e-12f : se;
  out[(size_t)e*DD + c0] = hs0/d;
  out[(size_t)e*DD + c1] = hs1/d;
}

// ---------------- K10: relation gather — lane-parallel scores + FMA stream ----------------
__global__ __launch_bounds__(256) void k_grel(const uint2* __restrict__ evR, const int* __restrict__ offR,
                   const unsigned short* __restrict__ U, const float* __restrict__ V,
                   const float* __restrict__ sig, const float* __restrict__ rho,
                   const float* __restrict__ bias,
                   const float* __restrict__ A1, const float* __restrict__ B1,
                   const float* __restrict__ sbase,
                   float* __restrict__ out){
  int lane = threadIdx.x & 63;
  int k = blockIdx.x >> 3;
  int wvs = (blockIdx.x & 7)*4 + (threadIdx.x >> 6);   // 0..31
  int c0 = 2*lane, c1 = c0+1;
  const ushort2* Ub = (const ushort2*)U;
  const float2*  Vp = (const float2*)V;
  float2 v = Vp[(size_t)k*64 + lane];
  float vb0 = v.x + bias[c0], vb1 = v.y + bias[c1];
  float rpb = rho[k] + sbase[1];
  float accY0=0.f, accY1=0.f, sep=0.f;
  int p0 = offR[k], p1 = offR[k+1];
  int tot = p1 - p0, per = (tot + 31) >> 5;
  int st = p0 + wvs*per, en = min(st + per, p1);
  for (int bs = st; bs < en; bs += 64){
    int n = min(64, en - bs);
    uint2 ev = make_uint2(0u, 0u); float ebl = 0.f;
    if (bs + lane < en){
      ev = evR[bs + lane];
      float s = sig[2*ev.x] + sig[2*ev.y + 1] + rpb;
      float bb = (s >= 0.f) ? -s : -0.01f*s;
      ebl = expf(bb);
    }
    sep += ebl;
    int j = 0;
    for (; j + 2 <= n; j += 2){
      unsigned a0 = __shfl(ev.x, j, 64),   d0 = __shfl(ev.y, j, 64);
      unsigned a1 = __shfl(ev.x, j+1, 64), d1 = __shfl(ev.y, j+1, 64);
      float eb0 = __shfl(ebl, j, 64);
      float eb1 = __shfl(ebl, j+1, 64);
      ushort2 ua0 = Ub[(size_t)a0*128 + lane];
      ushort2 ud0 = Ub[(size_t)d0*128 + 64 + lane];
      ushort2 ua1 = Ub[(size_t)a1*128 + lane];
      ushort2 ud1 = Ub[(size_t)d1*128 + 64 + lane];
      accY0 += eb0*(bf2f(ua0.x) + bf2f(ud0.x));
      accY1 += eb0*(bf2f(ua0.y) + bf2f(ud0.y));
      accY0 += eb1*(bf2f(ua1.x) + bf2f(ud1.x));
      accY1 += eb1*(bf2f(ua1.y) + bf2f(ud1.y));
    }
    for (; j < n; ++j){
      unsigned a0 = __shfl(ev.x, j, 64), d0 = __shfl(ev.y, j, 64);
      float eb0 = __shfl(ebl, j, 64);
      ushort2 ua0 = Ub[(size_t)a0*128 + lane];
      ushort2 ud0 = Ub[(size_t)d0*128 + 64 + lane];
      accY0 += eb0*(bf2f(ua0.x) + bf2f(ud0.x));
      accY1 += eb0*(bf2f(ua0.y) + bf2f(ud0.y));
    }
  }
  float se = wredsum(sep);
  float sY0 = accY0 + se*vb0;
  float sY1 = accY1 + se*vb1;
  float r0 = A1[c0]*sY0 + B1[c0]*se;
  float r1 = A1[c1]*sY1 + B1[c1]*se;
  atomAddF(&out[(size_t)RELOFF + (size_t)k*DD + c0], r0);
  atomAddF(&out[(size_t)RELOFF + (size_t)k*DD + c1], r1);
}

// ---------------- K11: finalize rel division ----------------
__global__ void k_fin_rel(float* __restrict__ out, const int* __restrict__ cntR){
  int idx = blockIdx.x*blockDim.x + threadIdx.x;   // NR*DD threads
  int k = idx >> 7;
  float c = fmaxf((float)cntR[k], 1.f);
  out[RELOFF + idx] = out[RELOFF + idx] / c;
}

extern "C" void kernel_launch(void* const* d_in, const int* in_sizes, int n_in,
                              void* d_out, int out_size, void* d_ws, size_t ws_size,
                              hipStream_t stream) {
  (void)in_sizes; (void)n_in; (void)ws_size; (void)out_size;
  const int*   trip = (const int*)  d_in[0];
  const float* ent  = (const float*)d_in[1];
  const float* rel  = (const float*)d_in[2];
  const float* aw   = (const float*)d_in[3];
  const float* ab   = (const float*)d_in[4];
  const float* a2w  = (const float*)d_in[5];
  const float* a2b  = (const float*)d_in[6];
  const float* bn0g = (const float*)d_in[7];
  const float* bn0b = (const float*)d_in[8];
  const float* bn1g = (const float*)d_in[9];
  const float* bn1b = (const float*)d_in[10];
  float* out = (float*)d_out;
  // Xbf scratch lives in the entity half of d_out (overwritten later by k_gent)
  unsigned short* Xbf = (unsigned short*)d_out;

  char* w = (char*)d_ws;
  size_t off = 0;
  auto take = [&](size_t bytes) -> char* {
    char* p = w + off;
    off = (off + bytes + 511) & ~(size_t)511;
    return p;
  };
  // zeroed region (accumulators)
  float* S        = (float*)take(512);
  float* Q        = (float*)take(512);
  float* colsum   = (float*)take(512);
  float* colsumsq = (float*)take(512);
  int*   cnt      = (int*)  take((size_t)NE*4);
  size_t zero_end = off;
  // non-zeroed (fully overwritten each launch)
  int*   cntR   = (int*)  take((size_t)NR*4);
  float* alpha0 = (float*)take(512);
  float* alpha1 = (float*)take(512);
  float* alpha2 = (float*)take(512);
  float* beta0  = (float*)take(512);
  float* beta1  = (float*)take(512);
  float* biasv  = (float*)take(512);
  float* A1     = (float*)take(512);
  float* B1     = (float*)take(512);
  float* a2A    = (float*)take(512);
  float* sbase  = (float*)take(512);
  float* rho    = (float*)take((size_t)NR*4);
  float* sig    = (float*)take((size_t)NE*2*4);
  int*   offE   = (int*)  take((size_t)(NE+1)*4);
  int*   curE   = (int*)  take((size_t)NE*4);
  int*   offR   = (int*)  take((size_t)(NR+1)*4);
  int*   gHist  = (int*)  take((size_t)NBH*NR*4);
  int*   gBase  = (int*)  take((size_t)NBH*NR*4);
  int*   bsum   = (int*)  take((size_t)NBS*4);
  int*   bbase  = (int*)  take((size_t)NBS*4);
  unsigned long long* evE = (unsigned long long*)take((size_t)NEV*8);
  unsigned long long* evR = (unsigned long long*)take((size_t)NT*8);
  float* V      = (float*)take((size_t)NR*DD*4);
  unsigned short* Wt2 = (unsigned short*)take((size_t)256*128*2);
  unsigned short* U   = (unsigned short*)take((size_t)NE*256*2);

  hipMemsetAsync((char*)d_out + (size_t)RELOFF*4, 0, (size_t)NR*DD*4, stream);
  hipMemsetAsync(d_ws, 0, zero_end, stream);

  k_hist     <<<NBH, 256, 0, stream>>>(trip, cnt, gHist);
  k_histscan <<<1, 512, 0, stream>>>(gHist, gBase, cntR, offR);
  k_scan1    <<<NBS, 1024, 0, stream>>>(cnt, offE, bsum);
  k_scan2    <<<1, 128, 0, stream>>>(bsum, bbase, offE);
  k_scan3    <<<NBS, 1024, 0, stream>>>(offE, curE, bbase);
  k_scat_ent <<<(NT+255)/256, 256, 0, stream>>>(trip, curE, evE);
  k_scat_rel <<<NBH, 256, 0, stream>>>(trip, gBase, evR);
  k_entstats <<<(NE+127)/128, 256, 0, stream>>>(ent, cnt, S, Q, Xbf);
  k_alpha    <<<1, 128, 0, stream>>>(rel, cntR, S, Q, bn0g, bn0b, alpha0, alpha1, alpha2, beta0, beta1);
  k_bias     <<<128, 128, 0, stream>>>(aw, ab, bn0b, beta0, beta1, biasv);
  k_v        <<<NR, 128, 0, stream>>>(rel, aw, alpha2, V);
  k_wfold2   <<<256, 128, 0, stream>>>(aw, alpha0, alpha1, Wt2);
  k_u2       <<<1563, 256, 0, stream>>>(Xbf, Wt2, U);
  k_c1b      <<<2048, 256, 0, stream>>>((const uint2*)evE, U, V, biasv, colsum, colsumsq);
  k_bn1fin   <<<1, 128, 0, stream>>>(colsum, colsumsq, bn1g, bn1b, a2w, a2b, biasv, A1, B1, a2A, sbase);
  k_sigma    <<<NE/4, 256, 0, stream>>>(U, a2A, sig);
  k_rho      <<<(NR+3)/4, 256, 0, stream>>>(V, a2A, rho);
  k_gent     <<<NE/4, 256, 0, stream>>>((const uint2*)evE, offE, U, V, sig, rho, biasv, A1, B1, sbase, out);
  k_grel     <<<NR*8, 256, 0, stream>>>((const uint2*)evR, offR, U, V, sig, rho, biasv, A1, B1, sbase, out);
  k_fin_rel  <<<(NR*DD)/256, 256, 0, stream>>>(out, cntR);
}

// Round 12
// 348.928 us; speedup vs baseline: 6.2659x; 1.0772x over previous
//
#include <hip/hip_runtime.h>
#include <hip/hip_bf16.h>

#define NE 100000
#define NR 500
#define DD 128
#define NT 250000
#define NEV 500000             // 2*NT events
#define RELOFF 12800000        // NE*DD
#define TWO_NF 500000.0f
#define NTF 250000.0f
#define TBH 2048
#define NBH ((NT + TBH - 1)/TBH)   // 123
#define NBS ((NE + 1023)/1024)     // 98

typedef __attribute__((ext_vector_type(8))) short short8;
typedef __attribute__((ext_vector_type(4))) float f32x4;

__device__ __forceinline__ float bf2f(unsigned short u){
  unsigned int x = ((unsigned int)u) << 16;
  return __uint_as_float(x);
}
__device__ __forceinline__ float bf2f_lo(unsigned int u){ return __uint_as_float(u << 16); }
__device__ __forceinline__ float bf2f_hi(unsigned int u){ return __uint_as_float(u & 0xFFFF0000u); }
__device__ __forceinline__ unsigned short f2bf(float f){
  __hip_bfloat16 h = __float2bfloat16(f);
  return *reinterpret_cast<unsigned short*>(&h);
}
__device__ __forceinline__ void atomAddF(float* p, float v){ unsafeAtomicAdd(p, v); }
__device__ __forceinline__ float wredsum(float x){
  x += __shfl_xor(x, 1, 64);  x += __shfl_xor(x, 2, 64);  x += __shfl_xor(x, 4, 64);
  x += __shfl_xor(x, 8, 64);  x += __shfl_xor(x, 16, 64); x += __shfl_xor(x, 32, 64);
  return x;
}
__device__ __forceinline__ int wredsumi(int x){
  x += __shfl_xor(x, 1, 64);  x += __shfl_xor(x, 2, 64);  x += __shfl_xor(x, 4, 64);
  x += __shfl_xor(x, 8, 64);  x += __shfl_xor(x, 16, 64); x += __shfl_xor(x, 32, 64);
  return x;
}

// ---------------- K1: per-block rel histogram + entity counts ----------------
__global__ __launch_bounds__(256) void k_hist(const int* __restrict__ trip,
                                              int* __restrict__ cnt, int* __restrict__ gHist){
  __shared__ int h[NR];
  int t = threadIdx.x;
  for (int r = t; r < NR; r += 256) h[r] = 0;
  __syncthreads();
  int b0 = blockIdx.x*TBH, b1 = min(b0+TBH, NT);
  for (int i = b0 + t; i < b1; i += 256){
    int t0 = trip[3*i], t1 = trip[3*i+1], t2 = trip[3*i+2];
    atomicAdd(&cnt[t0], 1);
    atomicAdd(&cnt[t1], 1);
    atomicAdd(&h[t2], 1);
  }
  __syncthreads();
  for (int r = t; r < NR; r += 256) gHist[blockIdx.x*NR + r] = h[r];
}

// ---------------- K1b: column-scan hists -> per-(block,rel) base, cntR, offR ----------------
__global__ __launch_bounds__(512) void k_histscan(const int* __restrict__ gHist,
                                                  int* __restrict__ base, int* __restrict__ cntR,
                                                  int* __restrict__ offR){
  __shared__ int sm[512];
  int r = threadIdx.x;
  int s = 0;
  if (r < NR){
    for (int b = 0; b < NBH; ++b){ base[b*NR + r] = s; s += gHist[b*NR + r]; }
    cntR[r] = s;
  }
  sm[r] = (r < NR) ? s : 0;
  __syncthreads();
  for (int st = 1; st < 512; st <<= 1){
    int x = (r >= st) ? sm[r-st] : 0;
    __syncthreads();
    sm[r] += x;
    __syncthreads();
  }
  if (r < NR){
    int off = sm[r] - s;               // exclusive
    offR[r] = off;
    for (int b = 0; b < NBH; ++b) base[b*NR + r] += off;
  }
  if (r == 0) offR[NR] = NT;
}

// ---------------- device-wide entity scan: phase 1 (block-local) ----------------
__global__ __launch_bounds__(1024) void k_scan1(const int* __restrict__ cnt,
                                                int* __restrict__ off, int* __restrict__ bsum){
  __shared__ int wsum[16];
  int t = threadIdx.x, lane = t & 63, w = t >> 6;
  int i = blockIdx.x*1024 + t;
  int v = (i < NE) ? cnt[i] : 0;
  int x = v;
  #pragma unroll
  for (int s = 1; s < 64; s <<= 1){ int y = __shfl_up(x, s, 64); if (lane >= s) x += y; }
  if (lane == 63) wsum[w] = x;
  __syncthreads();
  if (w == 0 && lane < 16){
    int xs = wsum[lane];
    #pragma unroll
    for (int s = 1; s < 16; s <<= 1){ int y = __shfl_up(xs, s, 16); if ((lane & 15) >= s) xs += y; }
    wsum[lane] = xs;
  }
  __syncthreads();
  int wprev = (w == 0) ? 0 : wsum[w-1];
  int incl = wprev + x;
  if (i < NE) off[i] = incl - v;          // block-local exclusive
  if (t == 1023) bsum[blockIdx.x] = incl; // block total
}

// ---------------- scan phases 2+3 fused: per-block prefix of bsum, add, write cur ----------------
__global__ __launch_bounds__(1024) void k_scan23(const int* __restrict__ bsum,
                                                 int* __restrict__ off, int* __restrict__ cur){
  __shared__ int basesh;
  int t = threadIdx.x;
  if (t < 64){
    int acc = 0;
    for (int b = t; b < blockIdx.x; b += 64) acc += bsum[b];
    acc = wredsumi(acc);
    if (t == 0) basesh = acc;
  }
  __syncthreads();
  int base = basesh;
  int i = blockIdx.x*1024 + t;
  if (i < NE){
    int o = off[i] + base;
    off[i] = o;
    cur[i] = o;
  }
  if (blockIdx.x == NBS-1 && t == 0) off[NE] = base + bsum[NBS-1];
}

// ---------------- scatter entity events (global cursors, nt stores) ----------------
__global__ void k_scat_ent(const int* __restrict__ trip, int* __restrict__ curE,
                           unsigned long long* __restrict__ evE){
  int i = blockIdx.x*blockDim.x + threadIdx.x;
  if (i < NT){
    int t0 = trip[3*i+0], t1 = trip[3*i+1], t2 = trip[3*i+2];
    int p0 = atomicAdd(&curE[t0], 1);
    unsigned long long e0 = (unsigned)t0 |
      ((unsigned long long)(((unsigned)t1 << 10) | ((unsigned)t2 << 1)) << 32);
    __builtin_nontemporal_store(e0, &evE[p0]);
    int p1 = atomicAdd(&curE[t1], 1);
    unsigned long long e1 = (unsigned)t1 |
      ((unsigned long long)(((unsigned)t0 << 10) | ((unsigned)t2 << 1) | 1u) << 32);
    __builtin_nontemporal_store(e1, &evE[p1]);
  }
}

// ---------------- scatter rel events (LDS cursors, deterministic bases) ----------------
__global__ __launch_bounds__(256) void k_scat_rel(const int* __restrict__ trip,
                                                  const int* __restrict__ base,
                                                  unsigned long long* __restrict__ evR){
  __shared__ int cur[NR];
  int t = threadIdx.x;
  for (int r = t; r < NR; r += 256) cur[r] = base[blockIdx.x*NR + r];
  __syncthreads();
  int b0 = blockIdx.x*TBH, b1 = min(b0+TBH, NT);
  for (int i = b0 + t; i < b1; i += 256){
    int t0 = trip[3*i], t1 = trip[3*i+1], t2 = trip[3*i+2];
    int p = atomicAdd(&cur[t2], 1);
    unsigned long long e = (unsigned)t0 | ((unsigned long long)(unsigned)t1 << 32);
    __builtin_nontemporal_store(e, &evR[p]);
  }
}

// ---------------- K2: entity column stats + fused X->bf16 convert ----------------
__global__ __launch_bounds__(256) void k_entstats(const float* __restrict__ ent, const int* __restrict__ cnt,
                                                  float* __restrict__ S, float* __restrict__ Q,
                                                  unsigned short* __restrict__ Xbf){
  int j = threadIdx.x & 127;
  int half = threadIdx.x >> 7;
  int r0 = blockIdx.x*128 + half;
  int r1 = min(blockIdx.x*128 + 128, NE);
  float s = 0.f, q = 0.f;
  for (int r = r0; r < r1; r += 2){
    float x = ent[(size_t)r*DD + j];
    Xbf[(size_t)r*DD + j] = f2bf(x);
    int w = cnt[r];
    if (w){
      float wf = (float)w;
      s += wf*x; q += wf*x*x;
    }
  }
  __shared__ float ss[256], qq[256];
  ss[threadIdx.x] = s; qq[threadIdx.x] = q; __syncthreads();
  if (half == 0){
    atomAddF(&S[j], ss[j] + ss[j+128]);
    atomAddF(&Q[j], qq[j] + qq[j+128]);
  }
}

// ---------------- K3: BN0 fold + rel variance ----------------
__global__ void k_alpha(const float* __restrict__ rel, const int* __restrict__ cntR,
                        const float* __restrict__ S, const float* __restrict__ Q,
                        const float* __restrict__ bn0g, const float* __restrict__ bn0b,
                        float* __restrict__ alpha0, float* __restrict__ alpha1, float* __restrict__ alpha2,
                        float* __restrict__ beta0, float* __restrict__ beta1){
  int j = threadIdx.x;
  float qr = 0.f;
  for (int k = 0; k < NR; ++k){
    float w = (float)cntR[k];
    float x = rel[k*DD + j];
    qr += w*x*x;
  }
  float mean = S[j] / TWO_NF;
  float var  = Q[j] / TWO_NF - mean*mean;
  float inv  = rsqrtf(var + 1e-5f);
  float a0 = inv * bn0g[j];
  float a1 = inv * bn0g[128+j];
  alpha0[j] = a0; alpha1[j] = a1;
  beta0[j] = bn0b[j]     - mean*a0;
  beta1[j] = bn0b[128+j] - mean*a1;
  float varR = qr / NTF;
  alpha2[j] = rsqrtf(varR + 1e-5f) * bn0g[256+j];
}

// ---------------- K_fold: bias (blocks 0..127) | V+Vbf (128..627) | Wt2 (628..883) ----------------
__global__ __launch_bounds__(128) void k_fold(const float* __restrict__ aw, const float* __restrict__ ab,
                        const float* __restrict__ bn0b, const float* __restrict__ rel,
                        const float* __restrict__ alpha0, const float* __restrict__ alpha1,
                        const float* __restrict__ alpha2,
                        const float* __restrict__ beta0, const float* __restrict__ beta1,
                        float* __restrict__ bias, float* __restrict__ V,
                        unsigned short* __restrict__ Vbf, unsigned short* __restrict__ Wt2){
  __shared__ float sm[128];
  int b = blockIdx.x, j = threadIdx.x;
  if (b < 128){
    int o = b;
    const float* r = aw + (size_t)o*384;
    float p = r[j]*beta0[j] + r[128+j]*beta1[j] + r[256+j]*bn0b[256+j];
    sm[j] = p; __syncthreads();
    for (int s = 64; s > 0; s >>= 1){ if (j < s) sm[j] += sm[j+s]; __syncthreads(); }
    if (j == 0) bias[o] = ab[o] + sm[0];
  } else if (b < 628){
    int k = b - 128;
    sm[j] = rel[k*DD + j] * alpha2[j];
    __syncthreads();
    float acc = 0.f;
    #pragma unroll 8
    for (int q = 0; q < 128; ++q) acc += aw[(size_t)j*384 + 256 + q] * sm[q];
    V[k*DD + j] = acc;
    Vbf[k*DD + j] = f2bf(acc);
  } else {
    int o = b - 628;           // 0..255
    int k = j;                 // 0..127
    float w;
    if (o < 128) w = aw[(size_t)o*384 + k] * alpha0[k];
    else         w = aw[(size_t)(o-128)*384 + 128 + k] * alpha1[k];
    Wt2[(size_t)o*128 + k] = f2bf(w);
  }
}

// ---------------- K6: U table via MFMA — wave owns 4 output tiles, B in registers ----------------
__global__ __launch_bounds__(256) void k_u2(const unsigned short* __restrict__ Xbf,
                                            const unsigned short* __restrict__ Wt2,
                                            unsigned short* __restrict__ Uo){
  int tid = threadIdx.x;
  int w = tid >> 6, l = tid & 63;
  int col = l & 15, grp = l >> 4, kof = grp*8;
  int e0 = blockIdx.x*64;                    // 1563 blocks * 64 = 100032
  int ot0 = w*4;

  const unsigned short* wb0 = Wt2 + (size_t)((ot0+0)*16 + col)*128 + kof;
  const unsigned short* wb1 = Wt2 + (size_t)((ot0+1)*16 + col)*128 + kof;
  const unsigned short* wb2 = Wt2 + (size_t)((ot0+2)*16 + col)*128 + kof;
  const unsigned short* wb3 = Wt2 + (size_t)((ot0+3)*16 + col)*128 + kof;
  short8 b00 = *(const short8*)(wb0);
  short8 b01 = *(const short8*)(wb0+32);
  short8 b02 = *(const short8*)(wb0+64);
  short8 b03 = *(const short8*)(wb0+96);
  short8 b10 = *(const short8*)(wb1);
  short8 b11 = *(const short8*)(wb1+32);
  short8 b12 = *(const short8*)(wb1+64);
  short8 b13 = *(const short8*)(wb1+96);
  short8 b20 = *(const short8*)(wb2);
  short8 b21 = *(const short8*)(wb2+32);
  short8 b22 = *(const short8*)(wb2+64);
  short8 b23 = *(const short8*)(wb2+96);
  short8 b30 = *(const short8*)(wb3);
  short8 b31 = *(const short8*)(wb3+32);
  short8 b32 = *(const short8*)(wb3+64);
  short8 b33 = *(const short8*)(wb3+96);

  #pragma unroll
  for (int et = 0; et < 4; ++et){
    int ebase = e0 + et*16;
    int e = min(ebase + col, NE-1);
    const unsigned short* xrow = Xbf + (size_t)e*DD;
    short8 a0 = *(const short8*)(xrow + kof);
    short8 a1 = *(const short8*)(xrow + 32 + kof);
    short8 a2 = *(const short8*)(xrow + 64 + kof);
    short8 a3 = *(const short8*)(xrow + 96 + kof);
    f32x4 c0 = (f32x4){0.f,0.f,0.f,0.f};
    f32x4 c1 = (f32x4){0.f,0.f,0.f,0.f};
    f32x4 c2 = (f32x4){0.f,0.f,0.f,0.f};
    f32x4 c3 = (f32x4){0.f,0.f,0.f,0.f};
    c0 = __builtin_amdgcn_mfma_f32_16x16x32_bf16(a0, b00, c0, 0, 0, 0);
    c1 = __builtin_amdgcn_mfma_f32_16x16x32_bf16(a0, b10, c1, 0, 0, 0);
    c2 = __builtin_amdgcn_mfma_f32_16x16x32_bf16(a0, b20, c2, 0, 0, 0);
    c3 = __builtin_amdgcn_mfma_f32_16x16x32_bf16(a0, b30, c3, 0, 0, 0);
    c0 = __builtin_amdgcn_mfma_f32_16x16x32_bf16(a1, b01, c0, 0, 0, 0);
    c1 = __builtin_amdgcn_mfma_f32_16x16x32_bf16(a1, b11, c1, 0, 0, 0);
    c2 = __builtin_amdgcn_mfma_f32_16x16x32_bf16(a1, b21, c2, 0, 0, 0);
    c3 = __builtin_amdgcn_mfma_f32_16x16x32_bf16(a1, b31, c3, 0, 0, 0);
    c0 = __builtin_amdgcn_mfma_f32_16x16x32_bf16(a2, b02, c0, 0, 0, 0);
    c1 = __builtin_amdgcn_mfma_f32_16x16x32_bf16(a2, b12, c1, 0, 0, 0);
    c2 = __builtin_amdgcn_mfma_f32_16x16x32_bf16(a2, b22, c2, 0, 0, 0);
    c3 = __builtin_amdgcn_mfma_f32_16x16x32_bf16(a2, b32, c3, 0, 0, 0);
    c0 = __builtin_amdgcn_mfma_f32_16x16x32_bf16(a3, b03, c0, 0, 0, 0);
    c1 = __builtin_amdgcn_mfma_f32_16x16x32_bf16(a3, b13, c1, 0, 0, 0);
    c2 = __builtin_amdgcn_mfma_f32_16x16x32_bf16(a3, b23, c2, 0, 0, 0);
    c3 = __builtin_amdgcn_mfma_f32_16x16x32_bf16(a3, b33, c3, 0, 0, 0);
    #pragma unroll
    for (int r = 0; r < 4; ++r){
      int row = ebase + 4*grp + r;
      if (row < NE){
        size_t rb = (size_t)row*256 + col;
        Uo[rb + (ot0+0)*16] = f2bf(c0[r]);
        Uo[rb + (ot0+1)*16] = f2bf(c1[r]);
        Uo[rb + (ot0+2)*16] = f2bf(c2[r]);
        Uo[rb + (ot0+3)*16] = f2bf(c3[r]);
      }
    }
  }
}

// ---------------- K7: BN1 column stats over CSR events (unroll x4, bf16 V) ----------------
__global__ __launch_bounds__(256) void k_c1b(const uint2* __restrict__ evE,
                   const unsigned short* __restrict__ U, const unsigned short* __restrict__ Vbf,
                   const float* __restrict__ bias,
                   float* __restrict__ colsum, float* __restrict__ colsumsq){
  int lane = threadIdx.x & 63;
  int w = threadIdx.x >> 6;
  int wv = blockIdx.x*4 + w;
  int nwv = gridDim.x*4;
  int per = (NEV + nwv - 1) / nwv;
  int st = wv*per, en = min(st + per, NEV);
  int c0 = 2*lane, c1 = c0+1;
  float b0 = bias[c0], b1 = bias[c1];
  const ushort2* Ub = (const ushort2*)U;
  const ushort2* Vb = (const ushort2*)Vbf;
  float s0=0.f, s1=0.f, q0=0.f, q1=0.f;
  for (int bs = st; bs < en; bs += 64){
    int n = min(64, en - bs);
    uint2 ev = (bs + lane < en) ? evE[bs + lane] : make_uint2(0u, 0u);
    int j = 0;
    for (; j + 4 <= n; j += 4){
      unsigned ow0 = __shfl(ev.x, j, 64),   pk0 = __shfl(ev.y, j, 64);
      unsigned ow1 = __shfl(ev.x, j+1, 64), pk1 = __shfl(ev.y, j+1, 64);
      unsigned ow2 = __shfl(ev.x, j+2, 64), pk2 = __shfl(ev.y, j+2, 64);
      unsigned ow3 = __shfl(ev.x, j+3, 64), pk3 = __shfl(ev.y, j+3, 64);
      ushort2 a0 = Ub[(size_t)ow0*128 + lane];
      ushort2 g0 = Ub[(size_t)(pk0 >> 10)*128 + 64 + lane];
      ushort2 v0 = Vb[((pk0 >> 1) & 0x1FF)*64 + lane];
      ushort2 a1 = Ub[(size_t)ow1*128 + lane];
      ushort2 g1 = Ub[(size_t)(pk1 >> 10)*128 + 64 + lane];
      ushort2 v1 = Vb[((pk1 >> 1) & 0x1FF)*64 + lane];
      ushort2 a2 = Ub[(size_t)ow2*128 + lane];
      ushort2 g2 = Ub[(size_t)(pk2 >> 10)*128 + 64 + lane];
      ushort2 v2 = Vb[((pk2 >> 1) & 0x1FF)*64 + lane];
      ushort2 a3 = Ub[(size_t)ow3*128 + lane];
      ushort2 g3 = Ub[(size_t)(pk3 >> 10)*128 + 64 + lane];
      ushort2 v3 = Vb[((pk3 >> 1) & 0x1FF)*64 + lane];
      float sg0 = (pk0 & 1) ? -1.f : 1.f;
      float sg1 = (pk1 & 1) ? -1.f : 1.f;
      float sg2 = (pk2 & 1) ? -1.f : 1.f;
      float sg3 = (pk3 & 1) ? -1.f : 1.f;
      float y00 = bf2f(a0.x) + bf2f(g0.x) + sg0*bf2f(v0.x) + b0;
      float y01 = bf2f(a0.y) + bf2f(g0.y) + sg0*bf2f(v0.y) + b1;
      float y10 = bf2f(a1.x) + bf2f(g1.x) + sg1*bf2f(v1.x) + b0;
      float y11 = bf2f(a1.y) + bf2f(g1.y) + sg1*bf2f(v1.y) + b1;
      float y20 = bf2f(a2.x) + bf2f(g2.x) + sg2*bf2f(v2.x) + b0;
      float y21 = bf2f(a2.y) + bf2f(g2.y) + sg2*bf2f(v2.y) + b1;
      float y30 = bf2f(a3.x) + bf2f(g3.x) + sg3*bf2f(v3.x) + b0;
      float y31 = bf2f(a3.y) + bf2f(g3.y) + sg3*bf2f(v3.y) + b1;
      s0 += y00 + y10 + y20 + y30;
      s1 += y01 + y11 + y21 + y31;
      q0 += y00*y00 + y10*y10 + y20*y20 + y30*y30;
      q1 += y01*y01 + y11*y11 + y21*y21 + y31*y31;
    }
    for (; j < n; ++j){
      unsigned ow0 = __shfl(ev.x, j, 64), pk0 = __shfl(ev.y, j, 64);
      ushort2 a0 = Ub[(size_t)ow0*128 + lane];
      ushort2 g0 = Ub[(size_t)(pk0 >> 10)*128 + 64 + lane];
      ushort2 v0 = Vb[((pk0 >> 1) & 0x1FF)*64 + lane];
      float sg0 = (pk0 & 1) ? -1.f : 1.f;
      float y00 = bf2f(a0.x) + bf2f(g0.x) + sg0*bf2f(v0.x) + b0;
      float y01 = bf2f(a0.y) + bf2f(g0.y) + sg0*bf2f(v0.y) + b1;
      s0 += y00;  q0 += y00*y00;
      s1 += y01;  q1 += y01*y01;
    }
  }
  __shared__ float sred[4][128], qred[4][128];
  sred[w][c0] = s0; sred[w][c1] = s1;
  qred[w][c0] = q0; qred[w][c1] = q1;
  __syncthreads();
  int t = threadIdx.x;
  if (t < 128){
    atomAddF(&colsum[t],   sred[0][t] + sred[1][t] + sred[2][t] + sred[3][t]);
    atomAddF(&colsumsq[t], qred[0][t] + qred[1][t] + qred[2][t] + qred[3][t]);
  }
}

// ---------------- K8: BN1 fold + a2 fold + pbsb ----------------
__global__ void k_bn1fin(const float* __restrict__ colsum, const float* __restrict__ colsumsq,
                         const float* __restrict__ bn1g, const float* __restrict__ bn1b,
                         const float* __restrict__ a2w, const float* __restrict__ a2b,
                         const float* __restrict__ biasv,
                         float* __restrict__ A1, float* __restrict__ B1,
                         float* __restrict__ a2A, float* __restrict__ sbase){
  int j = threadIdx.x;
  float mean = colsum[j] / TWO_NF;
  float var  = colsumsq[j] / TWO_NF - mean*mean;
  float A = rsqrtf(var + 1e-5f) * bn1g[j];
  float B = bn1b[j] - mean*A;
  A1[j] = A; B1[j] = B;
  float w2 = a2w[j];
  float aA = w2*A;
  a2A[j] = aA;
  __shared__ float sm[128], sm2[128];
  sm[j] = w2*B; sm2[j] = biasv[j]*aA;
  __syncthreads();
  for (int s = 64; s > 0; s >>= 1){
    if (j < s){ sm[j] += sm[j+s]; sm2[j] += sm2[j+s]; }
    __syncthreads();
  }
  if (j == 0){
    float sb = a2b[0] + sm[0];
    sbase[0] = sb;
    sbase[1] = sb + sm2[0];   // pbsb = dot(bias,a2A) + sbase
  }
}

// ---------------- K_sigrho: sigma (blocks 0..24999) | rho (25000..25124) ----------------
__global__ __launch_bounds__(256) void k_sigrho(const unsigned short* __restrict__ U,
                                                const float* __restrict__ V,
                                                const float* __restrict__ a2A,
                                                float* __restrict__ sig, float* __restrict__ rho){
  int lane = threadIdx.x & 63;
  if (blockIdx.x < NE/4){
    int e = blockIdx.x*4 + (threadIdx.x>>6);
    const uint2* Ur = (const uint2*)U;
    uint2 r = Ur[(size_t)e*64 + lane];
    int c = (lane & 31)*4;
    float4 w = *(const float4*)&a2A[c];
    float p = bf2f_lo(r.x)*w.x + bf2f_hi(r.x)*w.y + bf2f_lo(r.y)*w.z + bf2f_hi(r.y)*w.w;
    p += __shfl_xor(p, 1, 64); p += __shfl_xor(p, 2, 64); p += __shfl_xor(p, 4, 64);
    p += __shfl_xor(p, 8, 64); p += __shfl_xor(p, 16, 64);
    if ((lane & 31) == 0) sig[2*e + (lane >> 5)] = p;
  } else {
    int k = (blockIdx.x - NE/4)*4 + (threadIdx.x>>6);
    if (k >= NR) return;
    const float2* Vp = (const float2*)V;
    float2 v = Vp[(size_t)k*64 + lane];
    int c0 = 2*lane;
    float p = v.x*a2A[c0] + v.y*a2A[c0+1];
    p = wredsum(p);
    if (lane == 0) rho[k] = p;
  }
}

// ---------------- K9: entity gather (unroll x4, bf16 V) ----------------
__global__ __launch_bounds__(256) void k_gent(const uint2* __restrict__ evE, const int* __restrict__ offE,
                   const unsigned short* __restrict__ U, const unsigned short* __restrict__ Vbf,
                   const float* __restrict__ sig, const float* __restrict__ rho,
                   const float* __restrict__ bias,
                   const float* __restrict__ A1, const float* __restrict__ B1,
                   const float* __restrict__ sbase,
                   float* __restrict__ out){
  int lane = threadIdx.x & 63;
  int e = blockIdx.x*4 + (threadIdx.x>>6);
  if (e >= NE) return;
  int c0 = 2*lane, c1 = c0+1;
  const ushort2* Ub = (const ushort2*)U;
  const ushort2* Vb = (const ushort2*)Vbf;
  ushort2 u0 = Ub[(size_t)e*128 + lane];
  float base0 = bf2f(u0.x) + bias[c0], base1 = bf2f(u0.y) + bias[c1];
  float pb  = sbase[1];
  float s0e = sig[2*e];
  float accU0=0.f, accU1=0.f, accV0=0.f, accV1=0.f, sep=0.f;
  int p0 = offE[e], p1 = offE[e+1];
  for (int bs = p0; bs < p1; bs += 64){
    int n = min(64, p1 - bs);
    unsigned ev = 0u; float ebl = 0.f;
    if (bs + lane < p1){
      ev = evE[bs + lane].y;
      int oth = ev >> 10, rl = (ev >> 1) & 0x1FF;
      float sg = (ev & 1) ? -1.f : 1.f;
      float s = s0e + sig[2*oth + 1] + sg*rho[rl] + pb;
      float bb = (s >= 0.f) ? -s : -0.01f*s;
      ebl = expf(bb);
    }
    sep += ebl;
    int j = 0;
    for (; j + 4 <= n; j += 4){
      unsigned e0 = __shfl(ev, j, 64);
      unsigned e1 = __shfl(ev, j+1, 64);
      unsigned e2 = __shfl(ev, j+2, 64);
      unsigned e3 = __shfl(ev, j+3, 64);
      float eb0 = __shfl(ebl, j, 64);
      float eb1 = __shfl(ebl, j+1, 64);
      float eb2 = __shfl(ebl, j+2, 64);
      float eb3 = __shfl(ebl, j+3, 64);
      ushort2 g0 = Ub[(size_t)(e0 >> 10)*128 + 64 + lane];
      ushort2 g1 = Ub[(size_t)(e1 >> 10)*128 + 64 + lane];
      ushort2 g2 = Ub[(size_t)(e2 >> 10)*128 + 64 + lane];
      ushort2 g3 = Ub[(size_t)(e3 >> 10)*128 + 64 + lane];
      ushort2 v0 = Vb[((e0 >> 1) & 0x1FF)*64 + lane];
      ushort2 v1 = Vb[((e1 >> 1) & 0x1FF)*64 + lane];
      ushort2 v2 = Vb[((e2 >> 1) & 0x1FF)*64 + lane];
      ushort2 v3 = Vb[((e3 >> 1) & 0x1FF)*64 + lane];
      float w0 = (e0 & 1) ? -eb0 : eb0;
      float w1 = (e1 & 1) ? -eb1 : eb1;
      float w2 = (e2 & 1) ? -eb2 : eb2;
      float w3 = (e3 & 1) ? -eb3 : eb3;
      accU0 += eb0*bf2f(g0.x); accU1 += eb0*bf2f(g0.y);
      accV0 += w0*bf2f(v0.x);  accV1 += w0*bf2f(v0.y);
      accU0 += eb1*bf2f(g1.x); accU1 += eb1*bf2f(g1.y);
      accV0 += w1*bf2f(v1.x);  accV1 += w1*bf2f(v1.y);
      accU0 += eb2*bf2f(g2.x); accU1 += eb2*bf2f(g2.y);
      accV0 += w2*bf2f(v2.x);  accV1 += w2*bf2f(v2.y);
      accU0 += eb3*bf2f(g3.x); accU1 += eb3*bf2f(g3.y);
      accV0 += w3*bf2f(v3.x);  accV1 += w3*bf2f(v3.y);
    }
    for (; j < n; ++j){
      unsigned e0 = __shfl(ev, j, 64);
      float eb0 = __shfl(ebl, j, 64);
      ushort2 g0 = Ub[(size_t)(e0 >> 10)*128 + 64 + lane];
      ushort2 v0 = Vb[((e0 >> 1) & 0x1FF)*64 + lane];
      float w0 = (e0 & 1) ? -eb0 : eb0;
      accU0 += eb0*bf2f(g0.x); accU1 += eb0*bf2f(g0.y);
      accV0 += w0*bf2f(v0.x);  accV1 += w0*bf2f(v0.y);
    }
  }
  float se = wredsum(sep);
  float sY0 = se*base0 + accU0 + accV0;
  float sY1 = se*base1 + accU1 + accV1;
  float hs0 = A1[c0]*sY0 + B1[c0]*se;
  float hs1 = A1[c1]*sY1 + B1[c1]*se;
  float d = (se == 0.f) ? 1e-12f : se;
  out[(size_t)e*DD + c0] = hs0/d;
  out[(size_t)e*DD + c1] = hs1/d;
}

// ---------------- K10: relation gather — one block (16 waves) per rel, direct write ----------------
__global__ __launch_bounds__(1024) void k_grel2(const uint2* __restrict__ evR, const int* __restrict__ offR,
                   const unsigned short* __restrict__ U, const float* __restrict__ V,
                   const float* __restrict__ sig, const float* __restrict__ rho,
                   const float* __restrict__ bias,
                   const float* __restrict__ A1, const float* __restrict__ B1,
                   const float* __restrict__ sbase, const int* __restrict__ cntR,
                   float* __restrict__ out){
  __shared__ float rA[16][64], rB[16][64], sepw[16];
  int lane = threadIdx.x & 63;
  int w = threadIdx.x >> 6;       // 0..15
  int k = blockIdx.x;
  int c0 = 2*lane, c1 = c0+1;
  const ushort2* Ub = (const ushort2*)U;
  const float2*  Vp = (const float2*)V;
  float2 v = Vp[(size_t)k*64 + lane];
  float vb0 = v.x + bias[c0], vb1 = v.y + bias[c1];
  float rpb = rho[k] + sbase[1];
  float accY0=0.f, accY1=0.f, sep=0.f;
  int p0 = offR[k], p1 = offR[k+1];
  for (int bs = p0 + w*64; bs < p1; bs += 16*64){
    int n = min(64, p1 - bs);
    uint2 ev = make_uint2(0u, 0u); float ebl = 0.f;
    if (bs + lane < p1){
      ev = evR[bs + lane];
      float s = sig[2*ev.x] + sig[2*ev.y + 1] + rpb;
      float bb = (s >= 0.f) ? -s : -0.01f*s;
      ebl = expf(bb);
    }
    sep += ebl;
    int j = 0;
    for (; j + 2 <= n; j += 2){
      unsigned a0 = __shfl(ev.x, j, 64),   d0 = __shfl(ev.y, j, 64);
      unsigned a1 = __shfl(ev.x, j+1, 64), d1 = __shfl(ev.y, j+1, 64);
      float eb0 = __shfl(ebl, j, 64);
      float eb1 = __shfl(ebl, j+1, 64);
      ushort2 ua0 = Ub[(size_t)a0*128 + lane];
      ushort2 ud0 = Ub[(size_t)d0*128 + 64 + lane];
      ushort2 ua1 = Ub[(size_t)a1*128 + lane];
      ushort2 ud1 = Ub[(size_t)d1*128 + 64 + lane];
      accY0 += eb0*(bf2f(ua0.x) + bf2f(ud0.x));
      accY1 += eb0*(bf2f(ua0.y) + bf2f(ud0.y));
      accY0 += eb1*(bf2f(ua1.x) + bf2f(ud1.x));
      accY1 += eb1*(bf2f(ua1.y) + bf2f(ud1.y));
    }
    for (; j < n; ++j){
      unsigned a0 = __shfl(ev.x, j, 64), d0 = __shfl(ev.y, j, 64);
      float eb0 = __shfl(ebl, j, 64);
      ushort2 ua0 = Ub[(size_t)a0*128 + lane];
      ushort2 ud0 = Ub[(size_t)d0*128 + 64 + lane];
      accY0 += eb0*(bf2f(ua0.x) + bf2f(ud0.x));
      accY1 += eb0*(bf2f(ua0.y) + bf2f(ud0.y));
    }
  }
  float se_w = wredsum(sep);
  rA[w][lane] = accY0;
  rB[w][lane] = accY1;
  if (lane == 0) sepw[w] = se_w;
  __syncthreads();
  if (threadIdx.x < 64){
    int l = threadIdx.x;
    float sY0 = 0.f, sY1 = 0.f, se = 0.f;
    #pragma unroll
    for (int ww = 0; ww < 16; ++ww){ sY0 += rA[ww][l]; sY1 += rB[ww][l]; se += sepw[ww]; }
    sY0 += se*vb0;
    sY1 += se*vb1;
    float r0 = A1[c0]*sY0 + B1[c0]*se;
    float r1 = A1[c1]*sY1 + B1[c1]*se;
    float cdiv = fmaxf((float)cntR[k], 1.f);
    out[(size_t)RELOFF + (size_t)k*DD + c0] = r0/cdiv;
    out[(size_t)RELOFF + (size_t)k*DD + c1] = r1/cdiv;
  }
}

extern "C" void kernel_launch(void* const* d_in, const int* in_sizes, int n_in,
                              void* d_out, int out_size, void* d_ws, size_t ws_size,
                              hipStream_t stream) {
  (void)in_sizes; (void)n_in; (void)ws_size; (void)out_size;
  const int*   trip = (const int*)  d_in[0];
  const float* ent  = (const float*)d_in[1];
  const float* rel  = (const float*)d_in[2];
  const float* aw   = (const float*)d_in[3];
  const float* ab   = (const float*)d_in[4];
  const float* a2w  = (const float*)d_in[5];
  const float* a2b  = (const float*)d_in[6];
  const float* bn0g = (const float*)d_in[7];
  const float* bn0b = (const float*)d_in[8];
  const float* bn1g = (const float*)d_in[9];
  const float* bn1b = (const float*)d_in[10];
  float* out = (float*)d_out;
  // Xbf scratch lives in the entity half of d_out (overwritten later by k_gent)
  unsigned short* Xbf = (unsigned short*)d_out;

  char* w = (char*)d_ws;
  size_t off = 0;
  auto take = [&](size_t bytes) -> char* {
    char* p = w + off;
    off = (off + bytes + 511) & ~(size_t)511;
    return p;
  };
  // zeroed region (accumulators)
  float* S        = (float*)take(512);
  float* Q        = (float*)take(512);
  float* colsum   = (float*)take(512);
  float* colsumsq = (float*)take(512);
  int*   cnt      = (int*)  take((size_t)NE*4);
  size_t zero_end = off;
  // non-zeroed (fully overwritten each launch)
  int*   cntR   = (int*)  take((size_t)NR*4);
  float* alpha0 = (float*)take(512);
  float* alpha1 = (float*)take(512);
  float* alpha2 = (float*)take(512);
  float* beta0  = (float*)take(512);
  float* beta1  = (float*)take(512);
  float* biasv  = (float*)take(512);
  float* A1     = (float*)take(512);
  float* B1     = (float*)take(512);
  float* a2A    = (float*)take(512);
  float* sbase  = (float*)take(512);
  float* rho    = (float*)take((size_t)NR*4);
  float* sig    = (float*)take((size_t)NE*2*4);
  int*   offE   = (int*)  take((size_t)(NE+1)*4);
  int*   curE   = (int*)  take((size_t)NE*4);
  int*   offR   = (int*)  take((size_t)(NR+1)*4);
  int*   gHist  = (int*)  take((size_t)NBH*NR*4);
  int*   gBase  = (int*)  take((size_t)NBH*NR*4);
  int*   bsum   = (int*)  take((size_t)NBS*4);
  unsigned long long* evE = (unsigned long long*)take((size_t)NEV*8);
  unsigned long long* evR = (unsigned long long*)take((size_t)NT*8);
  float* V      = (float*)take((size_t)NR*DD*4);
  unsigned short* Vbf = (unsigned short*)take((size_t)NR*DD*2);
  unsigned short* Wt2 = (unsigned short*)take((size_t)256*128*2);
  unsigned short* U   = (unsigned short*)take((size_t)NE*256*2);

  hipMemsetAsync(d_ws, 0, zero_end, stream);

  k_hist     <<<NBH, 256, 0, stream>>>(trip, cnt, gHist);
  k_histscan <<<1, 512, 0, stream>>>(gHist, gBase, cntR, offR);
  k_scan1    <<<NBS, 1024, 0, stream>>>(cnt, offE, bsum);
  k_scan23   <<<NBS, 1024, 0, stream>>>(bsum, offE, curE);
  k_scat_ent <<<(NT+255)/256, 256, 0, stream>>>(trip, curE, evE);
  k_scat_rel <<<NBH, 256, 0, stream>>>(trip, gBase, evR);
  k_entstats <<<(NE+127)/128, 256, 0, stream>>>(ent, cnt, S, Q, Xbf);
  k_alpha    <<<1, 128, 0, stream>>>(rel, cntR, S, Q, bn0g, bn0b, alpha0, alpha1, alpha2, beta0, beta1);
  k_fold     <<<884, 128, 0, stream>>>(aw, ab, bn0b, rel, alpha0, alpha1, alpha2, beta0, beta1,
                                       biasv, V, Vbf, Wt2);
  k_u2       <<<1563, 256, 0, stream>>>(Xbf, Wt2, U);
  k_c1b      <<<2048, 256, 0, stream>>>((const uint2*)evE, U, Vbf, biasv, colsum, colsumsq);
  k_bn1fin   <<<1, 128, 0, stream>>>(colsum, colsumsq, bn1g, bn1b, a2w, a2b, biasv, A1, B1, a2A, sbase);
  k_sigrho   <<<NE/4 + (NR+3)/4, 256, 0, stream>>>(U, V, a2A, sig, rho);
  k_gent     <<<NE/4, 256, 0, stream>>>((const uint2*)evE, offE, U, Vbf, sig, rho, biasv, A1, B1, sbase, out);
  k_grel2    <<<NR, 1024, 0, stream>>>((const uint2*)evR, offR, U, V, sig, rho, biasv, A1, B1, sbase, cntR, out);
}